// Round 1
// baseline (397.116 us; speedup 1.0000x reference)
//
#include <hip/hip_runtime.h>

// ---------------------------------------------------------------------------
// MultiHeadsLinearAttention  (B=8, C=512, HEADS=8, CH=64, H=W=64 -> N=4096)
// Inputs fp32, output fp32. Compute: bf16 MFMA, fp32 accumulation.
//
// Stages:
//  W : Wg = qkv_w * g -> bf16 ; Wf = ffn_w -> bf16
//  T : per-token invx over fp32 x; xnT[p][c] = x*invx*sqrtC (bf16, k-contig)
//      chunked 2 batches at a time (grid 128x2 = 256 blocks), serial w/ C
//  C : QKV GEMM (128x128 tile, BK=64, both operands k-contiguous,
//      global_load_lds width-16 LINEAR staging): rows<512 -> Q (ws), else K,V
//  D : k-softmax stats (kmax,kinv)
//  E : attnP[bh][ks][d][c] = sum_{p in ks-slice} exp(k[c][p]-kmax)*v[d][p]
//      (MFMA, wave-specialized over d -> ZERO atomics, zero LDS; 8 p-partials)
//      attnP aliases the dead xnT chunk buffer.
//  F : q-softmax per token; xoT[b][p][hd] = qsm @ (sum_ks attnP * kinv)
//      (overwrites dead K region of d_out)
//  G : FFN GEMM y = ffn_b + Wf @ xoT  (overwrites Q in ws)
//  H1: invn2 = 1/||y||  ;  H2: out = y*invn2*g2*sqrtC + x (fp32)
//
// Round-7 lesson: global_load_lds + XOR-SWIZZLE staging diverged after graph
// replay. This round: global_load_lds with LINEAR destination (no swizzle, no
// padding — padding breaks the wave-uniform-base+lane*16 contract, m173).
// This is the verified m97 pattern (874-912 TF vs ~500 for sync staging).
// LDS tiles [128][64] linear: 16-way ds_read bank alias accepted (m97/m98:
// barrier drain dominates, conflicts not on critical path).
// Round-8 lesson: 8.4M contended global atomicAdds in attn = 175us wall ->
// partials + wave-specialization.
// ---------------------------------------------------------------------------

typedef __bf16 bf16_t;
typedef __bf16 bf8 __attribute__((ext_vector_type(8)));
typedef float f32x4 __attribute__((ext_vector_type(4)));

#define NC 512
#define NP 4096
#define SQRTC 22.62741699796952f
#define QSCALE 0.125f
#define LDP 88
#define QSTRIDE  ((size_t)NC * NP)      // 2097152  per-batch 512-row elems
#define KVSTRIDE ((size_t)1024 * NP)    // 4194304  per-batch kv elems (d_out)

__device__ inline unsigned short bfbits(__bf16 h) {
    return __builtin_bit_cast(unsigned short, h);
}

// async global->LDS, 16B per lane. LDS dest must be wave-uniform base;
// HW writes base + lane*16.
__device__ __forceinline__ void gload_lds16(const bf16_t* g, __bf16* l) {
    __builtin_amdgcn_global_load_lds(
        (const __attribute__((address_space(1))) void*)g,
        (__attribute__((address_space(3))) void*)l, 16, 0, 0);
}

// ---------------------------------------------------------------------------
// W: weight convert fp32->bf16, optional per-column scale g. 4 elems/thread.
// ---------------------------------------------------------------------------
__global__ __launch_bounds__(256) void
wconv_kernel(const float* __restrict__ w, const float* __restrict__ g,
             bf16_t* __restrict__ out) {
    int i0 = (blockIdx.x * 256 + threadIdx.x) * 4;
    float4 wv = *(const float4*)&w[i0];
    if (g) {
        const float4 gv = *(const float4*)&g[i0 & 511];
        wv.x *= gv.x; wv.y *= gv.y; wv.z *= gv.z; wv.w *= gv.w;
    }
    ushort4 o;
    o.x = bfbits((__bf16)wv.x);
    o.y = bfbits((__bf16)wv.y);
    o.z = bfbits((__bf16)wv.z);
    o.w = bfbits((__bf16)wv.w);
    *(ushort4*)&out[i0] = o;
}

// ---------------------------------------------------------------------------
// T: norm + transpose, 2 batches per launch. grid(128, 2) block 256.
// Block covers 32 tokens. xnT[p][c] = x[c][p] * sqrtC/max(||x[:,p]||,1e-12)
// ---------------------------------------------------------------------------
__global__ __launch_bounds__(256) void
norm_transpose_kernel(const float* __restrict__ x, bf16_t* __restrict__ xnT) {
    const int bl = blockIdx.y;
    const int p0 = blockIdx.x * 32;
    const int t = threadIdx.x;
    const float* xb = x + (size_t)bl * QSTRIDE;
    bf16_t* ob = xnT + (size_t)bl * QSTRIDE;

    // pass 1: sumsq — 8 threads per token, 64 c each
    const int pp = t & 31;
    const int ch = (t >> 5) * 64;
    float ss = 0.f;
    for (int c = 0; c < 64; ++c) {
        float v = xb[(size_t)(ch + c) * NP + p0 + pp];
        ss += v * v;
    }
    __shared__ float sS[8][32];
    __shared__ float sInv[32];
    sS[t >> 5][pp] = ss;
    __syncthreads();
    if (t < 32) {
        float tot = 0.f;
        #pragma unroll
        for (int j = 0; j < 8; ++j) tot += sS[j][t];
        sInv[t] = SQRTC / fmaxf(sqrtf(tot), 1e-12f);
    }
    __syncthreads();

    // pass 2: 32-c x 32-p chunks through LDS transpose
    __shared__ __bf16 sT[32][40];
    for (int cc = 0; cc < 512; cc += 32) {
        #pragma unroll
        for (int j = 0; j < 4; ++j) {
            int e = t + j * 256;                 // 1024 = 32c x 32p
            int cr = e >> 5, p = e & 31;
            sT[cr][p] = (__bf16)(xb[(size_t)(cc + cr) * NP + p0 + p] * sInv[p]);
        }
        __syncthreads();
        if (t < 128) {
            int p = t >> 2, c8 = (t & 3) * 8;
            bf8 v;
            #pragma unroll
            for (int q = 0; q < 8; ++q) v[q] = sT[c8 + q][p];
            *(bf8*)&ob[(size_t)(p0 + p) * NC + cc + c8] = v;
        }
        __syncthreads();
    }
}

// ---------------------------------------------------------------------------
// C: QKV GEMM. grid(32, 12, nb) block 256 (nb batches per launch).
// A = Wg [1536][512], B = xnT [p][c] (both k-contiguous bf16).
// 128x128 tile, BK=64, 4 waves of 64x64. global_load_lds linear staging:
// per wave 4 A-chunks + 4 B-chunks of 1024B (8 rows x 64 k each).
// ---------------------------------------------------------------------------
__global__ __launch_bounds__(256) void
gemm_qkv_kernel(const bf16_t* __restrict__ Wg, const bf16_t* __restrict__ xnT,
                bf16_t* __restrict__ qout, bf16_t* __restrict__ kvout) {
    const int bn = blockIdx.x, bm = blockIdx.y, b = blockIdx.z;
    const int t = threadIdx.x;
    const int w = t >> 6, ln = t & 63, quad = ln >> 4, l16 = ln & 15;
    const int wm = w >> 1, wn = w & 1;

    __shared__ __align__(16) __bf16 sA[128 * 64];
    __shared__ __align__(16) __bf16 sB[128 * 64];

    f32x4 acc[4][4] = {};
    const bf16_t* Abase = Wg + (size_t)(bm * 128) * NC;
    const bf16_t* Bbase = xnT + (size_t)b * QSTRIDE + (size_t)(bn * 128) * NC;

    // per-lane source row/col within a 1024B chunk (8 rows x 64 k)
    const int lrow = ln >> 3;           // 0..7
    const int lkc = (ln & 7) * 8;       // k offset, 16B granules

    for (int kt = 0; kt < 8; ++kt) {
        const int k0 = kt * 64;
        #pragma unroll
        for (int i = 0; i < 4; ++i) {
            const int chunk = w * 4 + i;          // 0..15, wave-uniform
            const int row = chunk * 8 + lrow;
            gload_lds16(Abase + (size_t)row * NC + k0 + lkc, &sA[chunk * 512]);
            gload_lds16(Bbase + (size_t)row * NC + k0 + lkc, &sB[chunk * 512]);
        }
        __syncthreads();
        #pragma unroll
        for (int ks = 0; ks < 2; ++ks) {
            const int kk = ks * 32;
            bf8 af[4], bfr[4];
            #pragma unroll
            for (int mi = 0; mi < 4; ++mi)
                af[mi] = *(const bf8*)&sA[(wm * 64 + mi * 16 + l16) * 64 + kk + quad * 8];
            #pragma unroll
            for (int ni = 0; ni < 4; ++ni)
                bfr[ni] = *(const bf8*)&sB[(wn * 64 + ni * 16 + l16) * 64 + kk + quad * 8];
            #pragma unroll
            for (int mi = 0; mi < 4; ++mi)
                #pragma unroll
                for (int ni = 0; ni < 4; ++ni)
                    acc[mi][ni] = __builtin_amdgcn_mfma_f32_16x16x32_bf16(
                        af[mi], bfr[ni], acc[mi][ni], 0, 0, 0);
        }
        __syncthreads();
    }

    bf16_t* qb = qout + (size_t)b * QSTRIDE;
    bf16_t* kvb = kvout + (size_t)b * KVSTRIDE;
    const int p0 = bn * 128;
    #pragma unroll
    for (int ni = 0; ni < 4; ++ni) {
        const int colL = wn * 64 + ni * 16 + l16;
        #pragma unroll
        for (int mi = 0; mi < 4; ++mi) {
            #pragma unroll
            for (int r = 0; r < 4; ++r) {
                const int row = bm * 128 + wm * 64 + mi * 16 + quad * 4 + r;
                const __bf16 val = (__bf16)acc[mi][ni][r];
                if (row < 512)
                    qb[(size_t)row * NP + p0 + colL] = val;
                else
                    kvb[(size_t)(row - 512) * NP + p0 + colL] = val;
            }
        }
    }
}

// ---------------------------------------------------------------------------
// G: FFN GEMM. grid(32, 4, 8) block 256.
// A = Wf [512][512], B = xoT [p][c] (d_out K region), out y (+bias) -> ws.
// Same global_load_lds linear staging as QKV GEMM.
// ---------------------------------------------------------------------------
__global__ __launch_bounds__(256) void
gemm_ffn_kernel(const bf16_t* __restrict__ Wf, const bf16_t* __restrict__ xoT,
                const float* __restrict__ bias, bf16_t* __restrict__ y) {
    const int bn = blockIdx.x, bm = blockIdx.y, b = blockIdx.z;
    const int t = threadIdx.x;
    const int w = t >> 6, ln = t & 63, quad = ln >> 4, l16 = ln & 15;
    const int wm = w >> 1, wn = w & 1;

    __shared__ __align__(16) __bf16 sA[128 * 64];
    __shared__ __align__(16) __bf16 sB[128 * 64];

    f32x4 acc[4][4] = {};
    const bf16_t* Abase = Wf + (size_t)(bm * 128) * NC;
    const bf16_t* Bbase = xoT + (size_t)b * KVSTRIDE + (size_t)(bn * 128) * NC;

    const int lrow = ln >> 3;
    const int lkc = (ln & 7) * 8;

    for (int kt = 0; kt < 8; ++kt) {
        const int k0 = kt * 64;
        #pragma unroll
        for (int i = 0; i < 4; ++i) {
            const int chunk = w * 4 + i;
            const int row = chunk * 8 + lrow;
            gload_lds16(Abase + (size_t)row * NC + k0 + lkc, &sA[chunk * 512]);
            gload_lds16(Bbase + (size_t)row * NC + k0 + lkc, &sB[chunk * 512]);
        }
        __syncthreads();
        #pragma unroll
        for (int ks = 0; ks < 2; ++ks) {
            const int kk = ks * 32;
            bf8 af[4], bfr[4];
            #pragma unroll
            for (int mi = 0; mi < 4; ++mi)
                af[mi] = *(const bf8*)&sA[(wm * 64 + mi * 16 + l16) * 64 + kk + quad * 8];
            #pragma unroll
            for (int ni = 0; ni < 4; ++ni)
                bfr[ni] = *(const bf8*)&sB[(wn * 64 + ni * 16 + l16) * 64 + kk + quad * 8];
            #pragma unroll
            for (int mi = 0; mi < 4; ++mi)
                #pragma unroll
                for (int ni = 0; ni < 4; ++ni)
                    acc[mi][ni] = __builtin_amdgcn_mfma_f32_16x16x32_bf16(
                        af[mi], bfr[ni], acc[mi][ni], 0, 0, 0);
        }
        __syncthreads();
    }

    bf16_t* yb = y + (size_t)b * QSTRIDE;
    const int p0 = bn * 128;
    #pragma unroll
    for (int mi = 0; mi < 4; ++mi) {
        #pragma unroll
        for (int ni = 0; ni < 4; ++ni) {
            const int col = p0 + wn * 64 + ni * 16 + l16;
            #pragma unroll
            for (int r = 0; r < 4; ++r) {
                const int row = bm * 128 + wm * 64 + mi * 16 + quad * 4 + r;
                float v = acc[mi][ni][r] + bias[row];
                yb[(size_t)row * NP + col] = (__bf16)v;
            }
        }
    }
}

// ---------------------------------------------------------------------------
// D: k-softmax stats per (b, channel) row. grid(512, 8) block 256.
// ---------------------------------------------------------------------------
__global__ __launch_bounds__(256) void
kstats_kernel(const bf16_t* __restrict__ kv, float* __restrict__ kmax,
              float* __restrict__ kinv) {
    const int oc = blockIdx.x, b = blockIdx.y;
    const int t = threadIdx.x, w = t >> 6, ln = t & 63;

    const bf16_t* row = kv + (size_t)b * KVSTRIDE + (size_t)oc * NP;
    float v[16];
    bf8 x0 = *(const bf8*)&row[t * 8];
    bf8 x1 = *(const bf8*)&row[2048 + t * 8];
    #pragma unroll
    for (int j = 0; j < 8; ++j) { v[j] = (float)x0[j]; v[8 + j] = (float)x1[j]; }

    float m = v[0];
    #pragma unroll
    for (int j = 1; j < 16; ++j) m = fmaxf(m, v[j]);
    #pragma unroll
    for (int off = 32; off > 0; off >>= 1) m = fmaxf(m, __shfl_down(m, off));
    __shared__ float sR[4];
    __shared__ float sS[4];
    if (ln == 0) sR[w] = m;
    __syncthreads();
    m = fmaxf(fmaxf(sR[0], sR[1]), fmaxf(sR[2], sR[3]));

    float s = 0.f;
    #pragma unroll
    for (int j = 0; j < 16; ++j) s += __expf(v[j] - m);
    #pragma unroll
    for (int off = 32; off > 0; off >>= 1) s += __shfl_down(s, off);
    if (ln == 0) sS[w] = s;
    __syncthreads();
    if (t == 0) {
        kmax[b * 512 + oc] = m;
        kinv[b * 512 + oc] = 1.0f / (sS[0] + sS[1] + sS[2] + sS[3]);
    }
}

// ---------------------------------------------------------------------------
// E: attnP[bh][ks][d][c] = sum_{p in slice} exp(k[c][p]-kmax[c]) * v[d][p].
// grid(8, 8, 8) block 256. Wave w owns d rows [w*16, w*16+16): no reduction,
// no atomics, no LDS. Each ks-slice covers 512 p (16 iters of 32 p).
// ---------------------------------------------------------------------------
__global__ __launch_bounds__(256) void
attn_kernel(const bf16_t* __restrict__ kv, const float* __restrict__ kmax,
            float* __restrict__ attnP) {
    const int h = blockIdx.x, ks = blockIdx.y, b = blockIdx.z;
    const int t = threadIdx.x, w = t >> 6, ln = t & 63, quad = ln >> 4, l16 = ln & 15;

    const bf16_t* Kb = kv + (size_t)b * KVSTRIDE + (size_t)(h * 64) * NP;
    const bf16_t* Vb = kv + (size_t)b * KVSTRIDE + (size_t)(512 + h * 64 + w * 16) * NP;

    float km[4];
    #pragma unroll
    for (int mi = 0; mi < 4; ++mi) km[mi] = kmax[b * 512 + h * 64 + mi * 16 + l16];

    f32x4 acc[4] = {};
    const int pbase = ks * 512 + quad * 8;
    #pragma unroll 4
    for (int it = 0; it < 16; ++it) {
        const int p0 = pbase + it * 32;
        bf8 bfr = *(const bf8*)&Vb[(size_t)l16 * NP + p0];
        #pragma unroll
        for (int mi = 0; mi < 4; ++mi) {
            bf8 kr = *(const bf8*)&Kb[(size_t)(mi * 16 + l16) * NP + p0];
            bf8 af;
            #pragma unroll
            for (int j = 0; j < 8; ++j)
                af[j] = (__bf16)__expf((float)kr[j] - km[mi]);
            acc[mi] = __builtin_amdgcn_mfma_f32_16x16x32_bf16(af, bfr, acc[mi], 0, 0, 0);
        }
    }

    // D layout: row (=c within mi-block) = quad*4+r, col (=d) = l16.
    float* outp = attnP + (((size_t)(b * 8 + h) * 8 + ks) << 12);
    #pragma unroll
    for (int mi = 0; mi < 4; ++mi) {
        float4 v;
        v.x = acc[mi][0]; v.y = acc[mi][1]; v.z = acc[mi][2]; v.w = acc[mi][3];
        *(float4*)&outp[(w * 16 + l16) * 64 + mi * 16 + quad * 4] = v;
    }
}

// ---------------------------------------------------------------------------
// F: q softmax over ch (*SCALE) then xoT[p][h*64+d] = qsm @ (attn*kinv).
// grid(32, 8, 8) block 256. attn = sum of 8 attnP partials (L2-resident).
// xoT overwrites dead K region of d_out.
// ---------------------------------------------------------------------------
__global__ __launch_bounds__(256) void
outgemm_kernel(const bf16_t* __restrict__ q, const float* __restrict__ attnP,
               const float* __restrict__ kinv, bf16_t* __restrict__ xoT) {
    const int pt = blockIdx.x, h = blockIdx.y, b = blockIdx.z;
    const int p0 = pt * 128;
    const int t = threadIdx.x, w = t >> 6, ln = t & 63, quad = ln >> 4, l16 = ln & 15;

    __shared__ __align__(16) __bf16 sQb[128][LDP];   // [p][c]
    __shared__ __align__(16) __bf16 sAt[64][LDP];    // [d][c]
    __shared__ float sMax[128], sInv[128];

    const bf16_t* qb = q + (size_t)b * QSTRIDE;
    const float* ap = attnP + (((size_t)(b * 8 + h) * 8) << 12);
    #pragma unroll
    for (int i = 0; i < 16; ++i) {
        int e = t + i * 256;             // d*64 + c
        int d = e >> 6, c = e & 63;
        float s = 0.f;
        #pragma unroll
        for (int ksi = 0; ksi < 8; ++ksi) s += ap[(ksi << 12) + e];
        sAt[d][c] = (__bf16)(s * kinv[b * 512 + h * 64 + c]);
    }
    #pragma unroll
    for (int i = 0; i < 32; ++i) {
        int e = t + i * 256;             // c*128 + p
        int c = e >> 7, p = e & 127;
        sQb[p][c] = qb[(size_t)(h * 64 + c) * NP + p0 + p];
    }
    __syncthreads();
    if (t < 128) {
        float m = -1e30f;
        #pragma unroll
        for (int c = 0; c < 64; ++c) m = fmaxf(m, (float)sQb[t][c]);
        float s = 0.f;
        #pragma unroll
        for (int c = 0; c < 64; ++c) s += __expf((float)sQb[t][c] - m);
        sMax[t] = m;
        sInv[t] = QSCALE / s;
    }
    __syncthreads();
    #pragma unroll
    for (int i = 0; i < 32; ++i) {
        int e = t + i * 256;             // p*64 + c
        int p = e >> 6, c = e & 63;
        sQb[p][c] = (__bf16)(__expf((float)sQb[p][c] - sMax[p]) * sInv[p]);
    }
    __syncthreads();

    f32x4 acc[2][4] = {};
    #pragma unroll
    for (int ksp = 0; ksp < 2; ++ksp) {
        const int kk = ksp * 32;
        bf8 af[2], bfr[4];
        #pragma unroll
        for (int mi = 0; mi < 2; ++mi)
            af[mi] = *(const bf8*)&sQb[w * 32 + mi * 16 + l16][kk + quad * 8];
        #pragma unroll
        for (int ni = 0; ni < 4; ++ni)
            bfr[ni] = *(const bf8*)&sAt[ni * 16 + l16][kk + quad * 8];
        #pragma unroll
        for (int mi = 0; mi < 2; ++mi)
            #pragma unroll
            for (int ni = 0; ni < 4; ++ni)
                acc[mi][ni] = __builtin_amdgcn_mfma_f32_16x16x32_bf16(
                    af[mi], bfr[ni], acc[mi][ni], 0, 0, 0);
    }
    bf16_t* xob = xoT + (size_t)b * KVSTRIDE;
    #pragma unroll
    for (int mi = 0; mi < 2; ++mi)
        #pragma unroll
        for (int ni = 0; ni < 4; ++ni)
            #pragma unroll
            for (int r = 0; r < 4; ++r) {
                int p = p0 + w * 32 + mi * 16 + quad * 4 + r;
                int dg = h * 64 + ni * 16 + l16;
                xob[(size_t)p * NC + dg] = (__bf16)acc[mi][ni][r];
            }
}

// ---------------------------------------------------------------------------
// H1: invn2[b][p] = 1/||y[:,p]||. grid(32, 8) block 256.
// ---------------------------------------------------------------------------
__global__ __launch_bounds__(256) void
ffnnorm_kernel(const bf16_t* __restrict__ y, float* __restrict__ invn2) {
    const int p0 = blockIdx.x * 128, b = blockIdx.y;
    const int t = threadIdx.x;
    const int p = p0 + (t & 127);
    const int obase = (t >> 7) * 256;
    const bf16_t* yb = y + (size_t)b * QSTRIDE;
    float s = 0.f;
    for (int o = 0; o < 256; ++o) {
        float v = (float)yb[(size_t)(obase + o) * NP + p];
        s += v * v;
    }
    __shared__ float sS[256];
    sS[t] = s;
    __syncthreads();
    if (t < 128)
        invn2[b * NP + p0 + t] = 1.0f / fmaxf(sqrtf(sS[t] + sS[t + 128]), 1e-12f);
}

// ---------------------------------------------------------------------------
// H2: out = y*invn2*g2*sqrtC + x (fp32 out). grid(1024, 8) block 256.
// ---------------------------------------------------------------------------
__global__ __launch_bounds__(256) void
final_kernel(const bf16_t* __restrict__ y, const float* __restrict__ invn2,
             const float* __restrict__ g2, const float* __restrict__ x,
             float* __restrict__ out) {
    const int b = blockIdx.y;
    int idx = blockIdx.x * 256 + threadIdx.x;      // [0, 262144)
    int o = idx >> 9;
    int p8 = (idx & 511) * 8;
    const bf16_t* yb = y + (size_t)b * QSTRIDE;
    const float* xb = x + (size_t)b * QSTRIDE;
    float* outb = out + (size_t)b * QSTRIDE;
    const float* inb = invn2 + (size_t)b * NP;

    bf8 yv = *(const bf8*)&yb[(size_t)o * NP + p8];
    float gv = g2[o] * SQRTC;
    float4 a = *(const float4*)&xb[(size_t)o * NP + p8];
    float4 b2 = *(const float4*)&xb[(size_t)o * NP + p8 + 4];

    float4 r0, r1;
    r0.x = (float)yv[0] * inb[p8 + 0] * gv + a.x;
    r0.y = (float)yv[1] * inb[p8 + 1] * gv + a.y;
    r0.z = (float)yv[2] * inb[p8 + 2] * gv + a.z;
    r0.w = (float)yv[3] * inb[p8 + 3] * gv + a.w;
    r1.x = (float)yv[4] * inb[p8 + 4] * gv + b2.x;
    r1.y = (float)yv[5] * inb[p8 + 5] * gv + b2.y;
    r1.z = (float)yv[6] * inb[p8 + 6] * gv + b2.z;
    r1.w = (float)yv[7] * inb[p8 + 7] * gv + b2.w;
    *(float4*)&outb[(size_t)o * NP + p8] = r0;
    *(float4*)&outb[(size_t)o * NP + p8 + 4] = r1;
}

// ---------------------------------------------------------------------------
extern "C" void kernel_launch(void* const* d_in, const int* in_sizes, int n_in,
                              void* d_out, int out_size, void* d_ws, size_t ws_size,
                              hipStream_t stream) {
    const float* x     = (const float*)d_in[0];
    const float* g     = (const float*)d_in[1];
    const float* qkv_w = (const float*)d_in[2];
    const float* ffn_w = (const float*)d_in[3];
    const float* ffn_b = (const float*)d_in[4];
    const float* ffn_g = (const float*)d_in[5];
    float* out = (float*)d_out;
    bf16_t* kv = (bf16_t*)d_out;     // 8*KVSTRIDE bf16 = 64 MiB (K,V then xoT)

    // workspace (~44.2 MB): attnP aliases xnT2 (disjoint lifetimes)
    bf16_t* q     = (bf16_t*)d_ws;                   // 8*QSTRIDE bf16 (Q, then y)
    bf16_t* xnT2  = q + 8 * QSTRIDE;                 // 2*QSTRIDE bf16 (chunk)
    float*  attnP = (float*)xnT2;                    // 64*8*4096 f32 = 8.39 MB
    bf16_t* Wg    = xnT2 + 2 * QSTRIDE;              // 786432 bf16
    bf16_t* Wf    = Wg + 786432;                     // 262144 bf16
    float*  kmax  = (float*)(Wf + 262144);           // 8*512 f32
    float*  kinv  = kmax + 8 * 512;                  // 8*512 f32
    float*  invn2 = kinv + 8 * 512;                  // 8*4096 f32

    wconv_kernel<<<dim3(768), 256, 0, stream>>>(qkv_w, g, Wg);
    wconv_kernel<<<dim3(256), 256, 0, stream>>>(ffn_w, nullptr, Wf);

    // chunked: normalize+transpose 2 batches, then their QKV GEMM
    for (int c = 0; c < 4; ++c) {
        norm_transpose_kernel<<<dim3(128, 2), 256, 0, stream>>>(
            x + (size_t)(2 * c) * QSTRIDE, xnT2);
        gemm_qkv_kernel<<<dim3(32, 12, 2), 256, 0, stream>>>(
            Wg, xnT2, q + (size_t)(2 * c) * QSTRIDE, kv + (size_t)(2 * c) * KVSTRIDE);
    }

    kstats_kernel<<<dim3(512, 8), 256, 0, stream>>>(kv, kmax, kinv);
    attn_kernel<<<dim3(8, 8, 8), 256, 0, stream>>>(kv, kmax, attnP);
    outgemm_kernel<<<dim3(32, 8, 8), 256, 0, stream>>>(q, attnP, kinv, kv);
    gemm_ffn_kernel<<<dim3(32, 4, 8), 256, 0, stream>>>(Wf, kv, ffn_b, q);
    ffnnorm_kernel<<<dim3(32, 8), 256, 0, stream>>>(q, invn2);
    final_kernel<<<dim3(1024, 8), 256, 0, stream>>>(q, invn2, ffn_g, x, out);
}

// Round 3
// 383.297 us; speedup vs baseline: 1.0361x; 1.0361x over previous
//
#include <hip/hip_runtime.h>

// ---------------------------------------------------------------------------
// MultiHeadsLinearAttention  (B=8, C=512, HEADS=8, CH=64, H=W=64 -> N=4096)
// Inputs fp32, output fp32. Compute: bf16 MFMA, fp32 accumulation.
//
// Stages:
//  W : Wg = qkv_w * g -> bf16 ; Wf = ffn_w -> bf16
//  T : per-token invx over fp32 x; xnT[p][c] = x*invx*sqrtC (bf16, k-contig)
//  C : QKV GEMM (128x128 tile, BK=64, global_load_lds width-16 LINEAR
//      staging): rows<512 -> Q (ws), else K,V (d_out)
//  D : k-softmax stats (kmax,kinv)
//  E : attnP[bh][ks][d][c] = sum_{p in ks-slice} exp(k[c][p]-kmax)*v[d][p]
//      (MFMA, wave-specialized over d -> ZERO atomics, zero LDS; 8 p-partials)
//  E2: attnsum: attnF[bh][d][c] = (sum_ks attnP) * kinv[c] -> bf16
//      (collapses the 8 partials ONCE; round-2 lesson: outgemm re-summed
//       them 32x -> 268 MB L2 traffic, 53us dispatch at 1.5% MfmaUtil)
//      attnF aliases dead Wg buffer.
//  F : q-softmax per token (wave-parallel, 8 lanes/token shfl-tree; was
//      t<128 serial 64-loop) ; xoT[b][p][hd] = qsm @ attnF
//      B-frags straight from L2-resident attnF (no LDS tile, loads hoisted)
//  G : FFN GEMM y = ffn_b + Wf @ xoT  (overwrites Q in ws)
//  H1: invn2 = 1/||y||  ;  H2: out = y*invn2*g2*sqrtC + x (fp32)
//
// Round-7 lesson: global_load_lds + XOR-SWIZZLE staging diverged after graph
// replay -> LINEAR destinations only (no swizzle, no padding, m173).
// Round-8 lesson: 8.4M contended global atomicAdds in attn = 175us wall ->
// partials + wave-specialization.
// NOTE: previous round's identical source hit "container failed twice"
// (infra acquisition error, no kernel signal) — resubmitted unchanged after
// a full correctness re-audit (indexing/alignment/aliasing all verified).
// ---------------------------------------------------------------------------

typedef __bf16 bf16_t;
typedef __bf16 bf8 __attribute__((ext_vector_type(8)));
typedef float f32x4 __attribute__((ext_vector_type(4)));

#define NC 512
#define NP 4096
#define SQRTC 22.62741699796952f
#define QSCALE 0.125f
#define QSTRIDE  ((size_t)NC * NP)      // 2097152  per-batch 512-row elems
#define KVSTRIDE ((size_t)1024 * NP)    // 4194304  per-batch kv elems (d_out)

__device__ inline unsigned short bfbits(__bf16 h) {
    return __builtin_bit_cast(unsigned short, h);
}

// async global->LDS, 16B per lane. LDS dest must be wave-uniform base;
// HW writes base + lane*16.
__device__ __forceinline__ void gload_lds16(const bf16_t* g, __bf16* l) {
    __builtin_amdgcn_global_load_lds(
        (const __attribute__((address_space(1))) void*)g,
        (__attribute__((address_space(3))) void*)l, 16, 0, 0);
}

// ---------------------------------------------------------------------------
// W: weight convert fp32->bf16, optional per-column scale g. 4 elems/thread.
// ---------------------------------------------------------------------------
__global__ __launch_bounds__(256) void
wconv_kernel(const float* __restrict__ w, const float* __restrict__ g,
             bf16_t* __restrict__ out) {
    int i0 = (blockIdx.x * 256 + threadIdx.x) * 4;
    float4 wv = *(const float4*)&w[i0];
    if (g) {
        const float4 gv = *(const float4*)&g[i0 & 511];
        wv.x *= gv.x; wv.y *= gv.y; wv.z *= gv.z; wv.w *= gv.w;
    }
    ushort4 o;
    o.x = bfbits((__bf16)wv.x);
    o.y = bfbits((__bf16)wv.y);
    o.z = bfbits((__bf16)wv.z);
    o.w = bfbits((__bf16)wv.w);
    *(ushort4*)&out[i0] = o;
}

// ---------------------------------------------------------------------------
// T: norm + transpose, 2 batches per launch. grid(128, 2) block 256.
// Block covers 32 tokens. xnT[p][c] = x[c][p] * sqrtC/max(||x[:,p]||,1e-12)
// ---------------------------------------------------------------------------
__global__ __launch_bounds__(256) void
norm_transpose_kernel(const float* __restrict__ x, bf16_t* __restrict__ xnT) {
    const int bl = blockIdx.y;
    const int p0 = blockIdx.x * 32;
    const int t = threadIdx.x;
    const float* xb = x + (size_t)bl * QSTRIDE;
    bf16_t* ob = xnT + (size_t)bl * QSTRIDE;

    // pass 1: sumsq — 8 threads per token, 64 c each
    const int pp = t & 31;
    const int ch = (t >> 5) * 64;
    float ss = 0.f;
    for (int c = 0; c < 64; ++c) {
        float v = xb[(size_t)(ch + c) * NP + p0 + pp];
        ss += v * v;
    }
    __shared__ float sS[8][32];
    __shared__ float sInv[32];
    sS[t >> 5][pp] = ss;
    __syncthreads();
    if (t < 32) {
        float tot = 0.f;
        #pragma unroll
        for (int j = 0; j < 8; ++j) tot += sS[j][t];
        sInv[t] = SQRTC / fmaxf(sqrtf(tot), 1e-12f);
    }
    __syncthreads();

    // pass 2: 32-c x 32-p chunks through LDS transpose
    __shared__ __bf16 sT[32][40];
    for (int cc = 0; cc < 512; cc += 32) {
        #pragma unroll
        for (int j = 0; j < 4; ++j) {
            int e = t + j * 256;                 // 1024 = 32c x 32p
            int cr = e >> 5, p = e & 31;
            sT[cr][p] = (__bf16)(xb[(size_t)(cc + cr) * NP + p0 + p] * sInv[p]);
        }
        __syncthreads();
        if (t < 128) {
            int p = t >> 2, c8 = (t & 3) * 8;
            bf8 v;
            #pragma unroll
            for (int q = 0; q < 8; ++q) v[q] = sT[c8 + q][p];
            *(bf8*)&ob[(size_t)(p0 + p) * NC + cc + c8] = v;
        }
        __syncthreads();
    }
}

// ---------------------------------------------------------------------------
// C: QKV GEMM. grid(32, 12, nb) block 256 (nb batches per launch).
// A = Wg [1536][512], B = xnT [p][c] (both k-contiguous bf16).
// 128x128 tile, BK=64, 4 waves of 64x64. global_load_lds linear staging.
// ---------------------------------------------------------------------------
__global__ __launch_bounds__(256) void
gemm_qkv_kernel(const bf16_t* __restrict__ Wg, const bf16_t* __restrict__ xnT,
                bf16_t* __restrict__ qout, bf16_t* __restrict__ kvout) {
    const int bn = blockIdx.x, bm = blockIdx.y, b = blockIdx.z;
    const int t = threadIdx.x;
    const int w = t >> 6, ln = t & 63, quad = ln >> 4, l16 = ln & 15;
    const int wm = w >> 1, wn = w & 1;

    __shared__ __align__(16) __bf16 sA[128 * 64];
    __shared__ __align__(16) __bf16 sB[128 * 64];

    f32x4 acc[4][4] = {};
    const bf16_t* Abase = Wg + (size_t)(bm * 128) * NC;
    const bf16_t* Bbase = xnT + (size_t)b * QSTRIDE + (size_t)(bn * 128) * NC;

    // per-lane source row/col within a 1024B chunk (8 rows x 64 k)
    const int lrow = ln >> 3;           // 0..7
    const int lkc = (ln & 7) * 8;       // k offset, 16B granules

    for (int kt = 0; kt < 8; ++kt) {
        const int k0 = kt * 64;
        #pragma unroll
        for (int i = 0; i < 4; ++i) {
            const int chunk = w * 4 + i;          // 0..15, wave-uniform
            const int row = chunk * 8 + lrow;
            gload_lds16(Abase + (size_t)row * NC + k0 + lkc, &sA[chunk * 512]);
            gload_lds16(Bbase + (size_t)row * NC + k0 + lkc, &sB[chunk * 512]);
        }
        __syncthreads();
        #pragma unroll
        for (int ks = 0; ks < 2; ++ks) {
            const int kk = ks * 32;
            bf8 af[4], bfr[4];
            #pragma unroll
            for (int mi = 0; mi < 4; ++mi)
                af[mi] = *(const bf8*)&sA[(wm * 64 + mi * 16 + l16) * 64 + kk + quad * 8];
            #pragma unroll
            for (int ni = 0; ni < 4; ++ni)
                bfr[ni] = *(const bf8*)&sB[(wn * 64 + ni * 16 + l16) * 64 + kk + quad * 8];
            #pragma unroll
            for (int mi = 0; mi < 4; ++mi)
                #pragma unroll
                for (int ni = 0; ni < 4; ++ni)
                    acc[mi][ni] = __builtin_amdgcn_mfma_f32_16x16x32_bf16(
                        af[mi], bfr[ni], acc[mi][ni], 0, 0, 0);
        }
        __syncthreads();
    }

    bf16_t* qb = qout + (size_t)b * QSTRIDE;
    bf16_t* kvb = kvout + (size_t)b * KVSTRIDE;
    const int p0 = bn * 128;
    #pragma unroll
    for (int ni = 0; ni < 4; ++ni) {
        const int colL = wn * 64 + ni * 16 + l16;
        #pragma unroll
        for (int mi = 0; mi < 4; ++mi) {
            #pragma unroll
            for (int r = 0; r < 4; ++r) {
                const int row = bm * 128 + wm * 64 + mi * 16 + quad * 4 + r;
                const __bf16 val = (__bf16)acc[mi][ni][r];
                if (row < 512)
                    qb[(size_t)row * NP + p0 + colL] = val;
                else
                    kvb[(size_t)(row - 512) * NP + p0 + colL] = val;
            }
        }
    }
}

// ---------------------------------------------------------------------------
// G: FFN GEMM. grid(32, 4, 8) block 256.
// A = Wf [512][512], B = xoT [p][c] (d_out K region), out y (+bias) -> ws.
// ---------------------------------------------------------------------------
__global__ __launch_bounds__(256) void
gemm_ffn_kernel(const bf16_t* __restrict__ Wf, const bf16_t* __restrict__ xoT,
                const float* __restrict__ bias, bf16_t* __restrict__ y) {
    const int bn = blockIdx.x, bm = blockIdx.y, b = blockIdx.z;
    const int t = threadIdx.x;
    const int w = t >> 6, ln = t & 63, quad = ln >> 4, l16 = ln & 15;
    const int wm = w >> 1, wn = w & 1;

    __shared__ __align__(16) __bf16 sA[128 * 64];
    __shared__ __align__(16) __bf16 sB[128 * 64];

    f32x4 acc[4][4] = {};
    const bf16_t* Abase = Wf + (size_t)(bm * 128) * NC;
    const bf16_t* Bbase = xoT + (size_t)b * KVSTRIDE + (size_t)(bn * 128) * NC;

    const int lrow = ln >> 3;
    const int lkc = (ln & 7) * 8;

    for (int kt = 0; kt < 8; ++kt) {
        const int k0 = kt * 64;
        #pragma unroll
        for (int i = 0; i < 4; ++i) {
            const int chunk = w * 4 + i;
            const int row = chunk * 8 + lrow;
            gload_lds16(Abase + (size_t)row * NC + k0 + lkc, &sA[chunk * 512]);
            gload_lds16(Bbase + (size_t)row * NC + k0 + lkc, &sB[chunk * 512]);
        }
        __syncthreads();
        #pragma unroll
        for (int ks = 0; ks < 2; ++ks) {
            const int kk = ks * 32;
            bf8 af[4], bfr[4];
            #pragma unroll
            for (int mi = 0; mi < 4; ++mi)
                af[mi] = *(const bf8*)&sA[(wm * 64 + mi * 16 + l16) * 64 + kk + quad * 8];
            #pragma unroll
            for (int ni = 0; ni < 4; ++ni)
                bfr[ni] = *(const bf8*)&sB[(wn * 64 + ni * 16 + l16) * 64 + kk + quad * 8];
            #pragma unroll
            for (int mi = 0; mi < 4; ++mi)
                #pragma unroll
                for (int ni = 0; ni < 4; ++ni)
                    acc[mi][ni] = __builtin_amdgcn_mfma_f32_16x16x32_bf16(
                        af[mi], bfr[ni], acc[mi][ni], 0, 0, 0);
        }
        __syncthreads();
    }

    bf16_t* yb = y + (size_t)b * QSTRIDE;
    const int p0 = bn * 128;
    #pragma unroll
    for (int mi = 0; mi < 4; ++mi) {
        #pragma unroll
        for (int ni = 0; ni < 4; ++ni) {
            const int col = p0 + wn * 64 + ni * 16 + l16;
            #pragma unroll
            for (int r = 0; r < 4; ++r) {
                const int row = bm * 128 + wm * 64 + mi * 16 + quad * 4 + r;
                float v = acc[mi][ni][r] + bias[row];
                yb[(size_t)row * NP + col] = (__bf16)v;
            }
        }
    }
}

// ---------------------------------------------------------------------------
// D: k-softmax stats per (b, channel) row. grid(512, 8) block 256.
// ---------------------------------------------------------------------------
__global__ __launch_bounds__(256) void
kstats_kernel(const bf16_t* __restrict__ kv, float* __restrict__ kmax,
              float* __restrict__ kinv) {
    const int oc = blockIdx.x, b = blockIdx.y;
    const int t = threadIdx.x, w = t >> 6, ln = t & 63;

    const bf16_t* row = kv + (size_t)b * KVSTRIDE + (size_t)oc * NP;
    float v[16];
    bf8 x0 = *(const bf8*)&row[t * 8];
    bf8 x1 = *(const bf8*)&row[2048 + t * 8];
    #pragma unroll
    for (int j = 0; j < 8; ++j) { v[j] = (float)x0[j]; v[8 + j] = (float)x1[j]; }

    float m = v[0];
    #pragma unroll
    for (int j = 1; j < 16; ++j) m = fmaxf(m, v[j]);
    #pragma unroll
    for (int off = 32; off > 0; off >>= 1) m = fmaxf(m, __shfl_down(m, off));
    __shared__ float sR[4];
    __shared__ float sS[4];
    if (ln == 0) sR[w] = m;
    __syncthreads();
    m = fmaxf(fmaxf(sR[0], sR[1]), fmaxf(sR[2], sR[3]));

    float s = 0.f;
    #pragma unroll
    for (int j = 0; j < 16; ++j) s += __expf(v[j] - m);
    #pragma unroll
    for (int off = 32; off > 0; off >>= 1) s += __shfl_down(s, off);
    if (ln == 0) sS[w] = s;
    __syncthreads();
    if (t == 0) {
        kmax[b * 512 + oc] = m;
        kinv[b * 512 + oc] = 1.0f / (sS[0] + sS[1] + sS[2] + sS[3]);
    }
}

// ---------------------------------------------------------------------------
// E: attnP[bh][ks][d][c] = sum_{p in slice} exp(k[c][p]-kmax[c]) * v[d][p].
// grid(8, 8, 8) block 256. Wave w owns d rows [w*16, w*16+16): no reduction,
// no atomics, no LDS. Each ks-slice covers 512 p (16 iters of 32 p).
// ---------------------------------------------------------------------------
__global__ __launch_bounds__(256) void
attn_kernel(const bf16_t* __restrict__ kv, const float* __restrict__ kmax,
            float* __restrict__ attnP) {
    const int h = blockIdx.x, ks = blockIdx.y, b = blockIdx.z;
    const int t = threadIdx.x, w = t >> 6, ln = t & 63, quad = ln >> 4, l16 = ln & 15;

    const bf16_t* Kb = kv + (size_t)b * KVSTRIDE + (size_t)(h * 64) * NP;
    const bf16_t* Vb = kv + (size_t)b * KVSTRIDE + (size_t)(512 + h * 64 + w * 16) * NP;

    float km[4];
    #pragma unroll
    for (int mi = 0; mi < 4; ++mi) km[mi] = kmax[b * 512 + h * 64 + mi * 16 + l16];

    f32x4 acc[4] = {};
    const int pbase = ks * 512 + quad * 8;
    #pragma unroll 4
    for (int it = 0; it < 16; ++it) {
        const int p0 = pbase + it * 32;
        bf8 bfr = *(const bf8*)&Vb[(size_t)l16 * NP + p0];
        #pragma unroll
        for (int mi = 0; mi < 4; ++mi) {
            bf8 kr = *(const bf8*)&Kb[(size_t)(mi * 16 + l16) * NP + p0];
            bf8 af;
            #pragma unroll
            for (int j = 0; j < 8; ++j)
                af[j] = (__bf16)__expf((float)kr[j] - km[mi]);
            acc[mi] = __builtin_amdgcn_mfma_f32_16x16x32_bf16(af, bfr, acc[mi], 0, 0, 0);
        }
    }

    // D layout: row (=c within mi-block) = quad*4+r, col (=d) = l16.
    float* outp = attnP + (((size_t)(b * 8 + h) * 8 + ks) << 12);
    #pragma unroll
    for (int mi = 0; mi < 4; ++mi) {
        float4 v;
        v.x = acc[mi][0]; v.y = acc[mi][1]; v.z = acc[mi][2]; v.w = acc[mi][3];
        *(float4*)&outp[(w * 16 + l16) * 64 + mi * 16 + quad * 4] = v;
    }
}

// ---------------------------------------------------------------------------
// E2: attnF[bh][d][c] = (sum_ks attnP[bh][ks][d][c]) * kinv[b][h*64+c] -> bf16
// grid(64, 4) block 256. Collapses the 8 p-partials ONCE (outgemm previously
// re-summed them 32x). attnF aliases dead Wg.
// ---------------------------------------------------------------------------
__global__ __launch_bounds__(256) void
attnsum_kernel(const float* __restrict__ attnP, const float* __restrict__ kinv,
               bf16_t* __restrict__ attnF) {
    const int bh = blockIdx.x;                     // b*8 + h
    const int e0 = blockIdx.y * 1024 + threadIdx.x * 4;
    const float* ap = attnP + ((size_t)bh << 15);  // 8 slices of 4096
    float4 s = {0.f, 0.f, 0.f, 0.f};
    #pragma unroll
    for (int ks = 0; ks < 8; ++ks) {
        float4 v = *(const float4*)&ap[(ks << 12) + e0];
        s.x += v.x; s.y += v.y; s.z += v.z; s.w += v.w;
    }
    const float* kvp = kinv + (bh >> 3) * 512 + (bh & 7) * 64;
    const int c = e0 & 63;
    ushort4 o;
    o.x = bfbits((__bf16)(s.x * kvp[c]));
    o.y = bfbits((__bf16)(s.y * kvp[c + 1]));
    o.z = bfbits((__bf16)(s.z * kvp[c + 2]));
    o.w = bfbits((__bf16)(s.w * kvp[c + 3]));
    *(ushort4*)&attnF[((size_t)bh << 12) + e0] = o;
}

// ---------------------------------------------------------------------------
// F: q softmax over ch (*SCALE) then xoT[p][h*64+d] = qsm @ attnF.
// grid(32, 8, 8) block 256. attnF B-frags direct from global (L2-resident,
// loads hoisted above the softmax). Softmax wave-parallel: 8 lanes/token,
// shfl_xor tree, all 256 threads busy. xoT overwrites dead K region of d_out.
// ---------------------------------------------------------------------------
__global__ __launch_bounds__(256) void
outgemm_kernel(const bf16_t* __restrict__ q, const bf16_t* __restrict__ attnF,
               bf16_t* __restrict__ xoT) {
    const int pt = blockIdx.x, h = blockIdx.y, b = blockIdx.z;
    const int p0 = pt * 128;
    const int t = threadIdx.x, w = t >> 6, ln = t & 63, quad = ln >> 4, l16 = ln & 15;

    __shared__ __align__(16) __bf16 sQb[128][72];   // [p][c], 18 KB

    // hoist B-fragment loads (L2-hot attnF) so latency hides under softmax
    const bf16_t* aF = attnF + ((size_t)(b * 8 + h) << 12);
    bf8 bfr[2][4];
    #pragma unroll
    for (int ksp = 0; ksp < 2; ++ksp)
        #pragma unroll
        for (int ni = 0; ni < 4; ++ni)
            bfr[ksp][ni] = *(const bf8*)&aF[(ni * 16 + l16) * 64 + ksp * 32 + quad * 8];

    const bf16_t* qb = q + (size_t)b * QSTRIDE;
    #pragma unroll
    for (int i = 0; i < 32; ++i) {
        int e = t + i * 256;             // c*128 + p
        int c = e >> 7, p = e & 127;
        sQb[p][c] = qb[(size_t)(h * 64 + c) * NP + p0 + p];
    }
    __syncthreads();

    // wave-parallel q-softmax: 8 lanes per token, 4 passes of 32 tokens
    #pragma unroll
    for (int pass = 0; pass < 4; ++pass) {
        const int tok = pass * 32 + (t >> 3);
        const int c8 = (t & 7) * 8;
        bf8 v = *(const bf8*)&sQb[tok][c8];
        float f[8];
        #pragma unroll
        for (int j = 0; j < 8; ++j) f[j] = (float)v[j];
        float m = f[0];
        #pragma unroll
        for (int j = 1; j < 8; ++j) m = fmaxf(m, f[j]);
        #pragma unroll
        for (int off = 1; off < 8; off <<= 1) m = fmaxf(m, __shfl_xor(m, off));
        float s = 0.f;
        #pragma unroll
        for (int j = 0; j < 8; ++j) { f[j] = __expf(f[j] - m); s += f[j]; }
        #pragma unroll
        for (int off = 1; off < 8; off <<= 1) s += __shfl_xor(s, off);
        const float inv = QSCALE / s;
        #pragma unroll
        for (int j = 0; j < 8; ++j) v[j] = (__bf16)(f[j] * inv);
        *(bf8*)&sQb[tok][c8] = v;
    }
    __syncthreads();

    f32x4 acc[2][4] = {};
    #pragma unroll
    for (int ksp = 0; ksp < 2; ++ksp) {
        const int kk = ksp * 32;
        bf8 af[2];
        #pragma unroll
        for (int mi = 0; mi < 2; ++mi)
            af[mi] = *(const bf8*)&sQb[w * 32 + mi * 16 + l16][kk + quad * 8];
        #pragma unroll
        for (int mi = 0; mi < 2; ++mi)
            #pragma unroll
            for (int ni = 0; ni < 4; ++ni)
                acc[mi][ni] = __builtin_amdgcn_mfma_f32_16x16x32_bf16(
                    af[mi], bfr[ksp][ni], acc[mi][ni], 0, 0, 0);
    }
    bf16_t* xob = xoT + (size_t)b * KVSTRIDE;
    #pragma unroll
    for (int mi = 0; mi < 2; ++mi)
        #pragma unroll
        for (int ni = 0; ni < 4; ++ni)
            #pragma unroll
            for (int r = 0; r < 4; ++r) {
                int p = p0 + w * 32 + mi * 16 + quad * 4 + r;
                int dg = h * 64 + ni * 16 + l16;
                xob[(size_t)p * NC + dg] = (__bf16)acc[mi][ni][r];
            }
}

// ---------------------------------------------------------------------------
// H1: invn2[b][p] = 1/||y[:,p]||. grid(32, 8) block 256.
// ---------------------------------------------------------------------------
__global__ __launch_bounds__(256) void
ffnnorm_kernel(const bf16_t* __restrict__ y, float* __restrict__ invn2) {
    const int p0 = blockIdx.x * 128, b = blockIdx.y;
    const int t = threadIdx.x;
    const int p = p0 + (t & 127);
    const int obase = (t >> 7) * 256;
    const bf16_t* yb = y + (size_t)b * QSTRIDE;
    float s = 0.f;
    for (int o = 0; o < 256; ++o) {
        float v = (float)yb[(size_t)(obase + o) * NP + p];
        s += v * v;
    }
    __shared__ float sS[256];
    sS[t] = s;
    __syncthreads();
    if (t < 128)
        invn2[b * NP + p0 + t] = 1.0f / fmaxf(sqrtf(sS[t] + sS[t + 128]), 1e-12f);
}

// ---------------------------------------------------------------------------
// H2: out = y*invn2*g2*sqrtC + x (fp32 out). grid(1024, 8) block 256.
// ---------------------------------------------------------------------------
__global__ __launch_bounds__(256) void
final_kernel(const bf16_t* __restrict__ y, const float* __restrict__ invn2,
             const float* __restrict__ g2, const float* __restrict__ x,
             float* __restrict__ out) {
    const int b = blockIdx.y;
    int idx = blockIdx.x * 256 + threadIdx.x;      // [0, 262144)
    int o = idx >> 9;
    int p8 = (idx & 511) * 8;
    const bf16_t* yb = y + (size_t)b * QSTRIDE;
    const float* xb = x + (size_t)b * QSTRIDE;
    float* outb = out + (size_t)b * QSTRIDE;
    const float* inb = invn2 + (size_t)b * NP;

    bf8 yv = *(const bf8*)&yb[(size_t)o * NP + p8];
    float gv = g2[o] * SQRTC;
    float4 a = *(const float4*)&xb[(size_t)o * NP + p8];
    float4 b2 = *(const float4*)&xb[(size_t)o * NP + p8 + 4];

    float4 r0, r1;
    r0.x = (float)yv[0] * inb[p8 + 0] * gv + a.x;
    r0.y = (float)yv[1] * inb[p8 + 1] * gv + a.y;
    r0.z = (float)yv[2] * inb[p8 + 2] * gv + a.z;
    r0.w = (float)yv[3] * inb[p8 + 3] * gv + a.w;
    r1.x = (float)yv[4] * inb[p8 + 4] * gv + b2.x;
    r1.y = (float)yv[5] * inb[p8 + 5] * gv + b2.y;
    r1.z = (float)yv[6] * inb[p8 + 6] * gv + b2.z;
    r1.w = (float)yv[7] * inb[p8 + 7] * gv + b2.w;
    *(float4*)&outb[(size_t)o * NP + p8] = r0;
    *(float4*)&outb[(size_t)o * NP + p8 + 4] = r1;
}

// ---------------------------------------------------------------------------
extern "C" void kernel_launch(void* const* d_in, const int* in_sizes, int n_in,
                              void* d_out, int out_size, void* d_ws, size_t ws_size,
                              hipStream_t stream) {
    const float* x     = (const float*)d_in[0];
    const float* g     = (const float*)d_in[1];
    const float* qkv_w = (const float*)d_in[2];
    const float* ffn_w = (const float*)d_in[3];
    const float* ffn_b = (const float*)d_in[4];
    const float* ffn_g = (const float*)d_in[5];
    float* out = (float*)d_out;
    bf16_t* kv = (bf16_t*)d_out;     // 8*KVSTRIDE bf16 = 64 MiB (K,V then xoT)

    // workspace (~44.2 MB): attnP aliases xnT2; attnF aliases dead Wg
    bf16_t* q     = (bf16_t*)d_ws;                   // 8*QSTRIDE bf16 (Q, then y)
    bf16_t* xnT2  = q + 8 * QSTRIDE;                 // 2*QSTRIDE bf16 (chunk)
    float*  attnP = (float*)xnT2;                    // 64*8*4096 f32 = 8.39 MB
    bf16_t* Wg    = xnT2 + 2 * QSTRIDE;              // 786432 bf16
    bf16_t* attnF = Wg;                              // 64*4096 bf16 = 512 KB
    bf16_t* Wf    = Wg + 786432;                     // 262144 bf16
    float*  kmax  = (float*)(Wf + 262144);           // 8*512 f32
    float*  kinv  = kmax + 8 * 512;                  // 8*512 f32
    float*  invn2 = kinv + 8 * 512;                  // 8*4096 f32

    wconv_kernel<<<dim3(768), 256, 0, stream>>>(qkv_w, g, Wg);
    wconv_kernel<<<dim3(256), 256, 0, stream>>>(ffn_w, nullptr, Wf);

    // chunked: normalize+transpose 2 batches, then their QKV GEMM
    for (int c = 0; c < 4; ++c) {
        norm_transpose_kernel<<<dim3(128, 2), 256, 0, stream>>>(
            x + (size_t)(2 * c) * QSTRIDE, xnT2);
        gemm_qkv_kernel<<<dim3(32, 12, 2), 256, 0, stream>>>(
            Wg, xnT2, q + (size_t)(2 * c) * QSTRIDE, kv + (size_t)(2 * c) * KVSTRIDE);
    }

    kstats_kernel<<<dim3(512, 8), 256, 0, stream>>>(kv, kmax, kinv);
    attn_kernel<<<dim3(8, 8, 8), 256, 0, stream>>>(kv, kmax, attnP);
    attnsum_kernel<<<dim3(64, 4), 256, 0, stream>>>(attnP, kinv, attnF);
    outgemm_kernel<<<dim3(32, 8, 8), 256, 0, stream>>>(q, attnF, kv);
    gemm_ffn_kernel<<<dim3(32, 4, 8), 256, 0, stream>>>(Wf, kv, ffn_b, q);
    ffnnorm_kernel<<<dim3(32, 8), 256, 0, stream>>>(q, invn2);
    final_kernel<<<dim3(1024, 8), 256, 0, stream>>>(q, invn2, ffn_g, x, out);
}

// Round 4
// 363.261 us; speedup vs baseline: 1.0932x; 1.0552x over previous
//
#include <hip/hip_runtime.h>

// ---------------------------------------------------------------------------
// MultiHeadsLinearAttention  (B=8, C=512, HEADS=8, CH=64, H=W=64 -> N=4096)
// Inputs fp32, output fp32. Compute: bf16 MFMA, fp32 accumulation.
//
// Stages:
//  W : Wg = qkv_w * g -> bf16 ; Wf = ffn_w -> bf16 (single merged launch)
//  T : per-token invx over fp32 x; xnT[p][c] = x*invx*sqrtC (bf16, k-contig)
//      v2: 512 thr (8 waves/CU), float4 pass-1 + shfl tree, 64-row pass-2
//  C : QKV GEMM (128x128 tile, BK=64, global_load_lds width-16 LINEAR
//      staging): rows<512 -> Q (ws), else K,V (d_out)
//  D : k-softmax stats (kmax,kinv)
//  E : attnP[bh][ks][d][c] = sum_{p in ks-slice} exp(k[c][p]-kmax)*v[d][p]
//      (MFMA, wave-specialized over d -> ZERO atomics, zero LDS; 8 p-partials)
//  E2: attnsum: attnF[bh][d][c] = (sum_ks attnP) * kinv[c] -> bf16
//      (+ zeroes ysq for the FFN epilogue accumulation)
//  F : q-softmax per token (wave-parallel 8-lane shfl) ; xoT = qsm @ attnF
//  G : FFN GEMM y = ffn_b + Wf @ xoT ; epilogue accumulates per-column
//      sumsq of bf16-rounded y into ysq (shfl-reduced, 1 atomic/col/2waves)
//      -> replaces the separate 32 MB ffnnorm pass
//  H : out = y/max(sqrt(ysq),eps)*g2*sqrtC + x (fp32)
//
// Round-7 lesson: global_load_lds + XOR-SWIZZLE staging diverged after graph
// replay -> LINEAR destinations only (no swizzle, no padding, m173).
// Round-8 lesson: 8.4M contended global atomicAdds in attn = 175us wall ->
// partials + wave-specialization.
// Round-R1 lesson: outgemm re-summed attnP 32x (53us @ 1.5% MfmaUtil) ->
// attnsum collapses once.
// ---------------------------------------------------------------------------

typedef __bf16 bf16_t;
typedef __bf16 bf8 __attribute__((ext_vector_type(8)));
typedef float f32x4 __attribute__((ext_vector_type(4)));

#define NC 512
#define NP 4096
#define SQRTC 22.62741699796952f
#define QSCALE 0.125f
#define QSTRIDE  ((size_t)NC * NP)      // 2097152  per-batch 512-row elems
#define KVSTRIDE ((size_t)1024 * NP)    // 4194304  per-batch kv elems (d_out)

__device__ inline unsigned short bfbits(__bf16 h) {
    return __builtin_bit_cast(unsigned short, h);
}

// async global->LDS, 16B per lane. LDS dest must be wave-uniform base;
// HW writes base + lane*16.
__device__ __forceinline__ void gload_lds16(const bf16_t* g, __bf16* l) {
    __builtin_amdgcn_global_load_lds(
        (const __attribute__((address_space(1))) void*)g,
        (__attribute__((address_space(3))) void*)l, 16, 0, 0);
}

// ---------------------------------------------------------------------------
// W: both weight converts in one launch. blocks 0..767: Wg = qkv_w * g;
// blocks 768..1023: Wf = ffn_w. 4 elems/thread.
// ---------------------------------------------------------------------------
__global__ __launch_bounds__(256) void
wconv_kernel(const float* __restrict__ qkv_w, const float* __restrict__ g,
             const float* __restrict__ ffn_w, bf16_t* __restrict__ Wg,
             bf16_t* __restrict__ Wf) {
    const int bx = blockIdx.x;
    if (bx < 768) {
        int i0 = (bx * 256 + threadIdx.x) * 4;
        float4 wv = *(const float4*)&qkv_w[i0];
        const float4 gv = *(const float4*)&g[i0 & 511];
        ushort4 o;
        o.x = bfbits((__bf16)(wv.x * gv.x));
        o.y = bfbits((__bf16)(wv.y * gv.y));
        o.z = bfbits((__bf16)(wv.z * gv.z));
        o.w = bfbits((__bf16)(wv.w * gv.w));
        *(ushort4*)&Wg[i0] = o;
    } else {
        int i0 = ((bx - 768) * 256 + threadIdx.x) * 4;
        float4 wv = *(const float4*)&ffn_w[i0];
        ushort4 o;
        o.x = bfbits((__bf16)wv.x);
        o.y = bfbits((__bf16)wv.y);
        o.z = bfbits((__bf16)wv.z);
        o.w = bfbits((__bf16)wv.w);
        *(ushort4*)&Wf[i0] = o;
    }
}

// ---------------------------------------------------------------------------
// T v2: norm + transpose, 2 batches per launch. grid(128, 2) block 512.
// Block covers 32 tokens. xnT[p][c] = x[c][p] * sqrtC/max(||x[:,p]||,1e-12)
// pass 1: float4 coalesced sumsq (8 loads/thread), shfl_xor tree over the
//         64 threads sharing a 4-token column group, LDS cross-wave finish.
// pass 2: 64-c x 32-p chunks through LDS transpose (8 iters, 16 barriers).
// 2nd x read is L3-resident (chunk read moments earlier) -> no HBM cost.
// ---------------------------------------------------------------------------
__global__ __launch_bounds__(512) void
norm_transpose_kernel(const float* __restrict__ x, bf16_t* __restrict__ xnT) {
    const int bl = blockIdx.y;
    const int p0 = blockIdx.x * 32;
    const int t = threadIdx.x;
    const float* xb = x + (size_t)bl * QSTRIDE;
    bf16_t* ob = xnT + (size_t)bl * QSTRIDE;

    // pass 1: thread (cg = t&7, r0 = t>>3) accumulates x^2 for tokens
    // [p0 + cg*4, +4) over rows {r0 + 64k}. Wave w covers rows == [8w,8w+8) mod 64.
    const int cg = t & 7, r0 = t >> 3;
    f32x4 ss = {0.f, 0.f, 0.f, 0.f};
    #pragma unroll
    for (int k = 0; k < 8; ++k) {
        const int c = r0 + k * 64;
        float4 v = *(const float4*)&xb[(size_t)c * NP + p0 + cg * 4];
        ss.x += v.x * v.x; ss.y += v.y * v.y;
        ss.z += v.z * v.z; ss.w += v.w * v.w;
    }
    // butterfly over lane bits 3..5: sums the 8 r0-values within the wave
    #pragma unroll
    for (int m = 8; m <= 32; m <<= 1) {
        ss.x += __shfl_xor(ss.x, m); ss.y += __shfl_xor(ss.y, m);
        ss.z += __shfl_xor(ss.z, m); ss.w += __shfl_xor(ss.w, m);
    }
    __shared__ float sP[8][34];
    __shared__ float sInv[32];
    const int w = t >> 6;
    if ((t & 63) < 8) {
        const int p = (t & 7) * 4;
        sP[w][p] = ss.x; sP[w][p + 1] = ss.y;
        sP[w][p + 2] = ss.z; sP[w][p + 3] = ss.w;
    }
    __syncthreads();
    if (t < 32) {
        float tot = 0.f;
        #pragma unroll
        for (int j = 0; j < 8; ++j) tot += sP[j][t];
        sInv[t] = SQRTC / fmaxf(sqrtf(tot), 1e-12f);
    }
    __syncthreads();

    // pass 2: 64-c x 32-p chunks through LDS transpose
    __shared__ __bf16 sT[64][40];
    for (int cc = 0; cc < 512; cc += 64) {
        #pragma unroll
        for (int j = 0; j < 4; ++j) {
            int e = t + j * 512;                 // 2048 = 64c x 32p
            int cr = e >> 5, p = e & 31;
            sT[cr][p] = (__bf16)(xb[(size_t)(cc + cr) * NP + p0 + p] * sInv[p]);
        }
        __syncthreads();
        if (t < 256) {
            int p = t >> 3, c8 = (t & 7) * 8;
            bf8 v;
            #pragma unroll
            for (int q = 0; q < 8; ++q) v[q] = sT[c8 + q][p];
            *(bf8*)&ob[(size_t)(p0 + p) * NC + cc + c8] = v;
        }
        __syncthreads();
    }
}

// ---------------------------------------------------------------------------
// C: QKV GEMM. grid(32, 12, nb) block 256 (nb batches per launch).
// A = Wg [1536][512], B = xnT [p][c] (both k-contiguous bf16).
// 128x128 tile, BK=64, 4 waves of 64x64. global_load_lds linear staging.
// ---------------------------------------------------------------------------
__global__ __launch_bounds__(256) void
gemm_qkv_kernel(const bf16_t* __restrict__ Wg, const bf16_t* __restrict__ xnT,
                bf16_t* __restrict__ qout, bf16_t* __restrict__ kvout) {
    const int bn = blockIdx.x, bm = blockIdx.y, b = blockIdx.z;
    const int t = threadIdx.x;
    const int w = t >> 6, ln = t & 63, quad = ln >> 4, l16 = ln & 15;
    const int wm = w >> 1, wn = w & 1;

    __shared__ __align__(16) __bf16 sA[128 * 64];
    __shared__ __align__(16) __bf16 sB[128 * 64];

    f32x4 acc[4][4] = {};
    const bf16_t* Abase = Wg + (size_t)(bm * 128) * NC;
    const bf16_t* Bbase = xnT + (size_t)b * QSTRIDE + (size_t)(bn * 128) * NC;

    // per-lane source row/col within a 1024B chunk (8 rows x 64 k)
    const int lrow = ln >> 3;           // 0..7
    const int lkc = (ln & 7) * 8;       // k offset, 16B granules

    for (int kt = 0; kt < 8; ++kt) {
        const int k0 = kt * 64;
        #pragma unroll
        for (int i = 0; i < 4; ++i) {
            const int chunk = w * 4 + i;          // 0..15, wave-uniform
            const int row = chunk * 8 + lrow;
            gload_lds16(Abase + (size_t)row * NC + k0 + lkc, &sA[chunk * 512]);
            gload_lds16(Bbase + (size_t)row * NC + k0 + lkc, &sB[chunk * 512]);
        }
        __syncthreads();
        #pragma unroll
        for (int ks = 0; ks < 2; ++ks) {
            const int kk = ks * 32;
            bf8 af[4], bfr[4];
            #pragma unroll
            for (int mi = 0; mi < 4; ++mi)
                af[mi] = *(const bf8*)&sA[(wm * 64 + mi * 16 + l16) * 64 + kk + quad * 8];
            #pragma unroll
            for (int ni = 0; ni < 4; ++ni)
                bfr[ni] = *(const bf8*)&sB[(wn * 64 + ni * 16 + l16) * 64 + kk + quad * 8];
            #pragma unroll
            for (int mi = 0; mi < 4; ++mi)
                #pragma unroll
                for (int ni = 0; ni < 4; ++ni)
                    acc[mi][ni] = __builtin_amdgcn_mfma_f32_16x16x32_bf16(
                        af[mi], bfr[ni], acc[mi][ni], 0, 0, 0);
        }
        __syncthreads();
    }

    bf16_t* qb = qout + (size_t)b * QSTRIDE;
    bf16_t* kvb = kvout + (size_t)b * KVSTRIDE;
    const int p0 = bn * 128;
    #pragma unroll
    for (int ni = 0; ni < 4; ++ni) {
        const int colL = wn * 64 + ni * 16 + l16;
        #pragma unroll
        for (int mi = 0; mi < 4; ++mi) {
            #pragma unroll
            for (int r = 0; r < 4; ++r) {
                const int row = bm * 128 + wm * 64 + mi * 16 + quad * 4 + r;
                const __bf16 val = (__bf16)acc[mi][ni][r];
                if (row < 512)
                    qb[(size_t)row * NP + p0 + colL] = val;
                else
                    kvb[(size_t)(row - 512) * NP + p0 + colL] = val;
            }
        }
    }
}

// ---------------------------------------------------------------------------
// G: FFN GEMM. grid(32, 4, 8) block 256.
// A = Wf [512][512], B = xoT [p][c] (d_out K region), out y (+bias) -> ws.
// Epilogue: per-column sumsq of bf16-rounded y accumulated into ysq
// (shfl-reduced over quad pairs; one atomicAdd per col per 2 waves).
// ---------------------------------------------------------------------------
__global__ __launch_bounds__(256) void
gemm_ffn_kernel(const bf16_t* __restrict__ Wf, const bf16_t* __restrict__ xoT,
                const float* __restrict__ bias, bf16_t* __restrict__ y,
                float* __restrict__ ysq) {
    const int bn = blockIdx.x, bm = blockIdx.y, b = blockIdx.z;
    const int t = threadIdx.x;
    const int w = t >> 6, ln = t & 63, quad = ln >> 4, l16 = ln & 15;
    const int wm = w >> 1, wn = w & 1;

    __shared__ __align__(16) __bf16 sA[128 * 64];
    __shared__ __align__(16) __bf16 sB[128 * 64];

    f32x4 acc[4][4] = {};
    const bf16_t* Abase = Wf + (size_t)(bm * 128) * NC;
    const bf16_t* Bbase = xoT + (size_t)b * KVSTRIDE + (size_t)(bn * 128) * NC;

    const int lrow = ln >> 3;
    const int lkc = (ln & 7) * 8;

    for (int kt = 0; kt < 8; ++kt) {
        const int k0 = kt * 64;
        #pragma unroll
        for (int i = 0; i < 4; ++i) {
            const int chunk = w * 4 + i;
            const int row = chunk * 8 + lrow;
            gload_lds16(Abase + (size_t)row * NC + k0 + lkc, &sA[chunk * 512]);
            gload_lds16(Bbase + (size_t)row * NC + k0 + lkc, &sB[chunk * 512]);
        }
        __syncthreads();
        #pragma unroll
        for (int ks = 0; ks < 2; ++ks) {
            const int kk = ks * 32;
            bf8 af[4], bfr[4];
            #pragma unroll
            for (int mi = 0; mi < 4; ++mi)
                af[mi] = *(const bf8*)&sA[(wm * 64 + mi * 16 + l16) * 64 + kk + quad * 8];
            #pragma unroll
            for (int ni = 0; ni < 4; ++ni)
                bfr[ni] = *(const bf8*)&sB[(wn * 64 + ni * 16 + l16) * 64 + kk + quad * 8];
            #pragma unroll
            for (int mi = 0; mi < 4; ++mi)
                #pragma unroll
                for (int ni = 0; ni < 4; ++ni)
                    acc[mi][ni] = __builtin_amdgcn_mfma_f32_16x16x32_bf16(
                        af[mi], bfr[ni], acc[mi][ni], 0, 0, 0);
        }
        __syncthreads();
    }

    bf16_t* yb = y + (size_t)b * QSTRIDE;
    float* sq = ysq + (size_t)b * NP;
    const int p0 = bn * 128;
    #pragma unroll
    for (int ni = 0; ni < 4; ++ni) {
        const int col = p0 + wn * 64 + ni * 16 + l16;
        float colsq = 0.f;
        #pragma unroll
        for (int mi = 0; mi < 4; ++mi) {
            #pragma unroll
            for (int r = 0; r < 4; ++r) {
                const int row = bm * 128 + wm * 64 + mi * 16 + quad * 4 + r;
                float v = acc[mi][ni][r] + bias[row];
                __bf16 vb = (__bf16)v;
                yb[(size_t)row * NP + col] = vb;
                float vf = (float)vb;
                colsq += vf * vf;
            }
        }
        // sum the 4 quads of this wave (lanes l16, +16, +32, +48)
        colsq += __shfl_xor(colsq, 16);
        colsq += __shfl_xor(colsq, 32);
        if (quad == 0) atomicAdd(&sq[col], colsq);
    }
}

// ---------------------------------------------------------------------------
// D: k-softmax stats per (b, channel) row. grid(512, 8) block 256.
// ---------------------------------------------------------------------------
__global__ __launch_bounds__(256) void
kstats_kernel(const bf16_t* __restrict__ kv, float* __restrict__ kmax,
              float* __restrict__ kinv) {
    const int oc = blockIdx.x, b = blockIdx.y;
    const int t = threadIdx.x, w = t >> 6, ln = t & 63;

    const bf16_t* row = kv + (size_t)b * KVSTRIDE + (size_t)oc * NP;
    float v[16];
    bf8 x0 = *(const bf8*)&row[t * 8];
    bf8 x1 = *(const bf8*)&row[2048 + t * 8];
    #pragma unroll
    for (int j = 0; j < 8; ++j) { v[j] = (float)x0[j]; v[8 + j] = (float)x1[j]; }

    float m = v[0];
    #pragma unroll
    for (int j = 1; j < 16; ++j) m = fmaxf(m, v[j]);
    #pragma unroll
    for (int off = 32; off > 0; off >>= 1) m = fmaxf(m, __shfl_down(m, off));
    __shared__ float sR[4];
    __shared__ float sS[4];
    if (ln == 0) sR[w] = m;
    __syncthreads();
    m = fmaxf(fmaxf(sR[0], sR[1]), fmaxf(sR[2], sR[3]));

    float s = 0.f;
    #pragma unroll
    for (int j = 0; j < 16; ++j) s += __expf(v[j] - m);
    #pragma unroll
    for (int off = 32; off > 0; off >>= 1) s += __shfl_down(s, off);
    if (ln == 0) sS[w] = s;
    __syncthreads();
    if (t == 0) {
        kmax[b * 512 + oc] = m;
        kinv[b * 512 + oc] = 1.0f / (sS[0] + sS[1] + sS[2] + sS[3]);
    }
}

// ---------------------------------------------------------------------------
// E: attnP[bh][ks][d][c] = sum_{p in slice} exp(k[c][p]-kmax[c]) * v[d][p].
// grid(8, 8, 8) block 256. Wave w owns d rows [w*16, w*16+16): no reduction,
// no atomics, no LDS. Each ks-slice covers 512 p (16 iters of 32 p).
// ---------------------------------------------------------------------------
__global__ __launch_bounds__(256) void
attn_kernel(const bf16_t* __restrict__ kv, const float* __restrict__ kmax,
            float* __restrict__ attnP) {
    const int h = blockIdx.x, ks = blockIdx.y, b = blockIdx.z;
    const int t = threadIdx.x, w = t >> 6, ln = t & 63, quad = ln >> 4, l16 = ln & 15;

    const bf16_t* Kb = kv + (size_t)b * KVSTRIDE + (size_t)(h * 64) * NP;
    const bf16_t* Vb = kv + (size_t)b * KVSTRIDE + (size_t)(512 + h * 64 + w * 16) * NP;

    float km[4];
    #pragma unroll
    for (int mi = 0; mi < 4; ++mi) km[mi] = kmax[b * 512 + h * 64 + mi * 16 + l16];

    f32x4 acc[4] = {};
    const int pbase = ks * 512 + quad * 8;
    #pragma unroll 4
    for (int it = 0; it < 16; ++it) {
        const int p0 = pbase + it * 32;
        bf8 bfr = *(const bf8*)&Vb[(size_t)l16 * NP + p0];
        #pragma unroll
        for (int mi = 0; mi < 4; ++mi) {
            bf8 kr = *(const bf8*)&Kb[(size_t)(mi * 16 + l16) * NP + p0];
            bf8 af;
            #pragma unroll
            for (int j = 0; j < 8; ++j)
                af[j] = (__bf16)__expf((float)kr[j] - km[mi]);
            acc[mi] = __builtin_amdgcn_mfma_f32_16x16x32_bf16(af, bfr, acc[mi], 0, 0, 0);
        }
    }

    // D layout: row (=c within mi-block) = quad*4+r, col (=d) = l16.
    float* outp = attnP + (((size_t)(b * 8 + h) * 8 + ks) << 12);
    #pragma unroll
    for (int mi = 0; mi < 4; ++mi) {
        float4 v;
        v.x = acc[mi][0]; v.y = acc[mi][1]; v.z = acc[mi][2]; v.w = acc[mi][3];
        *(float4*)&outp[(w * 16 + l16) * 64 + mi * 16 + quad * 4] = v;
    }
}

// ---------------------------------------------------------------------------
// E2: attnF[bh][d][c] = (sum_ks attnP[bh][ks][d][c]) * kinv[b][h*64+c] -> bf16
// grid(64, 4) block 256. Collapses the 8 p-partials ONCE. attnF aliases dead
// Wg. Also zeroes ysq (stream-ordered before gemm_ffn's accumulation).
// ---------------------------------------------------------------------------
__global__ __launch_bounds__(256) void
attnsum_kernel(const float* __restrict__ attnP, const float* __restrict__ kinv,
               bf16_t* __restrict__ attnF, float* __restrict__ ysq) {
    const int gtid = (blockIdx.x * 4 + blockIdx.y) * 256 + threadIdx.x;
    if (gtid < 8 * NP) ysq[gtid] = 0.f;

    const int bh = blockIdx.x;                     // b*8 + h
    const int e0 = blockIdx.y * 1024 + threadIdx.x * 4;
    const float* ap = attnP + ((size_t)bh << 15);  // 8 slices of 4096
    float4 s = {0.f, 0.f, 0.f, 0.f};
    #pragma unroll
    for (int ks = 0; ks < 8; ++ks) {
        float4 v = *(const float4*)&ap[(ks << 12) + e0];
        s.x += v.x; s.y += v.y; s.z += v.z; s.w += v.w;
    }
    const float* kvp = kinv + (bh >> 3) * 512 + (bh & 7) * 64;
    const int c = e0 & 63;
    ushort4 o;
    o.x = bfbits((__bf16)(s.x * kvp[c]));
    o.y = bfbits((__bf16)(s.y * kvp[c + 1]));
    o.z = bfbits((__bf16)(s.z * kvp[c + 2]));
    o.w = bfbits((__bf16)(s.w * kvp[c + 3]));
    *(ushort4*)&attnF[((size_t)bh << 12) + e0] = o;
}

// ---------------------------------------------------------------------------
// F: q softmax over ch (*SCALE) then xoT[p][h*64+d] = qsm @ attnF.
// grid(32, 8, 8) block 256. attnF B-frags direct from global (L2-resident,
// loads hoisted above the softmax). Softmax wave-parallel: 8 lanes/token,
// shfl_xor tree, all 256 threads busy. xoT overwrites dead K region of d_out.
// ---------------------------------------------------------------------------
__global__ __launch_bounds__(256) void
outgemm_kernel(const bf16_t* __restrict__ q, const bf16_t* __restrict__ attnF,
               bf16_t* __restrict__ xoT) {
    const int pt = blockIdx.x, h = blockIdx.y, b = blockIdx.z;
    const int p0 = pt * 128;
    const int t = threadIdx.x, w = t >> 6, ln = t & 63, quad = ln >> 4, l16 = ln & 15;

    __shared__ __align__(16) __bf16 sQb[128][72];   // [p][c], 18 KB

    // hoist B-fragment loads (L2-hot attnF) so latency hides under softmax
    const bf16_t* aF = attnF + ((size_t)(b * 8 + h) << 12);
    bf8 bfr[2][4];
    #pragma unroll
    for (int ksp = 0; ksp < 2; ++ksp)
        #pragma unroll
        for (int ni = 0; ni < 4; ++ni)
            bfr[ksp][ni] = *(const bf8*)&aF[(ni * 16 + l16) * 64 + ksp * 32 + quad * 8];

    const bf16_t* qb = q + (size_t)b * QSTRIDE;
    #pragma unroll
    for (int i = 0; i < 32; ++i) {
        int e = t + i * 256;             // c*128 + p
        int c = e >> 7, p = e & 127;
        sQb[p][c] = qb[(size_t)(h * 64 + c) * NP + p0 + p];
    }
    __syncthreads();

    // wave-parallel q-softmax: 8 lanes per token, 4 passes of 32 tokens
    #pragma unroll
    for (int pass = 0; pass < 4; ++pass) {
        const int tok = pass * 32 + (t >> 3);
        const int c8 = (t & 7) * 8;
        bf8 v = *(const bf8*)&sQb[tok][c8];
        float f[8];
        #pragma unroll
        for (int j = 0; j < 8; ++j) f[j] = (float)v[j];
        float m = f[0];
        #pragma unroll
        for (int j = 1; j < 8; ++j) m = fmaxf(m, f[j]);
        #pragma unroll
        for (int off = 1; off < 8; off <<= 1) m = fmaxf(m, __shfl_xor(m, off));
        float s = 0.f;
        #pragma unroll
        for (int j = 0; j < 8; ++j) { f[j] = __expf(f[j] - m); s += f[j]; }
        #pragma unroll
        for (int off = 1; off < 8; off <<= 1) s += __shfl_xor(s, off);
        const float inv = QSCALE / s;
        #pragma unroll
        for (int j = 0; j < 8; ++j) v[j] = (__bf16)(f[j] * inv);
        *(bf8*)&sQb[tok][c8] = v;
    }
    __syncthreads();

    f32x4 acc[2][4] = {};
    #pragma unroll
    for (int ksp = 0; ksp < 2; ++ksp) {
        const int kk = ksp * 32;
        bf8 af[2];
        #pragma unroll
        for (int mi = 0; mi < 2; ++mi)
            af[mi] = *(const bf8*)&sQb[w * 32 + mi * 16 + l16][kk + quad * 8];
        #pragma unroll
        for (int mi = 0; mi < 2; ++mi)
            #pragma unroll
            for (int ni = 0; ni < 4; ++ni)
                acc[mi][ni] = __builtin_amdgcn_mfma_f32_16x16x32_bf16(
                    af[mi], bfr[ksp][ni], acc[mi][ni], 0, 0, 0);
    }
    bf16_t* xob = xoT + (size_t)b * KVSTRIDE;
    #pragma unroll
    for (int mi = 0; mi < 2; ++mi)
        #pragma unroll
        for (int ni = 0; ni < 4; ++ni)
            #pragma unroll
            for (int r = 0; r < 4; ++r) {
                int p = p0 + w * 32 + mi * 16 + quad * 4 + r;
                int dg = h * 64 + ni * 16 + l16;
                xob[(size_t)p * NC + dg] = (__bf16)acc[mi][ni][r];
            }
}

// ---------------------------------------------------------------------------
// H: out = y/max(sqrt(ysq),eps)*g2*sqrtC + x (fp32 out). grid(1024, 8) b256.
// ---------------------------------------------------------------------------
__global__ __launch_bounds__(256) void
final_kernel(const bf16_t* __restrict__ y, const float* __restrict__ ysq,
             const float* __restrict__ g2, const float* __restrict__ x,
             float* __restrict__ out) {
    const int b = blockIdx.y;
    int idx = blockIdx.x * 256 + threadIdx.x;      // [0, 262144)
    int o = idx >> 9;
    int p8 = (idx & 511) * 8;
    const bf16_t* yb = y + (size_t)b * QSTRIDE;
    const float* xb = x + (size_t)b * QSTRIDE;
    float* outb = out + (size_t)b * QSTRIDE;
    const float* sq = ysq + (size_t)b * NP;

    bf8 yv = *(const bf8*)&yb[(size_t)o * NP + p8];
    float gv = g2[o] * SQRTC;
    float4 a = *(const float4*)&xb[(size_t)o * NP + p8];
    float4 b2 = *(const float4*)&xb[(size_t)o * NP + p8 + 4];
    float inb[8];
    #pragma unroll
    for (int j = 0; j < 8; ++j)
        inb[j] = 1.0f / fmaxf(sqrtf(sq[p8 + j]), 1e-12f);

    float4 r0, r1;
    r0.x = (float)yv[0] * inb[0] * gv + a.x;
    r0.y = (float)yv[1] * inb[1] * gv + a.y;
    r0.z = (float)yv[2] * inb[2] * gv + a.z;
    r0.w = (float)yv[3] * inb[3] * gv + a.w;
    r1.x = (float)yv[4] * inb[4] * gv + b2.x;
    r1.y = (float)yv[5] * inb[5] * gv + b2.y;
    r1.z = (float)yv[6] * inb[6] * gv + b2.z;
    r1.w = (float)yv[7] * inb[7] * gv + b2.w;
    *(float4*)&outb[(size_t)o * NP + p8] = r0;
    *(float4*)&outb[(size_t)o * NP + p8 + 4] = r1;
}

// ---------------------------------------------------------------------------
extern "C" void kernel_launch(void* const* d_in, const int* in_sizes, int n_in,
                              void* d_out, int out_size, void* d_ws, size_t ws_size,
                              hipStream_t stream) {
    const float* x     = (const float*)d_in[0];
    const float* g     = (const float*)d_in[1];
    const float* qkv_w = (const float*)d_in[2];
    const float* ffn_w = (const float*)d_in[3];
    const float* ffn_b = (const float*)d_in[4];
    const float* ffn_g = (const float*)d_in[5];
    float* out = (float*)d_out;
    bf16_t* kv = (bf16_t*)d_out;     // 8*KVSTRIDE bf16 = 64 MiB (K,V then xoT)

    // workspace (~44.2 MB): attnP aliases xnT2; attnF aliases dead Wg
    bf16_t* q     = (bf16_t*)d_ws;                   // 8*QSTRIDE bf16 (Q, then y)
    bf16_t* xnT2  = q + 8 * QSTRIDE;                 // 2*QSTRIDE bf16 (chunk)
    float*  attnP = (float*)xnT2;                    // 64*8*4096 f32 = 8.39 MB
    bf16_t* Wg    = xnT2 + 2 * QSTRIDE;              // 786432 bf16
    bf16_t* attnF = Wg;                              // 64*4096 bf16 = 512 KB
    bf16_t* Wf    = Wg + 786432;                     // 262144 bf16
    float*  kmax  = (float*)(Wf + 262144);           // 8*512 f32
    float*  kinv  = kmax + 8 * 512;                  // 8*512 f32
    float*  ysq   = kinv + 8 * 512;                  // 8*4096 f32

    wconv_kernel<<<dim3(1024), 256, 0, stream>>>(qkv_w, g, ffn_w, Wg, Wf);

    // chunked: normalize+transpose 2 batches, then their QKV GEMM
    for (int c = 0; c < 4; ++c) {
        norm_transpose_kernel<<<dim3(128, 2), 512, 0, stream>>>(
            x + (size_t)(2 * c) * QSTRIDE, xnT2);
        gemm_qkv_kernel<<<dim3(32, 12, 2), 256, 0, stream>>>(
            Wg, xnT2, q + (size_t)(2 * c) * QSTRIDE, kv + (size_t)(2 * c) * KVSTRIDE);
    }

    kstats_kernel<<<dim3(512, 8), 256, 0, stream>>>(kv, kmax, kinv);
    attn_kernel<<<dim3(8, 8, 8), 256, 0, stream>>>(kv, kmax, attnP);
    attnsum_kernel<<<dim3(64, 4), 256, 0, stream>>>(attnP, kinv, attnF, ysq);
    outgemm_kernel<<<dim3(32, 8, 8), 256, 0, stream>>>(q, attnF, kv);
    gemm_ffn_kernel<<<dim3(32, 4, 8), 256, 0, stream>>>(Wf, kv, ffn_b, q, ysq);
    final_kernel<<<dim3(1024, 8), 256, 0, stream>>>(q, ysq, ffn_g, x, out);
}

// Round 5
// 353.209 us; speedup vs baseline: 1.1243x; 1.0285x over previous
//
#include <hip/hip_runtime.h>

// ---------------------------------------------------------------------------
// MultiHeadsLinearAttention  (B=8, C=512, HEADS=8, CH=64, H=W=64 -> N=4096)
// Inputs fp32, output fp32. Compute: bf16 MFMA, fp32 accumulation.
//
// Stages:
//  W : Wg = qkv_w * g -> bf16 ; Wf = ffn_w -> bf16 (single merged launch)
//  T : per-token invx over fp32 x; xnT[p][c] = x*invx*sqrtC (bf16, k-contig)
//      512 thr; pass-2 uses all threads, 128-c chunks (8 barriers)
//  C : QKV GEMM (128x128 tile, BK=64, global_load_lds width-16 LINEAR
//      staging): rows<512 -> Q (ws), else K,V (d_out)
//      R5: LDS-staged epilogue -> 256B coalesced row-segment stores
//      (fragment-layout scatter was 4x32B segments per wave instr)
//  D : k-softmax stats (kmax,kinv)
//  E : attnP[bh][ks][d][c] = sum_{p in ks-slice} exp(k[c][p]-kmax)*v[d][p]
//      (MFMA, wave-specialized over d -> ZERO atomics, zero LDS; 8 p-partials)
//  E2: attnsum: attnF[bh][d][c] = (sum_ks attnP) * kinv[c] -> bf16
//      (+ zeroes ysq for the FFN epilogue accumulation)
//  F : q-softmax per token (wave-parallel 8-lane shfl) ; xoT = qsm @ attnF
//      R5: LDS-staged epilogue (reuses sQb) -> 128B coalesced segments
//  G : FFN GEMM y = ffn_b + Wf @ xoT ; epilogue accumulates per-column
//      sumsq of bf16-rounded y into ysq; R5: LDS-staged coalesced C-write
//  H : out = y/max(sqrt(ysq),eps)*g2*sqrtC + x (fp32)
//
// Round-7 lesson: global_load_lds + XOR-SWIZZLE staging diverged after graph
// replay -> LINEAR destinations only (no swizzle, no padding, m173).
// Round-8 lesson: 8.4M contended global atomicAdds in attn = 175us wall ->
// partials + wave-specialization.
// Round-R1 lesson: outgemm re-summed attnP 32x (53us @ 1.5% MfmaUtil) ->
// attnsum collapses once.
// ---------------------------------------------------------------------------

typedef __bf16 bf16_t;
typedef __bf16 bf8 __attribute__((ext_vector_type(8)));
typedef float f32x4 __attribute__((ext_vector_type(4)));

#define NC 512
#define NP 4096
#define SQRTC 22.62741699796952f
#define QSCALE 0.125f
#define QSTRIDE  ((size_t)NC * NP)      // 2097152  per-batch 512-row elems
#define KVSTRIDE ((size_t)1024 * NP)    // 4194304  per-batch kv elems (d_out)
#define LDC 136                          // epilogue C-tile stride (bank-spread)

__device__ inline unsigned short bfbits(__bf16 h) {
    return __builtin_bit_cast(unsigned short, h);
}

// async global->LDS, 16B per lane. LDS dest must be wave-uniform base;
// HW writes base + lane*16.
__device__ __forceinline__ void gload_lds16(const bf16_t* g, __bf16* l) {
    __builtin_amdgcn_global_load_lds(
        (const __attribute__((address_space(1))) void*)g,
        (__attribute__((address_space(3))) void*)l, 16, 0, 0);
}

// ---------------------------------------------------------------------------
// W: both weight converts in one launch. blocks 0..767: Wg = qkv_w * g;
// blocks 768..1023: Wf = ffn_w. 4 elems/thread.
// ---------------------------------------------------------------------------
__global__ __launch_bounds__(256) void
wconv_kernel(const float* __restrict__ qkv_w, const float* __restrict__ g,
             const float* __restrict__ ffn_w, bf16_t* __restrict__ Wg,
             bf16_t* __restrict__ Wf) {
    const int bx = blockIdx.x;
    if (bx < 768) {
        int i0 = (bx * 256 + threadIdx.x) * 4;
        float4 wv = *(const float4*)&qkv_w[i0];
        const float4 gv = *(const float4*)&g[i0 & 511];
        ushort4 o;
        o.x = bfbits((__bf16)(wv.x * gv.x));
        o.y = bfbits((__bf16)(wv.y * gv.y));
        o.z = bfbits((__bf16)(wv.z * gv.z));
        o.w = bfbits((__bf16)(wv.w * gv.w));
        *(ushort4*)&Wg[i0] = o;
    } else {
        int i0 = ((bx - 768) * 256 + threadIdx.x) * 4;
        float4 wv = *(const float4*)&ffn_w[i0];
        ushort4 o;
        o.x = bfbits((__bf16)wv.x);
        o.y = bfbits((__bf16)wv.y);
        o.z = bfbits((__bf16)wv.z);
        o.w = bfbits((__bf16)wv.w);
        *(ushort4*)&Wf[i0] = o;
    }
}

// ---------------------------------------------------------------------------
// T: norm + transpose, 2 batches per launch. grid(128, 2) block 512.
// Block covers 32 tokens. xnT[p][c] = x[c][p] * sqrtC/max(||x[:,p]||,1e-12)
// pass 1: float4 coalesced sumsq, shfl_xor tree, LDS cross-wave finish.
// pass 2: 128-c x 32-p chunks through LDS; all 512 threads write 256B rows.
// ---------------------------------------------------------------------------
__global__ __launch_bounds__(512) void
norm_transpose_kernel(const float* __restrict__ x, bf16_t* __restrict__ xnT) {
    const int bl = blockIdx.y;
    const int p0 = blockIdx.x * 32;
    const int t = threadIdx.x;
    const float* xb = x + (size_t)bl * QSTRIDE;
    bf16_t* ob = xnT + (size_t)bl * QSTRIDE;

    // pass 1: thread (cg = t&7, r0 = t>>3) accumulates x^2 for tokens
    // [p0 + cg*4, +4) over rows {r0 + 64k}.
    const int cg = t & 7, r0 = t >> 3;
    f32x4 ss = {0.f, 0.f, 0.f, 0.f};
    #pragma unroll
    for (int k = 0; k < 8; ++k) {
        const int c = r0 + k * 64;
        float4 v = *(const float4*)&xb[(size_t)c * NP + p0 + cg * 4];
        ss.x += v.x * v.x; ss.y += v.y * v.y;
        ss.z += v.z * v.z; ss.w += v.w * v.w;
    }
    #pragma unroll
    for (int m = 8; m <= 32; m <<= 1) {
        ss.x += __shfl_xor(ss.x, m); ss.y += __shfl_xor(ss.y, m);
        ss.z += __shfl_xor(ss.z, m); ss.w += __shfl_xor(ss.w, m);
    }
    __shared__ float sP[8][34];
    __shared__ float sInv[32];
    const int w = t >> 6;
    if ((t & 63) < 8) {
        const int p = (t & 7) * 4;
        sP[w][p] = ss.x; sP[w][p + 1] = ss.y;
        sP[w][p + 2] = ss.z; sP[w][p + 3] = ss.w;
    }
    __syncthreads();
    if (t < 32) {
        float tot = 0.f;
        #pragma unroll
        for (int j = 0; j < 8; ++j) tot += sP[j][t];
        sInv[t] = SQRTC / fmaxf(sqrtf(tot), 1e-12f);
    }
    __syncthreads();

    // pass 2: 128-c x 32-p chunks through LDS transpose, all threads active
    __shared__ __bf16 sT[128][41];
    for (int cc = 0; cc < 512; cc += 128) {
        #pragma unroll
        for (int j = 0; j < 8; ++j) {
            int e = t + j * 512;                 // 4096 = 128c x 32p
            int cr = e >> 5, p = e & 31;
            sT[cr][p] = (__bf16)(xb[(size_t)(cc + cr) * NP + p0 + p] * sInv[p]);
        }
        __syncthreads();
        {
            int p = t >> 4, c8 = (t & 15) * 8;
            bf8 v;
            #pragma unroll
            for (int q = 0; q < 8; ++q) v[q] = sT[c8 + q][p];
            *(bf8*)&ob[(size_t)(p0 + p) * NC + cc + c8] = v;
        }
        __syncthreads();
    }
}

// ---------------------------------------------------------------------------
// C: QKV GEMM. grid(32, 12, nb) block 256 (nb batches per launch).
// A = Wg [1536][512], B = xnT [p][c] (both k-contiguous bf16).
// 128x128 tile, BK=64, 4 waves of 64x64. global_load_lds linear staging.
// Epilogue: acc -> LDS [128][LDC] -> 256B coalesced row-segment stores.
// ---------------------------------------------------------------------------
__global__ __launch_bounds__(256) void
gemm_qkv_kernel(const bf16_t* __restrict__ Wg, const bf16_t* __restrict__ xnT,
                bf16_t* __restrict__ qout, bf16_t* __restrict__ kvout) {
    const int bn = blockIdx.x, bm = blockIdx.y, b = blockIdx.z;
    const int t = threadIdx.x;
    const int w = t >> 6, ln = t & 63, quad = ln >> 4, l16 = ln & 15;
    const int wm = w >> 1, wn = w & 1;

    // K-loop: A [0,8192), B [8192,16384). Epilogue C-tile: [128][LDC] = 17408.
    __shared__ __align__(16) __bf16 sAB[128 * LDC];
    __bf16* const sA = sAB;
    __bf16* const sB = sAB + 8192;

    f32x4 acc[4][4] = {};
    const bf16_t* Abase = Wg + (size_t)(bm * 128) * NC;
    const bf16_t* Bbase = xnT + (size_t)b * QSTRIDE + (size_t)(bn * 128) * NC;

    // per-lane source row/col within a 1024B chunk (8 rows x 64 k)
    const int lrow = ln >> 3;           // 0..7
    const int lkc = (ln & 7) * 8;       // k offset, 16B granules

    for (int kt = 0; kt < 8; ++kt) {
        const int k0 = kt * 64;
        #pragma unroll
        for (int i = 0; i < 4; ++i) {
            const int chunk = w * 4 + i;          // 0..15, wave-uniform
            const int row = chunk * 8 + lrow;
            gload_lds16(Abase + (size_t)row * NC + k0 + lkc, &sA[chunk * 512]);
            gload_lds16(Bbase + (size_t)row * NC + k0 + lkc, &sB[chunk * 512]);
        }
        __syncthreads();
        #pragma unroll
        for (int ks = 0; ks < 2; ++ks) {
            const int kk = ks * 32;
            bf8 af[4], bfr[4];
            #pragma unroll
            for (int mi = 0; mi < 4; ++mi)
                af[mi] = *(const bf8*)&sA[(wm * 64 + mi * 16 + l16) * 64 + kk + quad * 8];
            #pragma unroll
            for (int ni = 0; ni < 4; ++ni)
                bfr[ni] = *(const bf8*)&sB[(wn * 64 + ni * 16 + l16) * 64 + kk + quad * 8];
            #pragma unroll
            for (int mi = 0; mi < 4; ++mi)
                #pragma unroll
                for (int ni = 0; ni < 4; ++ni)
                    acc[mi][ni] = __builtin_amdgcn_mfma_f32_16x16x32_bf16(
                        af[mi], bfr[ni], acc[mi][ni], 0, 0, 0);
        }
        __syncthreads();
    }

    // epilogue: dump acc into LDS C-tile, then coalesced 16B stores
    {
        const int rbase = wm * 64 + quad * 4;
        const int cbase = wn * 64 + l16;
        #pragma unroll
        for (int mi = 0; mi < 4; ++mi)
            #pragma unroll
            for (int ni = 0; ni < 4; ++ni)
                #pragma unroll
                for (int r = 0; r < 4; ++r)
                    sAB[(rbase + mi * 16 + r) * LDC + cbase + ni * 16] =
                        (__bf16)acc[mi][ni][r];
    }
    __syncthreads();
    bf16_t* qb = qout + (size_t)b * QSTRIDE;
    bf16_t* kvb = kvout + (size_t)b * KVSTRIDE;
    const int p0 = bn * 128;
    #pragma unroll
    for (int i = 0; i < 8; ++i) {
        int e = t + i * 256;               // 2048 = 128 rows x 16 segs
        int rr = e >> 4, seg = (e & 15) * 8;
        bf8 v = *(const bf8*)&sAB[rr * LDC + seg];
        int row = bm * 128 + rr;
        if (row < 512)
            *(bf8*)&qb[(size_t)row * NP + p0 + seg] = v;
        else
            *(bf8*)&kvb[(size_t)(row - 512) * NP + p0 + seg] = v;
    }
}

// ---------------------------------------------------------------------------
// G: FFN GEMM. grid(32, 4, 8) block 256.
// A = Wf [512][512], B = xoT [p][c] (d_out K region), out y (+bias) -> ws.
// Epilogue: per-column sumsq into ysq (shfl-reduced, 1 atomic/col/2waves),
// then LDS-staged coalesced C-write.
// ---------------------------------------------------------------------------
__global__ __launch_bounds__(256) void
gemm_ffn_kernel(const bf16_t* __restrict__ Wf, const bf16_t* __restrict__ xoT,
                const float* __restrict__ bias, bf16_t* __restrict__ y,
                float* __restrict__ ysq) {
    const int bn = blockIdx.x, bm = blockIdx.y, b = blockIdx.z;
    const int t = threadIdx.x;
    const int w = t >> 6, ln = t & 63, quad = ln >> 4, l16 = ln & 15;
    const int wm = w >> 1, wn = w & 1;

    __shared__ __align__(16) __bf16 sAB[128 * LDC];
    __bf16* const sA = sAB;
    __bf16* const sB = sAB + 8192;

    f32x4 acc[4][4] = {};
    const bf16_t* Abase = Wf + (size_t)(bm * 128) * NC;
    const bf16_t* Bbase = xoT + (size_t)b * KVSTRIDE + (size_t)(bn * 128) * NC;

    const int lrow = ln >> 3;
    const int lkc = (ln & 7) * 8;

    for (int kt = 0; kt < 8; ++kt) {
        const int k0 = kt * 64;
        #pragma unroll
        for (int i = 0; i < 4; ++i) {
            const int chunk = w * 4 + i;
            const int row = chunk * 8 + lrow;
            gload_lds16(Abase + (size_t)row * NC + k0 + lkc, &sA[chunk * 512]);
            gload_lds16(Bbase + (size_t)row * NC + k0 + lkc, &sB[chunk * 512]);
        }
        __syncthreads();
        #pragma unroll
        for (int ks = 0; ks < 2; ++ks) {
            const int kk = ks * 32;
            bf8 af[4], bfr[4];
            #pragma unroll
            for (int mi = 0; mi < 4; ++mi)
                af[mi] = *(const bf8*)&sA[(wm * 64 + mi * 16 + l16) * 64 + kk + quad * 8];
            #pragma unroll
            for (int ni = 0; ni < 4; ++ni)
                bfr[ni] = *(const bf8*)&sB[(wn * 64 + ni * 16 + l16) * 64 + kk + quad * 8];
            #pragma unroll
            for (int mi = 0; mi < 4; ++mi)
                #pragma unroll
                for (int ni = 0; ni < 4; ++ni)
                    acc[mi][ni] = __builtin_amdgcn_mfma_f32_16x16x32_bf16(
                        af[mi], bfr[ni], acc[mi][ni], 0, 0, 0);
        }
        __syncthreads();
    }

    // ysq epilogue (register layout) + dump bf16-rounded y into LDS C-tile
    float* sq = ysq + (size_t)b * NP;
    const int p0 = bn * 128;
    {
        const int rbase = wm * 64 + quad * 4;
        #pragma unroll
        for (int ni = 0; ni < 4; ++ni) {
            const int col = p0 + wn * 64 + ni * 16 + l16;
            float colsq = 0.f;
            #pragma unroll
            for (int mi = 0; mi < 4; ++mi) {
                #pragma unroll
                for (int r = 0; r < 4; ++r) {
                    const int row = bm * 128 + rbase + mi * 16 + r;
                    __bf16 vb = (__bf16)(acc[mi][ni][r] + bias[row]);
                    sAB[(rbase + mi * 16 + r) * LDC + wn * 64 + ni * 16 + l16] = vb;
                    float vf = (float)vb;
                    colsq += vf * vf;
                }
            }
            colsq += __shfl_xor(colsq, 16);
            colsq += __shfl_xor(colsq, 32);
            if (quad == 0) atomicAdd(&sq[col], colsq);
        }
    }
    __syncthreads();
    bf16_t* yb = y + (size_t)b * QSTRIDE;
    #pragma unroll
    for (int i = 0; i < 8; ++i) {
        int e = t + i * 256;
        int rr = e >> 4, seg = (e & 15) * 8;
        bf8 v = *(const bf8*)&sAB[rr * LDC + seg];
        *(bf8*)&yb[(size_t)(bm * 128 + rr) * NP + p0 + seg] = v;
    }
}

// ---------------------------------------------------------------------------
// D: k-softmax stats per (b, channel) row. grid(512, 8) block 256.
// ---------------------------------------------------------------------------
__global__ __launch_bounds__(256) void
kstats_kernel(const bf16_t* __restrict__ kv, float* __restrict__ kmax,
              float* __restrict__ kinv) {
    const int oc = blockIdx.x, b = blockIdx.y;
    const int t = threadIdx.x, w = t >> 6, ln = t & 63;

    const bf16_t* row = kv + (size_t)b * KVSTRIDE + (size_t)oc * NP;
    float v[16];
    bf8 x0 = *(const bf8*)&row[t * 8];
    bf8 x1 = *(const bf8*)&row[2048 + t * 8];
    #pragma unroll
    for (int j = 0; j < 8; ++j) { v[j] = (float)x0[j]; v[8 + j] = (float)x1[j]; }

    float m = v[0];
    #pragma unroll
    for (int j = 1; j < 16; ++j) m = fmaxf(m, v[j]);
    #pragma unroll
    for (int off = 32; off > 0; off >>= 1) m = fmaxf(m, __shfl_down(m, off));
    __shared__ float sR[4];
    __shared__ float sS[4];
    if (ln == 0) sR[w] = m;
    __syncthreads();
    m = fmaxf(fmaxf(sR[0], sR[1]), fmaxf(sR[2], sR[3]));

    float s = 0.f;
    #pragma unroll
    for (int j = 0; j < 16; ++j) s += __expf(v[j] - m);
    #pragma unroll
    for (int off = 32; off > 0; off >>= 1) s += __shfl_down(s, off);
    if (ln == 0) sS[w] = s;
    __syncthreads();
    if (t == 0) {
        kmax[b * 512 + oc] = m;
        kinv[b * 512 + oc] = 1.0f / (sS[0] + sS[1] + sS[2] + sS[3]);
    }
}

// ---------------------------------------------------------------------------
// E: attnP[bh][ks][d][c] = sum_{p in slice} exp(k[c][p]-kmax[c]) * v[d][p].
// grid(8, 8, 8) block 256. Wave w owns d rows [w*16, w*16+16): no reduction,
// no atomics, no LDS. Each ks-slice covers 512 p (16 iters of 32 p).
// ---------------------------------------------------------------------------
__global__ __launch_bounds__(256) void
attn_kernel(const bf16_t* __restrict__ kv, const float* __restrict__ kmax,
            float* __restrict__ attnP) {
    const int h = blockIdx.x, ks = blockIdx.y, b = blockIdx.z;
    const int t = threadIdx.x, w = t >> 6, ln = t & 63, quad = ln >> 4, l16 = ln & 15;

    const bf16_t* Kb = kv + (size_t)b * KVSTRIDE + (size_t)(h * 64) * NP;
    const bf16_t* Vb = kv + (size_t)b * KVSTRIDE + (size_t)(512 + h * 64 + w * 16) * NP;

    float km[4];
    #pragma unroll
    for (int mi = 0; mi < 4; ++mi) km[mi] = kmax[b * 512 + h * 64 + mi * 16 + l16];

    f32x4 acc[4] = {};
    const int pbase = ks * 512 + quad * 8;
    #pragma unroll 4
    for (int it = 0; it < 16; ++it) {
        const int p0 = pbase + it * 32;
        bf8 bfr = *(const bf8*)&Vb[(size_t)l16 * NP + p0];
        #pragma unroll
        for (int mi = 0; mi < 4; ++mi) {
            bf8 kr = *(const bf8*)&Kb[(size_t)(mi * 16 + l16) * NP + p0];
            bf8 af;
            #pragma unroll
            for (int j = 0; j < 8; ++j)
                af[j] = (__bf16)__expf((float)kr[j] - km[mi]);
            acc[mi] = __builtin_amdgcn_mfma_f32_16x16x32_bf16(af, bfr, acc[mi], 0, 0, 0);
        }
    }

    // D layout: row (=c within mi-block) = quad*4+r, col (=d) = l16.
    float* outp = attnP + (((size_t)(b * 8 + h) * 8 + ks) << 12);
    #pragma unroll
    for (int mi = 0; mi < 4; ++mi) {
        float4 v;
        v.x = acc[mi][0]; v.y = acc[mi][1]; v.z = acc[mi][2]; v.w = acc[mi][3];
        *(float4*)&outp[(w * 16 + l16) * 64 + mi * 16 + quad * 4] = v;
    }
}

// ---------------------------------------------------------------------------
// E2: attnF[bh][d][c] = (sum_ks attnP[bh][ks][d][c]) * kinv[b][h*64+c] -> bf16
// grid(64, 4) block 256. Collapses the 8 p-partials ONCE. attnF aliases dead
// Wg. Also zeroes ysq (stream-ordered before gemm_ffn's accumulation).
// ---------------------------------------------------------------------------
__global__ __launch_bounds__(256) void
attnsum_kernel(const float* __restrict__ attnP, const float* __restrict__ kinv,
               bf16_t* __restrict__ attnF, float* __restrict__ ysq) {
    const int gtid = (blockIdx.x * 4 + blockIdx.y) * 256 + threadIdx.x;
    if (gtid < 8 * NP) ysq[gtid] = 0.f;

    const int bh = blockIdx.x;                     // b*8 + h
    const int e0 = blockIdx.y * 1024 + threadIdx.x * 4;
    const float* ap = attnP + ((size_t)bh << 15);  // 8 slices of 4096
    float4 s = {0.f, 0.f, 0.f, 0.f};
    #pragma unroll
    for (int ks = 0; ks < 8; ++ks) {
        float4 v = *(const float4*)&ap[(ks << 12) + e0];
        s.x += v.x; s.y += v.y; s.z += v.z; s.w += v.w;
    }
    const float* kvp = kinv + (bh >> 3) * 512 + (bh & 7) * 64;
    const int c = e0 & 63;
    ushort4 o;
    o.x = bfbits((__bf16)(s.x * kvp[c]));
    o.y = bfbits((__bf16)(s.y * kvp[c + 1]));
    o.z = bfbits((__bf16)(s.z * kvp[c + 2]));
    o.w = bfbits((__bf16)(s.w * kvp[c + 3]));
    *(ushort4*)&attnF[((size_t)bh << 12) + e0] = o;
}

// ---------------------------------------------------------------------------
// F: q softmax over ch (*SCALE) then xoT[p][h*64+d] = qsm @ attnF.
// grid(32, 8, 8) block 256. attnF B-frags direct from global (L2-resident,
// loads hoisted above the softmax). Softmax wave-parallel: 8 lanes/token.
// Epilogue: LDS-staged (reuses sQb) -> 128B coalesced segments.
// xoT overwrites dead K region of d_out.
// ---------------------------------------------------------------------------
__global__ __launch_bounds__(256) void
outgemm_kernel(const bf16_t* __restrict__ q, const bf16_t* __restrict__ attnF,
               bf16_t* __restrict__ xoT) {
    const int pt = blockIdx.x, h = blockIdx.y, b = blockIdx.z;
    const int p0 = pt * 128;
    const int t = threadIdx.x, w = t >> 6, ln = t & 63, quad = ln >> 4, l16 = ln & 15;

    __shared__ __align__(16) __bf16 sQb[128][72];   // [p][c], 18 KB

    // hoist B-fragment loads (L2-hot attnF) so latency hides under softmax
    const bf16_t* aF = attnF + ((size_t)(b * 8 + h) << 12);
    bf8 bfr[2][4];
    #pragma unroll
    for (int ksp = 0; ksp < 2; ++ksp)
        #pragma unroll
        for (int ni = 0; ni < 4; ++ni)
            bfr[ksp][ni] = *(const bf8*)&aF[(ni * 16 + l16) * 64 + ksp * 32 + quad * 8];

    const bf16_t* qb = q + (size_t)b * QSTRIDE;
    #pragma unroll
    for (int i = 0; i < 32; ++i) {
        int e = t + i * 256;             // c*128 + p
        int c = e >> 7, p = e & 127;
        sQb[p][c] = qb[(size_t)(h * 64 + c) * NP + p0 + p];
    }
    __syncthreads();

    // wave-parallel q-softmax: 8 lanes per token, 4 passes of 32 tokens
    #pragma unroll
    for (int pass = 0; pass < 4; ++pass) {
        const int tok = pass * 32 + (t >> 3);
        const int c8 = (t & 7) * 8;
        bf8 v = *(const bf8*)&sQb[tok][c8];
        float f[8];
        #pragma unroll
        for (int j = 0; j < 8; ++j) f[j] = (float)v[j];
        float m = f[0];
        #pragma unroll
        for (int j = 1; j < 8; ++j) m = fmaxf(m, f[j]);
        #pragma unroll
        for (int off = 1; off < 8; off <<= 1) m = fmaxf(m, __shfl_xor(m, off));
        float s = 0.f;
        #pragma unroll
        for (int j = 0; j < 8; ++j) { f[j] = __expf(f[j] - m); s += f[j]; }
        #pragma unroll
        for (int off = 1; off < 8; off <<= 1) s += __shfl_xor(s, off);
        const float inv = QSCALE / s;
        #pragma unroll
        for (int j = 0; j < 8; ++j) v[j] = (__bf16)(f[j] * inv);
        *(bf8*)&sQb[tok][c8] = v;
    }
    __syncthreads();

    f32x4 acc[2][4] = {};
    #pragma unroll
    for (int ksp = 0; ksp < 2; ++ksp) {
        const int kk = ksp * 32;
        bf8 af[2];
        #pragma unroll
        for (int mi = 0; mi < 2; ++mi)
            af[mi] = *(const bf8*)&sQb[w * 32 + mi * 16 + l16][kk + quad * 8];
        #pragma unroll
        for (int mi = 0; mi < 2; ++mi)
            #pragma unroll
            for (int ni = 0; ni < 4; ++ni)
                acc[mi][ni] = __builtin_amdgcn_mfma_f32_16x16x32_bf16(
                    af[mi], bfr[ksp][ni], acc[mi][ni], 0, 0, 0);
    }
    __syncthreads();   // sQb reads done -> safe to reuse as C-tile

    // dump acc -> sQb [128 rows][64 cols], then 128B coalesced stores
    #pragma unroll
    for (int mi = 0; mi < 2; ++mi)
        #pragma unroll
        for (int ni = 0; ni < 4; ++ni)
            #pragma unroll
            for (int r = 0; r < 4; ++r)
                sQb[w * 32 + mi * 16 + quad * 4 + r][ni * 16 + l16] =
                    (__bf16)acc[mi][ni][r];
    __syncthreads();
    bf16_t* xob = xoT + (size_t)b * KVSTRIDE;
    #pragma unroll
    for (int i = 0; i < 4; ++i) {
        int e = t + i * 256;               // 1024 = 128 rows x 8 segs
        int rr = e >> 3, seg = (e & 7) * 8;
        bf8 v = *(const bf8*)&sQb[rr][seg];
        *(bf8*)&xob[(size_t)(p0 + rr) * NC + h * 64 + seg] = v;
    }
}

// ---------------------------------------------------------------------------
// H: out = y/max(sqrt(ysq),eps)*g2*sqrtC + x (fp32 out). grid(1024, 8) b256.
// ---------------------------------------------------------------------------
__global__ __launch_bounds__(256) void
final_kernel(const bf16_t* __restrict__ y, const float* __restrict__ ysq,
             const float* __restrict__ g2, const float* __restrict__ x,
             float* __restrict__ out) {
    const int b = blockIdx.y;
    int idx = blockIdx.x * 256 + threadIdx.x;      // [0, 262144)
    int o = idx >> 9;
    int p8 = (idx & 511) * 8;
    const bf16_t* yb = y + (size_t)b * QSTRIDE;
    const float* xb = x + (size_t)b * QSTRIDE;
    float* outb = out + (size_t)b * QSTRIDE;
    const float* sq = ysq + (size_t)b * NP;

    bf8 yv = *(const bf8*)&yb[(size_t)o * NP + p8];
    float gv = g2[o] * SQRTC;
    float4 a = *(const float4*)&xb[(size_t)o * NP + p8];
    float4 b2 = *(const float4*)&xb[(size_t)o * NP + p8 + 4];
    float inb[8];
    #pragma unroll
    for (int j = 0; j < 8; ++j)
        inb[j] = 1.0f / fmaxf(sqrtf(sq[p8 + j]), 1e-12f);

    float4 r0, r1;
    r0.x = (float)yv[0] * inb[0] * gv + a.x;
    r0.y = (float)yv[1] * inb[1] * gv + a.y;
    r0.z = (float)yv[2] * inb[2] * gv + a.z;
    r0.w = (float)yv[3] * inb[3] * gv + a.w;
    r1.x = (float)yv[4] * inb[4] * gv + b2.x;
    r1.y = (float)yv[5] * inb[5] * gv + b2.y;
    r1.z = (float)yv[6] * inb[6] * gv + b2.z;
    r1.w = (float)yv[7] * inb[7] * gv + b2.w;
    *(float4*)&outb[(size_t)o * NP + p8] = r0;
    *(float4*)&outb[(size_t)o * NP + p8 + 4] = r1;
}

// ---------------------------------------------------------------------------
extern "C" void kernel_launch(void* const* d_in, const int* in_sizes, int n_in,
                              void* d_out, int out_size, void* d_ws, size_t ws_size,
                              hipStream_t stream) {
    const float* x     = (const float*)d_in[0];
    const float* g     = (const float*)d_in[1];
    const float* qkv_w = (const float*)d_in[2];
    const float* ffn_w = (const float*)d_in[3];
    const float* ffn_b = (const float*)d_in[4];
    const float* ffn_g = (const float*)d_in[5];
    float* out = (float*)d_out;
    bf16_t* kv = (bf16_t*)d_out;     // 8*KVSTRIDE bf16 = 64 MiB (K,V then xoT)

    // workspace (~44.2 MB): attnP aliases xnT2; attnF aliases dead Wg
    bf16_t* q     = (bf16_t*)d_ws;                   // 8*QSTRIDE bf16 (Q, then y)
    bf16_t* xnT2  = q + 8 * QSTRIDE;                 // 2*QSTRIDE bf16 (chunk)
    float*  attnP = (float*)xnT2;                    // 64*8*4096 f32 = 8.39 MB
    bf16_t* Wg    = xnT2 + 2 * QSTRIDE;              // 786432 bf16
    bf16_t* attnF = Wg;                              // 64*4096 bf16 = 512 KB
    bf16_t* Wf    = Wg + 786432;                     // 262144 bf16
    float*  kmax  = (float*)(Wf + 262144);           // 8*512 f32
    float*  kinv  = kmax + 8 * 512;                  // 8*512 f32
    float*  ysq   = kinv + 8 * 512;                  // 8*4096 f32

    wconv_kernel<<<dim3(1024), 256, 0, stream>>>(qkv_w, g, ffn_w, Wg, Wf);

    // chunked: normalize+transpose 2 batches, then their QKV GEMM
    for (int c = 0; c < 4; ++c) {
        norm_transpose_kernel<<<dim3(128, 2), 512, 0, stream>>>(
            x + (size_t)(2 * c) * QSTRIDE, xnT2);
        gemm_qkv_kernel<<<dim3(32, 12, 2), 256, 0, stream>>>(
            Wg, xnT2, q + (size_t)(2 * c) * QSTRIDE, kv + (size_t)(2 * c) * KVSTRIDE);
    }

    kstats_kernel<<<dim3(512, 8), 256, 0, stream>>>(kv, kmax, kinv);
    attn_kernel<<<dim3(8, 8, 8), 256, 0, stream>>>(kv, kmax, attnP);
    attnsum_kernel<<<dim3(64, 4), 256, 0, stream>>>(attnP, kinv, attnF, ysq);
    outgemm_kernel<<<dim3(32, 8, 8), 256, 0, stream>>>(q, attnF, kv);
    gemm_ffn_kernel<<<dim3(32, 4, 8), 256, 0, stream>>>(Wf, kv, ffn_b, q, ysq);
    final_kernel<<<dim3(1024, 8), 256, 0, stream>>>(q, ysq, ffn_g, x, out);
}

// Round 6
// 319.751 us; speedup vs baseline: 1.2420x; 1.1046x over previous
//
#include <hip/hip_runtime.h>

// ---------------------------------------------------------------------------
// MultiHeadsLinearAttention  (B=8, C=512, HEADS=8, CH=64, H=W=64 -> N=4096)
// Inputs fp32, output fp32. Compute: bf16 MFMA, fp32 accumulation.
//
// Stages:
//  W : Wg = qkv_w * g -> bf16 ; Wf = ffn_w -> bf16 (single merged launch)
//  T : per-token invx over fp32 x; xnT[p][c] = x*invx*sqrtC (bf16, k-contig)
//      512 thr; pass-2 float4 re-read (16B/lane); R6: single 8-batch launch
//      when ws_size permits (gate), else 2-batch chunks as before
//  C : QKV GEMM (128x128 tile, BK=64, global_load_lds width-16 LINEAR
//      staging): rows<512 -> Q (ws), else K,V (d_out); LDS-staged epilogue
//      R6: single grid(32,12,8) launch under the ws gate
//  D : k-softmax stats (kmax,kinv)
//  E : attnP[bh][ks][d][c] = sum_{p in ks-slice} exp(k[c][p]-kmax)*v[d][p]
//      (MFMA, wave-specialized over d -> ZERO atomics, zero LDS; 8 p-partials)
//  E2: attnsum: attnF[bh][d][c] = (sum_ks attnP) * kinv[c] -> bf16
//      (+ zeroes ysq for the FFN epilogue accumulation)
//  F : q-softmax per token (wave-parallel 8-lane shfl) ; xoT = qsm @ attnF
//      LDS-staged epilogue -> 128B coalesced segments
//  G : FFN GEMM y = ffn_b + Wf @ xoT ; epilogue accumulates per-column
//      sumsq of bf16-rounded y into ysq; LDS-staged coalesced C-write
//  H : out = y/max(sqrt(ysq),eps)*g2*sqrtC + x (fp32)
//
// Round-7 lesson: global_load_lds + XOR-SWIZZLE staging diverged after graph
// replay -> LINEAR destinations only (no swizzle, no padding, m173).
// Round-8 lesson: 8.4M contended global atomicAdds in attn = 175us wall ->
// partials + wave-specialization.
// Round-R1 lesson: outgemm re-summed attnP 32x (53us @ 1.5% MfmaUtil) ->
// attnsum collapses once.
// Round-R5 lesson (learn_hip m99/m100/m131-141): 128^2 2-barrier GEMMs with
// gload_lds are at their structural ceiling; dbuf/vmcnt tweaks neutral ->
// this round attacks launch/drain overhead instead (ws-gated full-batch).
// ---------------------------------------------------------------------------

typedef __bf16 bf16_t;
typedef __bf16 bf8 __attribute__((ext_vector_type(8)));
typedef float f32x4 __attribute__((ext_vector_type(4)));

#define NC 512
#define NP 4096
#define SQRTC 22.62741699796952f
#define QSCALE 0.125f
#define QSTRIDE  ((size_t)NC * NP)      // 2097152  per-batch 512-row elems
#define KVSTRIDE ((size_t)1024 * NP)    // 4194304  per-batch kv elems (d_out)
#define LDC 136                          // epilogue C-tile stride (bank-spread)

__device__ inline unsigned short bfbits(__bf16 h) {
    return __builtin_bit_cast(unsigned short, h);
}

// async global->LDS, 16B per lane. LDS dest must be wave-uniform base;
// HW writes base + lane*16.
__device__ __forceinline__ void gload_lds16(const bf16_t* g, __bf16* l) {
    __builtin_amdgcn_global_load_lds(
        (const __attribute__((address_space(1))) void*)g,
        (__attribute__((address_space(3))) void*)l, 16, 0, 0);
}

// ---------------------------------------------------------------------------
// W: both weight converts in one launch. blocks 0..767: Wg = qkv_w * g;
// blocks 768..1023: Wf = ffn_w. 4 elems/thread.
// ---------------------------------------------------------------------------
__global__ __launch_bounds__(256) void
wconv_kernel(const float* __restrict__ qkv_w, const float* __restrict__ g,
             const float* __restrict__ ffn_w, bf16_t* __restrict__ Wg,
             bf16_t* __restrict__ Wf) {
    const int bx = blockIdx.x;
    if (bx < 768) {
        int i0 = (bx * 256 + threadIdx.x) * 4;
        float4 wv = *(const float4*)&qkv_w[i0];
        const float4 gv = *(const float4*)&g[i0 & 511];
        ushort4 o;
        o.x = bfbits((__bf16)(wv.x * gv.x));
        o.y = bfbits((__bf16)(wv.y * gv.y));
        o.z = bfbits((__bf16)(wv.z * gv.z));
        o.w = bfbits((__bf16)(wv.w * gv.w));
        *(ushort4*)&Wg[i0] = o;
    } else {
        int i0 = ((bx - 768) * 256 + threadIdx.x) * 4;
        float4 wv = *(const float4*)&ffn_w[i0];
        ushort4 o;
        o.x = bfbits((__bf16)wv.x);
        o.y = bfbits((__bf16)wv.y);
        o.z = bfbits((__bf16)wv.z);
        o.w = bfbits((__bf16)wv.w);
        *(ushort4*)&Wf[i0] = o;
    }
}

// ---------------------------------------------------------------------------
// T: norm + transpose. grid(128, nb) block 512. Block covers 32 tokens of
// batch blockIdx.y. xnT[p][c] = x[c][p] * sqrtC/max(||x[:,p]||,1e-12)
// pass 1: float4 coalesced sumsq, shfl_xor tree, LDS cross-wave finish.
// pass 2: 128-c x 32-p chunks via LDS; float4 re-read (L2-hot), 256B writes.
// ---------------------------------------------------------------------------
__global__ __launch_bounds__(512) void
norm_transpose_kernel(const float* __restrict__ x, bf16_t* __restrict__ xnT) {
    const int bl = blockIdx.y;
    const int p0 = blockIdx.x * 32;
    const int t = threadIdx.x;
    const float* xb = x + (size_t)bl * QSTRIDE;
    bf16_t* ob = xnT + (size_t)bl * QSTRIDE;

    // pass 1: thread (cg = t&7, r0 = t>>3) accumulates x^2 for tokens
    // [p0 + cg*4, +4) over rows {r0 + 64k}.
    const int cg = t & 7, r0 = t >> 3;
    f32x4 ss = {0.f, 0.f, 0.f, 0.f};
    #pragma unroll
    for (int k = 0; k < 8; ++k) {
        const int c = r0 + k * 64;
        float4 v = *(const float4*)&xb[(size_t)c * NP + p0 + cg * 4];
        ss.x += v.x * v.x; ss.y += v.y * v.y;
        ss.z += v.z * v.z; ss.w += v.w * v.w;
    }
    #pragma unroll
    for (int m = 8; m <= 32; m <<= 1) {
        ss.x += __shfl_xor(ss.x, m); ss.y += __shfl_xor(ss.y, m);
        ss.z += __shfl_xor(ss.z, m); ss.w += __shfl_xor(ss.w, m);
    }
    __shared__ float sP[8][34];
    __shared__ float sInv[32];
    const int w = t >> 6;
    if ((t & 63) < 8) {
        const int p = (t & 7) * 4;
        sP[w][p] = ss.x; sP[w][p + 1] = ss.y;
        sP[w][p + 2] = ss.z; sP[w][p + 3] = ss.w;
    }
    __syncthreads();
    if (t < 32) {
        float tot = 0.f;
        #pragma unroll
        for (int j = 0; j < 8; ++j) tot += sP[j][t];
        sInv[t] = SQRTC / fmaxf(sqrtf(tot), 1e-12f);
    }
    __syncthreads();

    // pass 2: 128-c x 32-p chunks through LDS transpose, float4 loads
    __shared__ __bf16 sT[128][41];
    for (int cc = 0; cc < 512; cc += 128) {
        #pragma unroll
        for (int j = 0; j < 2; ++j) {
            int idx = t + j * 512;               // [0,1024): 128 cr x 8 pg
            int cr = idx >> 3, pg = idx & 7;
            float4 v = *(const float4*)&xb[(size_t)(cc + cr) * NP + p0 + pg * 4];
            sT[cr][pg * 4 + 0] = (__bf16)(v.x * sInv[pg * 4 + 0]);
            sT[cr][pg * 4 + 1] = (__bf16)(v.y * sInv[pg * 4 + 1]);
            sT[cr][pg * 4 + 2] = (__bf16)(v.z * sInv[pg * 4 + 2]);
            sT[cr][pg * 4 + 3] = (__bf16)(v.w * sInv[pg * 4 + 3]);
        }
        __syncthreads();
        {
            int p = t >> 4, c8 = (t & 15) * 8;
            bf8 v;
            #pragma unroll
            for (int q = 0; q < 8; ++q) v[q] = sT[c8 + q][p];
            *(bf8*)&ob[(size_t)(p0 + p) * NC + cc + c8] = v;
        }
        __syncthreads();
    }
}

// ---------------------------------------------------------------------------
// C: QKV GEMM. grid(32, 12, nb) block 256 (nb batches per launch).
// A = Wg [1536][512], B = xnT [p][c] (both k-contiguous bf16).
// 128x128 tile, BK=64, 4 waves of 64x64. global_load_lds linear staging.
// Epilogue: acc -> LDS [128][LDC] -> 256B coalesced row-segment stores.
// ---------------------------------------------------------------------------
__global__ __launch_bounds__(256) void
gemm_qkv_kernel(const bf16_t* __restrict__ Wg, const bf16_t* __restrict__ xnT,
                bf16_t* __restrict__ qout, bf16_t* __restrict__ kvout) {
    const int bn = blockIdx.x, bm = blockIdx.y, b = blockIdx.z;
    const int t = threadIdx.x;
    const int w = t >> 6, ln = t & 63, quad = ln >> 4, l16 = ln & 15;
    const int wm = w >> 1, wn = w & 1;

    // K-loop: A [0,8192), B [8192,16384). Epilogue C-tile: [128][LDC].
    __shared__ __align__(16) __bf16 sAB[128 * LDC];
    __bf16* const sA = sAB;
    __bf16* const sB = sAB + 8192;

    f32x4 acc[4][4] = {};
    const bf16_t* Abase = Wg + (size_t)(bm * 128) * NC;
    const bf16_t* Bbase = xnT + (size_t)b * QSTRIDE + (size_t)(bn * 128) * NC;

    // per-lane source row/col within a 1024B chunk (8 rows x 64 k)
    const int lrow = ln >> 3;           // 0..7
    const int lkc = (ln & 7) * 8;       // k offset, 16B granules

    for (int kt = 0; kt < 8; ++kt) {
        const int k0 = kt * 64;
        #pragma unroll
        for (int i = 0; i < 4; ++i) {
            const int chunk = w * 4 + i;          // 0..15, wave-uniform
            const int row = chunk * 8 + lrow;
            gload_lds16(Abase + (size_t)row * NC + k0 + lkc, &sA[chunk * 512]);
            gload_lds16(Bbase + (size_t)row * NC + k0 + lkc, &sB[chunk * 512]);
        }
        __syncthreads();
        #pragma unroll
        for (int ks = 0; ks < 2; ++ks) {
            const int kk = ks * 32;
            bf8 af[4], bfr[4];
            #pragma unroll
            for (int mi = 0; mi < 4; ++mi)
                af[mi] = *(const bf8*)&sA[(wm * 64 + mi * 16 + l16) * 64 + kk + quad * 8];
            #pragma unroll
            for (int ni = 0; ni < 4; ++ni)
                bfr[ni] = *(const bf8*)&sB[(wn * 64 + ni * 16 + l16) * 64 + kk + quad * 8];
            #pragma unroll
            for (int mi = 0; mi < 4; ++mi)
                #pragma unroll
                for (int ni = 0; ni < 4; ++ni)
                    acc[mi][ni] = __builtin_amdgcn_mfma_f32_16x16x32_bf16(
                        af[mi], bfr[ni], acc[mi][ni], 0, 0, 0);
        }
        __syncthreads();
    }

    // epilogue: dump acc into LDS C-tile, then coalesced 16B stores
    {
        const int rbase = wm * 64 + quad * 4;
        const int cbase = wn * 64 + l16;
        #pragma unroll
        for (int mi = 0; mi < 4; ++mi)
            #pragma unroll
            for (int ni = 0; ni < 4; ++ni)
                #pragma unroll
                for (int r = 0; r < 4; ++r)
                    sAB[(rbase + mi * 16 + r) * LDC + cbase + ni * 16] =
                        (__bf16)acc[mi][ni][r];
    }
    __syncthreads();
    bf16_t* qb = qout + (size_t)b * QSTRIDE;
    bf16_t* kvb = kvout + (size_t)b * KVSTRIDE;
    const int p0 = bn * 128;
    #pragma unroll
    for (int i = 0; i < 8; ++i) {
        int e = t + i * 256;               // 2048 = 128 rows x 16 segs
        int rr = e >> 4, seg = (e & 15) * 8;
        bf8 v = *(const bf8*)&sAB[rr * LDC + seg];
        int row = bm * 128 + rr;
        if (row < 512)
            *(bf8*)&qb[(size_t)row * NP + p0 + seg] = v;
        else
            *(bf8*)&kvb[(size_t)(row - 512) * NP + p0 + seg] = v;
    }
}

// ---------------------------------------------------------------------------
// G: FFN GEMM. grid(32, 4, 8) block 256.
// A = Wf [512][512], B = xoT [p][c] (d_out K region), out y (+bias) -> ws.
// Epilogue: per-column sumsq into ysq (shfl-reduced, 1 atomic/col/2waves),
// then LDS-staged coalesced C-write.
// ---------------------------------------------------------------------------
__global__ __launch_bounds__(256) void
gemm_ffn_kernel(const bf16_t* __restrict__ Wf, const bf16_t* __restrict__ xoT,
                const float* __restrict__ bias, bf16_t* __restrict__ y,
                float* __restrict__ ysq) {
    const int bn = blockIdx.x, bm = blockIdx.y, b = blockIdx.z;
    const int t = threadIdx.x;
    const int w = t >> 6, ln = t & 63, quad = ln >> 4, l16 = ln & 15;
    const int wm = w >> 1, wn = w & 1;

    __shared__ __align__(16) __bf16 sAB[128 * LDC];
    __bf16* const sA = sAB;
    __bf16* const sB = sAB + 8192;

    f32x4 acc[4][4] = {};
    const bf16_t* Abase = Wf + (size_t)(bm * 128) * NC;
    const bf16_t* Bbase = xoT + (size_t)b * KVSTRIDE + (size_t)(bn * 128) * NC;

    const int lrow = ln >> 3;
    const int lkc = (ln & 7) * 8;

    for (int kt = 0; kt < 8; ++kt) {
        const int k0 = kt * 64;
        #pragma unroll
        for (int i = 0; i < 4; ++i) {
            const int chunk = w * 4 + i;
            const int row = chunk * 8 + lrow;
            gload_lds16(Abase + (size_t)row * NC + k0 + lkc, &sA[chunk * 512]);
            gload_lds16(Bbase + (size_t)row * NC + k0 + lkc, &sB[chunk * 512]);
        }
        __syncthreads();
        #pragma unroll
        for (int ks = 0; ks < 2; ++ks) {
            const int kk = ks * 32;
            bf8 af[4], bfr[4];
            #pragma unroll
            for (int mi = 0; mi < 4; ++mi)
                af[mi] = *(const bf8*)&sA[(wm * 64 + mi * 16 + l16) * 64 + kk + quad * 8];
            #pragma unroll
            for (int ni = 0; ni < 4; ++ni)
                bfr[ni] = *(const bf8*)&sB[(wn * 64 + ni * 16 + l16) * 64 + kk + quad * 8];
            #pragma unroll
            for (int mi = 0; mi < 4; ++mi)
                #pragma unroll
                for (int ni = 0; ni < 4; ++ni)
                    acc[mi][ni] = __builtin_amdgcn_mfma_f32_16x16x32_bf16(
                        af[mi], bfr[ni], acc[mi][ni], 0, 0, 0);
        }
        __syncthreads();
    }

    // ysq epilogue (register layout) + dump bf16-rounded y into LDS C-tile
    float* sq = ysq + (size_t)b * NP;
    const int p0 = bn * 128;
    {
        const int rbase = wm * 64 + quad * 4;
        #pragma unroll
        for (int ni = 0; ni < 4; ++ni) {
            const int col = p0 + wn * 64 + ni * 16 + l16;
            float colsq = 0.f;
            #pragma unroll
            for (int mi = 0; mi < 4; ++mi) {
                #pragma unroll
                for (int r = 0; r < 4; ++r) {
                    const int row = bm * 128 + rbase + mi * 16 + r;
                    __bf16 vb = (__bf16)(acc[mi][ni][r] + bias[row]);
                    sAB[(rbase + mi * 16 + r) * LDC + wn * 64 + ni * 16 + l16] = vb;
                    float vf = (float)vb;
                    colsq += vf * vf;
                }
            }
            colsq += __shfl_xor(colsq, 16);
            colsq += __shfl_xor(colsq, 32);
            if (quad == 0) atomicAdd(&sq[col], colsq);
        }
    }
    __syncthreads();
    bf16_t* yb = y + (size_t)b * QSTRIDE;
    #pragma unroll
    for (int i = 0; i < 8; ++i) {
        int e = t + i * 256;
        int rr = e >> 4, seg = (e & 15) * 8;
        bf8 v = *(const bf8*)&sAB[rr * LDC + seg];
        *(bf8*)&yb[(size_t)(bm * 128 + rr) * NP + p0 + seg] = v;
    }
}

// ---------------------------------------------------------------------------
// D: k-softmax stats per (b, channel) row. grid(512, 8) block 256.
// ---------------------------------------------------------------------------
__global__ __launch_bounds__(256) void
kstats_kernel(const bf16_t* __restrict__ kv, float* __restrict__ kmax,
              float* __restrict__ kinv) {
    const int oc = blockIdx.x, b = blockIdx.y;
    const int t = threadIdx.x, w = t >> 6, ln = t & 63;

    const bf16_t* row = kv + (size_t)b * KVSTRIDE + (size_t)oc * NP;
    float v[16];
    bf8 x0 = *(const bf8*)&row[t * 8];
    bf8 x1 = *(const bf8*)&row[2048 + t * 8];
    #pragma unroll
    for (int j = 0; j < 8; ++j) { v[j] = (float)x0[j]; v[8 + j] = (float)x1[j]; }

    float m = v[0];
    #pragma unroll
    for (int j = 1; j < 16; ++j) m = fmaxf(m, v[j]);
    #pragma unroll
    for (int off = 32; off > 0; off >>= 1) m = fmaxf(m, __shfl_down(m, off));
    __shared__ float sR[4];
    __shared__ float sS[4];
    if (ln == 0) sR[w] = m;
    __syncthreads();
    m = fmaxf(fmaxf(sR[0], sR[1]), fmaxf(sR[2], sR[3]));

    float s = 0.f;
    #pragma unroll
    for (int j = 0; j < 16; ++j) s += __expf(v[j] - m);
    #pragma unroll
    for (int off = 32; off > 0; off >>= 1) s += __shfl_down(s, off);
    if (ln == 0) sS[w] = s;
    __syncthreads();
    if (t == 0) {
        kmax[b * 512 + oc] = m;
        kinv[b * 512 + oc] = 1.0f / (sS[0] + sS[1] + sS[2] + sS[3]);
    }
}

// ---------------------------------------------------------------------------
// E: attnP[bh][ks][d][c] = sum_{p in slice} exp(k[c][p]-kmax[c]) * v[d][p].
// grid(8, 8, 8) block 256. Wave w owns d rows [w*16, w*16+16): no reduction,
// no atomics, no LDS. Each ks-slice covers 512 p (16 iters of 32 p).
// ---------------------------------------------------------------------------
__global__ __launch_bounds__(256) void
attn_kernel(const bf16_t* __restrict__ kv, const float* __restrict__ kmax,
            float* __restrict__ attnP) {
    const int h = blockIdx.x, ks = blockIdx.y, b = blockIdx.z;
    const int t = threadIdx.x, w = t >> 6, ln = t & 63, quad = ln >> 4, l16 = ln & 15;

    const bf16_t* Kb = kv + (size_t)b * KVSTRIDE + (size_t)(h * 64) * NP;
    const bf16_t* Vb = kv + (size_t)b * KVSTRIDE + (size_t)(512 + h * 64 + w * 16) * NP;

    float km[4];
    #pragma unroll
    for (int mi = 0; mi < 4; ++mi) km[mi] = kmax[b * 512 + h * 64 + mi * 16 + l16];

    f32x4 acc[4] = {};
    const int pbase = ks * 512 + quad * 8;
    #pragma unroll 4
    for (int it = 0; it < 16; ++it) {
        const int p0 = pbase + it * 32;
        bf8 bfr = *(const bf8*)&Vb[(size_t)l16 * NP + p0];
        #pragma unroll
        for (int mi = 0; mi < 4; ++mi) {
            bf8 kr = *(const bf8*)&Kb[(size_t)(mi * 16 + l16) * NP + p0];
            bf8 af;
            #pragma unroll
            for (int j = 0; j < 8; ++j)
                af[j] = (__bf16)__expf((float)kr[j] - km[mi]);
            acc[mi] = __builtin_amdgcn_mfma_f32_16x16x32_bf16(af, bfr, acc[mi], 0, 0, 0);
        }
    }

    // D layout: row (=c within mi-block) = quad*4+r, col (=d) = l16.
    float* outp = attnP + (((size_t)(b * 8 + h) * 8 + ks) << 12);
    #pragma unroll
    for (int mi = 0; mi < 4; ++mi) {
        float4 v;
        v.x = acc[mi][0]; v.y = acc[mi][1]; v.z = acc[mi][2]; v.w = acc[mi][3];
        *(float4*)&outp[(w * 16 + l16) * 64 + mi * 16 + quad * 4] = v;
    }
}

// ---------------------------------------------------------------------------
// E2: attnF[bh][d][c] = (sum_ks attnP[bh][ks][d][c]) * kinv[b][h*64+c] -> bf16
// grid(64, 4) block 256. Collapses the 8 p-partials ONCE. attnF aliases dead
// Wg. Also zeroes ysq (stream-ordered before gemm_ffn's accumulation).
// ---------------------------------------------------------------------------
__global__ __launch_bounds__(256) void
attnsum_kernel(const float* __restrict__ attnP, const float* __restrict__ kinv,
               bf16_t* __restrict__ attnF, float* __restrict__ ysq) {
    const int gtid = (blockIdx.x * 4 + blockIdx.y) * 256 + threadIdx.x;
    if (gtid < 8 * NP) ysq[gtid] = 0.f;

    const int bh = blockIdx.x;                     // b*8 + h
    const int e0 = blockIdx.y * 1024 + threadIdx.x * 4;
    const float* ap = attnP + ((size_t)bh << 15);  // 8 slices of 4096
    float4 s = {0.f, 0.f, 0.f, 0.f};
    #pragma unroll
    for (int ks = 0; ks < 8; ++ks) {
        float4 v = *(const float4*)&ap[(ks << 12) + e0];
        s.x += v.x; s.y += v.y; s.z += v.z; s.w += v.w;
    }
    const float* kvp = kinv + (bh >> 3) * 512 + (bh & 7) * 64;
    const int c = e0 & 63;
    ushort4 o;
    o.x = bfbits((__bf16)(s.x * kvp[c]));
    o.y = bfbits((__bf16)(s.y * kvp[c + 1]));
    o.z = bfbits((__bf16)(s.z * kvp[c + 2]));
    o.w = bfbits((__bf16)(s.w * kvp[c + 3]));
    *(ushort4*)&attnF[((size_t)bh << 12) + e0] = o;
}

// ---------------------------------------------------------------------------
// F: q softmax over ch (*SCALE) then xoT[p][h*64+d] = qsm @ attnF.
// grid(32, 8, 8) block 256. attnF B-frags direct from global (L2-resident,
// loads hoisted above the softmax). Softmax wave-parallel: 8 lanes/token.
// Epilogue: LDS-staged (reuses sQb) -> 128B coalesced segments.
// xoT overwrites dead K region of d_out.
// ---------------------------------------------------------------------------
__global__ __launch_bounds__(256) void
outgemm_kernel(const bf16_t* __restrict__ q, const bf16_t* __restrict__ attnF,
               bf16_t* __restrict__ xoT) {
    const int pt = blockIdx.x, h = blockIdx.y, b = blockIdx.z;
    const int p0 = pt * 128;
    const int t = threadIdx.x, w = t >> 6, ln = t & 63, quad = ln >> 4, l16 = ln & 15;

    __shared__ __align__(16) __bf16 sQb[128][72];   // [p][c], 18 KB

    // hoist B-fragment loads (L2-hot attnF) so latency hides under softmax
    const bf16_t* aF = attnF + ((size_t)(b * 8 + h) << 12);
    bf8 bfr[2][4];
    #pragma unroll
    for (int ksp = 0; ksp < 2; ++ksp)
        #pragma unroll
        for (int ni = 0; ni < 4; ++ni)
            bfr[ksp][ni] = *(const bf8*)&aF[(ni * 16 + l16) * 64 + ksp * 32 + quad * 8];

    const bf16_t* qb = q + (size_t)b * QSTRIDE;
    #pragma unroll
    for (int i = 0; i < 32; ++i) {
        int e = t + i * 256;             // c*128 + p
        int c = e >> 7, p = e & 127;
        sQb[p][c] = qb[(size_t)(h * 64 + c) * NP + p0 + p];
    }
    __syncthreads();

    // wave-parallel q-softmax: 8 lanes per token, 4 passes of 32 tokens
    #pragma unroll
    for (int pass = 0; pass < 4; ++pass) {
        const int tok = pass * 32 + (t >> 3);
        const int c8 = (t & 7) * 8;
        bf8 v = *(const bf8*)&sQb[tok][c8];
        float f[8];
        #pragma unroll
        for (int j = 0; j < 8; ++j) f[j] = (float)v[j];
        float m = f[0];
        #pragma unroll
        for (int j = 1; j < 8; ++j) m = fmaxf(m, f[j]);
        #pragma unroll
        for (int off = 1; off < 8; off <<= 1) m = fmaxf(m, __shfl_xor(m, off));
        float s = 0.f;
        #pragma unroll
        for (int j = 0; j < 8; ++j) { f[j] = __expf(f[j] - m); s += f[j]; }
        #pragma unroll
        for (int off = 1; off < 8; off <<= 1) s += __shfl_xor(s, off);
        const float inv = QSCALE / s;
        #pragma unroll
        for (int j = 0; j < 8; ++j) v[j] = (__bf16)(f[j] * inv);
        *(bf8*)&sQb[tok][c8] = v;
    }
    __syncthreads();

    f32x4 acc[2][4] = {};
    #pragma unroll
    for (int ksp = 0; ksp < 2; ++ksp) {
        const int kk = ksp * 32;
        bf8 af[2];
        #pragma unroll
        for (int mi = 0; mi < 2; ++mi)
            af[mi] = *(const bf8*)&sQb[w * 32 + mi * 16 + l16][kk + quad * 8];
        #pragma unroll
        for (int mi = 0; mi < 2; ++mi)
            #pragma unroll
            for (int ni = 0; ni < 4; ++ni)
                acc[mi][ni] = __builtin_amdgcn_mfma_f32_16x16x32_bf16(
                    af[mi], bfr[ksp][ni], acc[mi][ni], 0, 0, 0);
    }
    __syncthreads();   // sQb reads done -> safe to reuse as C-tile

    // dump acc -> sQb [128 rows][64 cols], then 128B coalesced stores
    #pragma unroll
    for (int mi = 0; mi < 2; ++mi)
        #pragma unroll
        for (int ni = 0; ni < 4; ++ni)
            #pragma unroll
            for (int r = 0; r < 4; ++r)
                sQb[w * 32 + mi * 16 + quad * 4 + r][ni * 16 + l16] =
                    (__bf16)acc[mi][ni][r];
    __syncthreads();
    bf16_t* xob = xoT + (size_t)b * KVSTRIDE;
    #pragma unroll
    for (int i = 0; i < 4; ++i) {
        int e = t + i * 256;               // 1024 = 128 rows x 8 segs
        int rr = e >> 3, seg = (e & 7) * 8;
        bf8 v = *(const bf8*)&sQb[rr][seg];
        *(bf8*)&xob[(size_t)(p0 + rr) * NC + h * 64 + seg] = v;
    }
}

// ---------------------------------------------------------------------------
// H: out = y/max(sqrt(ysq),eps)*g2*sqrtC + x (fp32 out). grid(1024, 8) b256.
// ---------------------------------------------------------------------------
__global__ __launch_bounds__(256) void
final_kernel(const bf16_t* __restrict__ y, const float* __restrict__ ysq,
             const float* __restrict__ g2, const float* __restrict__ x,
             float* __restrict__ out) {
    const int b = blockIdx.y;
    int idx = blockIdx.x * 256 + threadIdx.x;      // [0, 262144)
    int o = idx >> 9;
    int p8 = (idx & 511) * 8;
    const bf16_t* yb = y + (size_t)b * QSTRIDE;
    const float* xb = x + (size_t)b * QSTRIDE;
    float* outb = out + (size_t)b * QSTRIDE;
    const float* sq = ysq + (size_t)b * NP;

    bf8 yv = *(const bf8*)&yb[(size_t)o * NP + p8];
    float gv = g2[o] * SQRTC;
    float4 a = *(const float4*)&xb[(size_t)o * NP + p8];
    float4 b2 = *(const float4*)&xb[(size_t)o * NP + p8 + 4];
    float inb[8];
    #pragma unroll
    for (int j = 0; j < 8; ++j)
        inb[j] = 1.0f / fmaxf(sqrtf(sq[p8 + j]), 1e-12f);

    float4 r0, r1;
    r0.x = (float)yv[0] * inb[0] * gv + a.x;
    r0.y = (float)yv[1] * inb[1] * gv + a.y;
    r0.z = (float)yv[2] * inb[2] * gv + a.z;
    r0.w = (float)yv[3] * inb[3] * gv + a.w;
    r1.x = (float)yv[4] * inb[4] * gv + b2.x;
    r1.y = (float)yv[5] * inb[5] * gv + b2.y;
    r1.z = (float)yv[6] * inb[6] * gv + b2.z;
    r1.w = (float)yv[7] * inb[7] * gv + b2.w;
    *(float4*)&outb[(size_t)o * NP + p8] = r0;
    *(float4*)&outb[(size_t)o * NP + p8 + 4] = r1;
}

// ---------------------------------------------------------------------------
extern "C" void kernel_launch(void* const* d_in, const int* in_sizes, int n_in,
                              void* d_out, int out_size, void* d_ws, size_t ws_size,
                              hipStream_t stream) {
    const float* x     = (const float*)d_in[0];
    const float* g     = (const float*)d_in[1];
    const float* qkv_w = (const float*)d_in[2];
    const float* ffn_w = (const float*)d_in[3];
    const float* ffn_b = (const float*)d_in[4];
    const float* ffn_g = (const float*)d_in[5];
    float* out = (float*)d_out;
    bf16_t* kv = (bf16_t*)d_out;     // 8*KVSTRIDE bf16 = 64 MiB (K,V then xoT)

    // ws gate: full 8-batch xnT (69.4 MB layout) vs 2-batch chunks (44.2 MB)
    // Full layout:   q | xnT (8 batches) | Wg | Wf | kmax | kinv | ysq
    // Chunk layout:  q | xnT2 (2 batches) | Wg | Wf | kmax | kinv | ysq
    // attnP aliases the front of the xnT region in both (disjoint lifetime);
    // attnF aliases dead Wg in both.
    const size_t FULL_BYTES =
        (8 * QSTRIDE + 8 * QSTRIDE + 786432 + 262144) * sizeof(bf16_t) +
        (8 * 512 + 8 * 512 + 8 * (size_t)NP) * sizeof(float);
    const bool full = ws_size >= FULL_BYTES;

    bf16_t* q    = (bf16_t*)d_ws;                    // 8*QSTRIDE bf16 (Q, then y)
    bf16_t* xnT  = q + 8 * QSTRIDE;                  // 8 or 2 batches
    bf16_t* Wg   = xnT + (full ? 8 : 2) * QSTRIDE;   // 786432 bf16
    float*  attnP = (float*)xnT;                     // 8.39 MB (after xnT dead)
    bf16_t* attnF = Wg;                              // 512 KB (after Wg dead)
    bf16_t* Wf   = Wg + 786432;                      // 262144 bf16
    float*  kmax = (float*)(Wf + 262144);            // 8*512 f32
    float*  kinv = kmax + 8 * 512;                   // 8*512 f32
    float*  ysq  = kinv + 8 * 512;                   // 8*4096 f32

    wconv_kernel<<<dim3(1024), 256, 0, stream>>>(qkv_w, g, ffn_w, Wg, Wf);

    if (full) {
        // one nt launch (1024 blocks) + one QKV GEMM launch (3072 blocks)
        norm_transpose_kernel<<<dim3(128, 8), 512, 0, stream>>>(x, xnT);
        gemm_qkv_kernel<<<dim3(32, 12, 8), 256, 0, stream>>>(Wg, xnT, q, kv);
    } else {
        // chunked: normalize+transpose 2 batches, then their QKV GEMM
        for (int c = 0; c < 4; ++c) {
            norm_transpose_kernel<<<dim3(128, 2), 512, 0, stream>>>(
                x + (size_t)(2 * c) * QSTRIDE, xnT);
            gemm_qkv_kernel<<<dim3(32, 12, 2), 256, 0, stream>>>(
                Wg, xnT, q + (size_t)(2 * c) * QSTRIDE,
                kv + (size_t)(2 * c) * KVSTRIDE);
        }
    }

    kstats_kernel<<<dim3(512, 8), 256, 0, stream>>>(kv, kmax, kinv);
    attn_kernel<<<dim3(8, 8, 8), 256, 0, stream>>>(kv, kmax, attnP);
    attnsum_kernel<<<dim3(64, 4), 256, 0, stream>>>(attnP, kinv, attnF, ysq);
    outgemm_kernel<<<dim3(32, 8, 8), 256, 0, stream>>>(q, attnF, kv);
    gemm_ffn_kernel<<<dim3(32, 4, 8), 256, 0, stream>>>(Wf, kv, ffn_b, q, ysq);
    final_kernel<<<dim3(1024, 8), 256, 0, stream>>>(q, ysq, ffn_g, x, out);
}

// Round 7
// 305.148 us; speedup vs baseline: 1.3014x; 1.0479x over previous
//
#include <hip/hip_runtime.h>

// ---------------------------------------------------------------------------
// MultiHeadsLinearAttention  (B=8, C=512, HEADS=8, CH=64, H=W=64 -> N=4096)
// Inputs fp32, output fp32. Compute: bf16 MFMA, fp32 accumulation.
//
// Stages:
//  W : Wg = qkv_w * g -> bf16 ; Wf = ffn_w -> bf16 (single merged launch)
//  T : per-token invx over fp32 x; xnT[p][c] = x*invx*sqrtC (bf16, k-contig)
//  C : QKV GEMM (128x128 tile, BK=64, global_load_lds width-16 staging,
//      R7: T2 XOR swizzle — LINEAR LDS dest + permuted SOURCE + XOR READ):
//      rows<512 -> Q (ws), else K,V (d_out); LDS-staged coalesced epilogue
//  D : k-softmax stats (kmax,kinv)
//  E : attnP[bh][ks][d][c] = sum_{p in ks-slice} exp(k[c][p]-kmax)*v[d][p]
//  E2: attnsum: attnF = (sum_ks attnP) * kinv -> bf16 (+ zeroes ysq)
//  F : q-softmax per token (wave-parallel 8-lane shfl) ; xoT = qsm @ attnF
//  G : FFN GEMM y = ffn_b + Wf @ xoT (same R7 swizzle); ysq epilogue
//  H : out = y/max(sqrt(ysq),eps)*g2*sqrtC + x (fp32)
//
// R6 counters: gemm_qkv 93us, SQ_LDS_BANK_CONFLICT 19.27M, MfmaUtil 21.6%.
// Root cause: linear [128][64] bf16 tile row stride = 128B = bank period ->
// ds_read_b128 fragment reads are 16-way conflicts (T2 regime, m201).
// R7 fix (rule #21 both-sides pairing, m173/m201): LDS dest stays LINEAR
// (wave-uniform base + lane*16); each lane's GLOBAL source k-granule is
// permuted kseg = (ln&7)^lrow (within the same 128B row span -> identical
// coalescing); ds_read applies kseg^(row&7). 16 lanes -> 8 slots x2 = 2-way
// alias (free, m136). NOTE prior-session scar "gload_lds+swizzle diverged"
// matched a DEST-side/mispaired swizzle; this is the verified source/read
// pairing. If this diverges -> revert permanently.
// Round-8 lesson: 8.4M contended atomics in attn -> partials + wave-spec.
// R1 lesson: outgemm re-summed attnP 32x -> attnsum collapses once.
// ---------------------------------------------------------------------------

typedef __bf16 bf16_t;
typedef __bf16 bf8 __attribute__((ext_vector_type(8)));
typedef float f32x4 __attribute__((ext_vector_type(4)));

#define NC 512
#define NP 4096
#define SQRTC 22.62741699796952f
#define QSCALE 0.125f
#define QSTRIDE  ((size_t)NC * NP)      // 2097152  per-batch 512-row elems
#define KVSTRIDE ((size_t)1024 * NP)    // 4194304  per-batch kv elems (d_out)
#define LDC 136                          // epilogue C-tile stride (bank-spread)

__device__ inline unsigned short bfbits(__bf16 h) {
    return __builtin_bit_cast(unsigned short, h);
}

// async global->LDS, 16B per lane. LDS dest must be wave-uniform base;
// HW writes base + lane*16.
__device__ __forceinline__ void gload_lds16(const bf16_t* g, __bf16* l) {
    __builtin_amdgcn_global_load_lds(
        (const __attribute__((address_space(1))) void*)g,
        (__attribute__((address_space(3))) void*)l, 16, 0, 0);
}

// ---------------------------------------------------------------------------
// W: both weight converts in one launch. blocks 0..767: Wg = qkv_w * g;
// blocks 768..1023: Wf = ffn_w. 4 elems/thread.
// ---------------------------------------------------------------------------
__global__ __launch_bounds__(256) void
wconv_kernel(const float* __restrict__ qkv_w, const float* __restrict__ g,
             const float* __restrict__ ffn_w, bf16_t* __restrict__ Wg,
             bf16_t* __restrict__ Wf) {
    const int bx = blockIdx.x;
    if (bx < 768) {
        int i0 = (bx * 256 + threadIdx.x) * 4;
        float4 wv = *(const float4*)&qkv_w[i0];
        const float4 gv = *(const float4*)&g[i0 & 511];
        ushort4 o;
        o.x = bfbits((__bf16)(wv.x * gv.x));
        o.y = bfbits((__bf16)(wv.y * gv.y));
        o.z = bfbits((__bf16)(wv.z * gv.z));
        o.w = bfbits((__bf16)(wv.w * gv.w));
        *(ushort4*)&Wg[i0] = o;
    } else {
        int i0 = ((bx - 768) * 256 + threadIdx.x) * 4;
        float4 wv = *(const float4*)&ffn_w[i0];
        ushort4 o;
        o.x = bfbits((__bf16)wv.x);
        o.y = bfbits((__bf16)wv.y);
        o.z = bfbits((__bf16)wv.z);
        o.w = bfbits((__bf16)wv.w);
        *(ushort4*)&Wf[i0] = o;
    }
}

// ---------------------------------------------------------------------------
// T: norm + transpose. grid(128, nb) block 512. Block covers 32 tokens of
// batch blockIdx.y. xnT[p][c] = x[c][p] * sqrtC/max(||x[:,p]||,1e-12)
// ---------------------------------------------------------------------------
__global__ __launch_bounds__(512) void
norm_transpose_kernel(const float* __restrict__ x, bf16_t* __restrict__ xnT) {
    const int bl = blockIdx.y;
    const int p0 = blockIdx.x * 32;
    const int t = threadIdx.x;
    const float* xb = x + (size_t)bl * QSTRIDE;
    bf16_t* ob = xnT + (size_t)bl * QSTRIDE;

    // pass 1: thread (cg = t&7, r0 = t>>3) accumulates x^2 for tokens
    // [p0 + cg*4, +4) over rows {r0 + 64k}.
    const int cg = t & 7, r0 = t >> 3;
    f32x4 ss = {0.f, 0.f, 0.f, 0.f};
    #pragma unroll
    for (int k = 0; k < 8; ++k) {
        const int c = r0 + k * 64;
        float4 v = *(const float4*)&xb[(size_t)c * NP + p0 + cg * 4];
        ss.x += v.x * v.x; ss.y += v.y * v.y;
        ss.z += v.z * v.z; ss.w += v.w * v.w;
    }
    #pragma unroll
    for (int m = 8; m <= 32; m <<= 1) {
        ss.x += __shfl_xor(ss.x, m); ss.y += __shfl_xor(ss.y, m);
        ss.z += __shfl_xor(ss.z, m); ss.w += __shfl_xor(ss.w, m);
    }
    __shared__ float sP[8][34];
    __shared__ float sInv[32];
    const int w = t >> 6;
    if ((t & 63) < 8) {
        const int p = (t & 7) * 4;
        sP[w][p] = ss.x; sP[w][p + 1] = ss.y;
        sP[w][p + 2] = ss.z; sP[w][p + 3] = ss.w;
    }
    __syncthreads();
    if (t < 32) {
        float tot = 0.f;
        #pragma unroll
        for (int j = 0; j < 8; ++j) tot += sP[j][t];
        sInv[t] = SQRTC / fmaxf(sqrtf(tot), 1e-12f);
    }
    __syncthreads();

    // pass 2: 128-c x 32-p chunks through LDS transpose, float4 loads
    __shared__ __bf16 sT[128][41];
    for (int cc = 0; cc < 512; cc += 128) {
        #pragma unroll
        for (int j = 0; j < 2; ++j) {
            int idx = t + j * 512;               // [0,1024): 128 cr x 8 pg
            int cr = idx >> 3, pg = idx & 7;
            float4 v = *(const float4*)&xb[(size_t)(cc + cr) * NP + p0 + pg * 4];
            sT[cr][pg * 4 + 0] = (__bf16)(v.x * sInv[pg * 4 + 0]);
            sT[cr][pg * 4 + 1] = (__bf16)(v.y * sInv[pg * 4 + 1]);
            sT[cr][pg * 4 + 2] = (__bf16)(v.z * sInv[pg * 4 + 2]);
            sT[cr][pg * 4 + 3] = (__bf16)(v.w * sInv[pg * 4 + 3]);
        }
        __syncthreads();
        {
            int p = t >> 4, c8 = (t & 15) * 8;
            bf8 v;
            #pragma unroll
            for (int q = 0; q < 8; ++q) v[q] = sT[c8 + q][p];
            *(bf8*)&ob[(size_t)(p0 + p) * NC + cc + c8] = v;
        }
        __syncthreads();
    }
}

// ---------------------------------------------------------------------------
// C: QKV GEMM. grid(32, 12, nb) block 256.
// A = Wg [1536][512], B = xnT [p][c] (both k-contiguous bf16).
// 128x128 tile, BK=64, 4 waves of 64x64. gload_lds linear staging with
// T2 source-permutation swizzle; XOR ds_read. LDS-staged epilogue.
// ---------------------------------------------------------------------------
__global__ __launch_bounds__(256) void
gemm_qkv_kernel(const bf16_t* __restrict__ Wg, const bf16_t* __restrict__ xnT,
                bf16_t* __restrict__ qout, bf16_t* __restrict__ kvout) {
    const int bn = blockIdx.x, bm = blockIdx.y, b = blockIdx.z;
    const int t = threadIdx.x;
    const int w = t >> 6, ln = t & 63, quad = ln >> 4, l16 = ln & 15;
    const int wm = w >> 1, wn = w & 1;

    // K-loop: A [0,8192), B [8192,16384). Epilogue C-tile: [128][LDC].
    __shared__ __align__(16) __bf16 sAB[128 * LDC];
    __bf16* const sA = sAB;
    __bf16* const sB = sAB + 8192;

    f32x4 acc[4][4] = {};
    const bf16_t* Abase = Wg + (size_t)(bm * 128) * NC;
    const bf16_t* Bbase = xnT + (size_t)b * QSTRIDE + (size_t)(bn * 128) * NC;

    // staging: chunk covers rows [chunk*8, +8), each row's 8 k-granules
    // PERMUTED: lane (lrow, s) fetches kseg = s ^ lrow of row chunk*8+lrow.
    // LDS granule G = chunk*64 + lane holds (row = G/8, kseg = (G&7)^(row&7)).
    const int lrow = ln >> 3;                 // 0..7
    const int lkc = ((ln & 7) ^ lrow) * 8;    // permuted k offset (same 128B span)
    const int xr = l16 & 7;                   // read-side XOR key (row&7)

    for (int kt = 0; kt < 8; ++kt) {
        const int k0 = kt * 64;
        #pragma unroll
        for (int i = 0; i < 4; ++i) {
            const int chunk = w * 4 + i;          // 0..15, wave-uniform
            const int row = chunk * 8 + lrow;
            gload_lds16(Abase + (size_t)row * NC + k0 + lkc, &sA[chunk * 512]);
            gload_lds16(Bbase + (size_t)row * NC + k0 + lkc, &sB[chunk * 512]);
        }
        __syncthreads();
        #pragma unroll
        for (int ks = 0; ks < 2; ++ks) {
            bf8 af[4], bfr[4];
            const int kx = ((ks * 4 + quad) ^ xr) << 3;   // swizzled k offset
            #pragma unroll
            for (int mi = 0; mi < 4; ++mi)
                af[mi] = *(const bf8*)&sA[(wm * 64 + mi * 16 + l16) * 64 + kx];
            #pragma unroll
            for (int ni = 0; ni < 4; ++ni)
                bfr[ni] = *(const bf8*)&sB[(wn * 64 + ni * 16 + l16) * 64 + kx];
            #pragma unroll
            for (int mi = 0; mi < 4; ++mi)
                #pragma unroll
                for (int ni = 0; ni < 4; ++ni)
                    acc[mi][ni] = __builtin_amdgcn_mfma_f32_16x16x32_bf16(
                        af[mi], bfr[ni], acc[mi][ni], 0, 0, 0);
        }
        __syncthreads();
    }

    // epilogue: dump acc into LDS C-tile, then coalesced 16B stores
    {
        const int rbase = wm * 64 + quad * 4;
        const int cbase = wn * 64 + l16;
        #pragma unroll
        for (int mi = 0; mi < 4; ++mi)
            #pragma unroll
            for (int ni = 0; ni < 4; ++ni)
                #pragma unroll
                for (int r = 0; r < 4; ++r)
                    sAB[(rbase + mi * 16 + r) * LDC + cbase + ni * 16] =
                        (__bf16)acc[mi][ni][r];
    }
    __syncthreads();
    bf16_t* qb = qout + (size_t)b * QSTRIDE;
    bf16_t* kvb = kvout + (size_t)b * KVSTRIDE;
    const int p0 = bn * 128;
    #pragma unroll
    for (int i = 0; i < 8; ++i) {
        int e = t + i * 256;               // 2048 = 128 rows x 16 segs
        int rr = e >> 4, seg = (e & 15) * 8;
        bf8 v = *(const bf8*)&sAB[rr * LDC + seg];
        int row = bm * 128 + rr;
        if (row < 512)
            *(bf8*)&qb[(size_t)row * NP + p0 + seg] = v;
        else
            *(bf8*)&kvb[(size_t)(row - 512) * NP + p0 + seg] = v;
    }
}

// ---------------------------------------------------------------------------
// G: FFN GEMM. grid(32, 4, 8) block 256. Same R7 swizzle as QKV GEMM.
// A = Wf [512][512], B = xoT [p][c] (d_out K region), out y (+bias) -> ws.
// Epilogue: per-column sumsq into ysq, then LDS-staged coalesced C-write.
// ---------------------------------------------------------------------------
__global__ __launch_bounds__(256) void
gemm_ffn_kernel(const bf16_t* __restrict__ Wf, const bf16_t* __restrict__ xoT,
                const float* __restrict__ bias, bf16_t* __restrict__ y,
                float* __restrict__ ysq) {
    const int bn = blockIdx.x, bm = blockIdx.y, b = blockIdx.z;
    const int t = threadIdx.x;
    const int w = t >> 6, ln = t & 63, quad = ln >> 4, l16 = ln & 15;
    const int wm = w >> 1, wn = w & 1;

    __shared__ __align__(16) __bf16 sAB[128 * LDC];
    __bf16* const sA = sAB;
    __bf16* const sB = sAB + 8192;

    f32x4 acc[4][4] = {};
    const bf16_t* Abase = Wf + (size_t)(bm * 128) * NC;
    const bf16_t* Bbase = xoT + (size_t)b * KVSTRIDE + (size_t)(bn * 128) * NC;

    const int lrow = ln >> 3;
    const int lkc = ((ln & 7) ^ lrow) * 8;
    const int xr = l16 & 7;

    for (int kt = 0; kt < 8; ++kt) {
        const int k0 = kt * 64;
        #pragma unroll
        for (int i = 0; i < 4; ++i) {
            const int chunk = w * 4 + i;
            const int row = chunk * 8 + lrow;
            gload_lds16(Abase + (size_t)row * NC + k0 + lkc, &sA[chunk * 512]);
            gload_lds16(Bbase + (size_t)row * NC + k0 + lkc, &sB[chunk * 512]);
        }
        __syncthreads();
        #pragma unroll
        for (int ks = 0; ks < 2; ++ks) {
            bf8 af[4], bfr[4];
            const int kx = ((ks * 4 + quad) ^ xr) << 3;
            #pragma unroll
            for (int mi = 0; mi < 4; ++mi)
                af[mi] = *(const bf8*)&sA[(wm * 64 + mi * 16 + l16) * 64 + kx];
            #pragma unroll
            for (int ni = 0; ni < 4; ++ni)
                bfr[ni] = *(const bf8*)&sB[(wn * 64 + ni * 16 + l16) * 64 + kx];
            #pragma unroll
            for (int mi = 0; mi < 4; ++mi)
                #pragma unroll
                for (int ni = 0; ni < 4; ++ni)
                    acc[mi][ni] = __builtin_amdgcn_mfma_f32_16x16x32_bf16(
                        af[mi], bfr[ni], acc[mi][ni], 0, 0, 0);
        }
        __syncthreads();
    }

    // ysq epilogue (register layout) + dump bf16-rounded y into LDS C-tile
    float* sq = ysq + (size_t)b * NP;
    const int p0 = bn * 128;
    {
        const int rbase = wm * 64 + quad * 4;
        #pragma unroll
        for (int ni = 0; ni < 4; ++ni) {
            const int col = p0 + wn * 64 + ni * 16 + l16;
            float colsq = 0.f;
            #pragma unroll
            for (int mi = 0; mi < 4; ++mi) {
                #pragma unroll
                for (int r = 0; r < 4; ++r) {
                    const int row = bm * 128 + rbase + mi * 16 + r;
                    __bf16 vb = (__bf16)(acc[mi][ni][r] + bias[row]);
                    sAB[(rbase + mi * 16 + r) * LDC + wn * 64 + ni * 16 + l16] = vb;
                    float vf = (float)vb;
                    colsq += vf * vf;
                }
            }
            colsq += __shfl_xor(colsq, 16);
            colsq += __shfl_xor(colsq, 32);
            if (quad == 0) atomicAdd(&sq[col], colsq);
        }
    }
    __syncthreads();
    bf16_t* yb = y + (size_t)b * QSTRIDE;
    #pragma unroll
    for (int i = 0; i < 8; ++i) {
        int e = t + i * 256;
        int rr = e >> 4, seg = (e & 15) * 8;
        bf8 v = *(const bf8*)&sAB[rr * LDC + seg];
        *(bf8*)&yb[(size_t)(bm * 128 + rr) * NP + p0 + seg] = v;
    }
}

// ---------------------------------------------------------------------------
// D: k-softmax stats per (b, channel) row. grid(512, 8) block 256.
// ---------------------------------------------------------------------------
__global__ __launch_bounds__(256) void
kstats_kernel(const bf16_t* __restrict__ kv, float* __restrict__ kmax,
              float* __restrict__ kinv) {
    const int oc = blockIdx.x, b = blockIdx.y;
    const int t = threadIdx.x, w = t >> 6, ln = t & 63;

    const bf16_t* row = kv + (size_t)b * KVSTRIDE + (size_t)oc * NP;
    float v[16];
    bf8 x0 = *(const bf8*)&row[t * 8];
    bf8 x1 = *(const bf8*)&row[2048 + t * 8];
    #pragma unroll
    for (int j = 0; j < 8; ++j) { v[j] = (float)x0[j]; v[8 + j] = (float)x1[j]; }

    float m = v[0];
    #pragma unroll
    for (int j = 1; j < 16; ++j) m = fmaxf(m, v[j]);
    #pragma unroll
    for (int off = 32; off > 0; off >>= 1) m = fmaxf(m, __shfl_down(m, off));
    __shared__ float sR[4];
    __shared__ float sS[4];
    if (ln == 0) sR[w] = m;
    __syncthreads();
    m = fmaxf(fmaxf(sR[0], sR[1]), fmaxf(sR[2], sR[3]));

    float s = 0.f;
    #pragma unroll
    for (int j = 0; j < 16; ++j) s += __expf(v[j] - m);
    #pragma unroll
    for (int off = 32; off > 0; off >>= 1) s += __shfl_down(s, off);
    if (ln == 0) sS[w] = s;
    __syncthreads();
    if (t == 0) {
        kmax[b * 512 + oc] = m;
        kinv[b * 512 + oc] = 1.0f / (sS[0] + sS[1] + sS[2] + sS[3]);
    }
}

// ---------------------------------------------------------------------------
// E: attnP[bh][ks][d][c] = sum_{p in slice} exp(k[c][p]-kmax[c]) * v[d][p].
// grid(8, 8, 8) block 256. Wave w owns d rows [w*16, w*16+16): no reduction,
// no atomics, no LDS. Each ks-slice covers 512 p (16 iters of 32 p).
// ---------------------------------------------------------------------------
__global__ __launch_bounds__(256) void
attn_kernel(const bf16_t* __restrict__ kv, const float* __restrict__ kmax,
            float* __restrict__ attnP) {
    const int h = blockIdx.x, ks = blockIdx.y, b = blockIdx.z;
    const int t = threadIdx.x, w = t >> 6, ln = t & 63, quad = ln >> 4, l16 = ln & 15;

    const bf16_t* Kb = kv + (size_t)b * KVSTRIDE + (size_t)(h * 64) * NP;
    const bf16_t* Vb = kv + (size_t)b * KVSTRIDE + (size_t)(512 + h * 64 + w * 16) * NP;

    float km[4];
    #pragma unroll
    for (int mi = 0; mi < 4; ++mi) km[mi] = kmax[b * 512 + h * 64 + mi * 16 + l16];

    f32x4 acc[4] = {};
    const int pbase = ks * 512 + quad * 8;
    #pragma unroll 4
    for (int it = 0; it < 16; ++it) {
        const int p0 = pbase + it * 32;
        bf8 bfr = *(const bf8*)&Vb[(size_t)l16 * NP + p0];
        #pragma unroll
        for (int mi = 0; mi < 4; ++mi) {
            bf8 kr = *(const bf8*)&Kb[(size_t)(mi * 16 + l16) * NP + p0];
            bf8 af;
            #pragma unroll
            for (int j = 0; j < 8; ++j)
                af[j] = (__bf16)__expf((float)kr[j] - km[mi]);
            acc[mi] = __builtin_amdgcn_mfma_f32_16x16x32_bf16(af, bfr, acc[mi], 0, 0, 0);
        }
    }

    // D layout: row (=c within mi-block) = quad*4+r, col (=d) = l16.
    float* outp = attnP + (((size_t)(b * 8 + h) * 8 + ks) << 12);
    #pragma unroll
    for (int mi = 0; mi < 4; ++mi) {
        float4 v;
        v.x = acc[mi][0]; v.y = acc[mi][1]; v.z = acc[mi][2]; v.w = acc[mi][3];
        *(float4*)&outp[(w * 16 + l16) * 64 + mi * 16 + quad * 4] = v;
    }
}

// ---------------------------------------------------------------------------
// E2: attnF[bh][d][c] = (sum_ks attnP[bh][ks][d][c]) * kinv[b][h*64+c] -> bf16
// grid(64, 4) block 256. Collapses the 8 p-partials ONCE. attnF aliases dead
// Wg. Also zeroes ysq (stream-ordered before gemm_ffn's accumulation).
// ---------------------------------------------------------------------------
__global__ __launch_bounds__(256) void
attnsum_kernel(const float* __restrict__ attnP, const float* __restrict__ kinv,
               bf16_t* __restrict__ attnF, float* __restrict__ ysq) {
    const int gtid = (blockIdx.x * 4 + blockIdx.y) * 256 + threadIdx.x;
    if (gtid < 8 * NP) ysq[gtid] = 0.f;

    const int bh = blockIdx.x;                     // b*8 + h
    const int e0 = blockIdx.y * 1024 + threadIdx.x * 4;
    const float* ap = attnP + ((size_t)bh << 15);  // 8 slices of 4096
    float4 s = {0.f, 0.f, 0.f, 0.f};
    #pragma unroll
    for (int ks = 0; ks < 8; ++ks) {
        float4 v = *(const float4*)&ap[(ks << 12) + e0];
        s.x += v.x; s.y += v.y; s.z += v.z; s.w += v.w;
    }
    const float* kvp = kinv + (bh >> 3) * 512 + (bh & 7) * 64;
    const int c = e0 & 63;
    ushort4 o;
    o.x = bfbits((__bf16)(s.x * kvp[c]));
    o.y = bfbits((__bf16)(s.y * kvp[c + 1]));
    o.z = bfbits((__bf16)(s.z * kvp[c + 2]));
    o.w = bfbits((__bf16)(s.w * kvp[c + 3]));
    *(ushort4*)&attnF[((size_t)bh << 12) + e0] = o;
}

// ---------------------------------------------------------------------------
// F: q softmax over ch (*SCALE) then xoT[p][h*64+d] = qsm @ attnF.
// grid(32, 8, 8) block 256. attnF B-frags direct from global (L2-resident,
// loads hoisted above the softmax). Softmax wave-parallel: 8 lanes/token.
// Epilogue: LDS-staged (reuses sQb) -> 128B coalesced segments.
// ---------------------------------------------------------------------------
__global__ __launch_bounds__(256) void
outgemm_kernel(const bf16_t* __restrict__ q, const bf16_t* __restrict__ attnF,
               bf16_t* __restrict__ xoT) {
    const int pt = blockIdx.x, h = blockIdx.y, b = blockIdx.z;
    const int p0 = pt * 128;
    const int t = threadIdx.x, w = t >> 6, ln = t & 63, quad = ln >> 4, l16 = ln & 15;

    __shared__ __align__(16) __bf16 sQb[128][72];   // [p][c], 18 KB

    // hoist B-fragment loads (L2-hot attnF) so latency hides under softmax
    const bf16_t* aF = attnF + ((size_t)(b * 8 + h) << 12);
    bf8 bfr[2][4];
    #pragma unroll
    for (int ksp = 0; ksp < 2; ++ksp)
        #pragma unroll
        for (int ni = 0; ni < 4; ++ni)
            bfr[ksp][ni] = *(const bf8*)&aF[(ni * 16 + l16) * 64 + ksp * 32 + quad * 8];

    const bf16_t* qb = q + (size_t)b * QSTRIDE;
    #pragma unroll
    for (int i = 0; i < 32; ++i) {
        int e = t + i * 256;             // c*128 + p
        int c = e >> 7, p = e & 127;
        sQb[p][c] = qb[(size_t)(h * 64 + c) * NP + p0 + p];
    }
    __syncthreads();

    // wave-parallel q-softmax: 8 lanes per token, 4 passes of 32 tokens
    #pragma unroll
    for (int pass = 0; pass < 4; ++pass) {
        const int tok = pass * 32 + (t >> 3);
        const int c8 = (t & 7) * 8;
        bf8 v = *(const bf8*)&sQb[tok][c8];
        float f[8];
        #pragma unroll
        for (int j = 0; j < 8; ++j) f[j] = (float)v[j];
        float m = f[0];
        #pragma unroll
        for (int j = 1; j < 8; ++j) m = fmaxf(m, f[j]);
        #pragma unroll
        for (int off = 1; off < 8; off <<= 1) m = fmaxf(m, __shfl_xor(m, off));
        float s = 0.f;
        #pragma unroll
        for (int j = 0; j < 8; ++j) { f[j] = __expf(f[j] - m); s += f[j]; }
        #pragma unroll
        for (int off = 1; off < 8; off <<= 1) s += __shfl_xor(s, off);
        const float inv = QSCALE / s;
        #pragma unroll
        for (int j = 0; j < 8; ++j) v[j] = (__bf16)(f[j] * inv);
        *(bf8*)&sQb[tok][c8] = v;
    }
    __syncthreads();

    f32x4 acc[2][4] = {};
    #pragma unroll
    for (int ksp = 0; ksp < 2; ++ksp) {
        const int kk = ksp * 32;
        bf8 af[2];
        #pragma unroll
        for (int mi = 0; mi < 2; ++mi)
            af[mi] = *(const bf8*)&sQb[w * 32 + mi * 16 + l16][kk + quad * 8];
        #pragma unroll
        for (int mi = 0; mi < 2; ++mi)
            #pragma unroll
            for (int ni = 0; ni < 4; ++ni)
                acc[mi][ni] = __builtin_amdgcn_mfma_f32_16x16x32_bf16(
                    af[mi], bfr[ksp][ni], acc[mi][ni], 0, 0, 0);
    }
    __syncthreads();   // sQb reads done -> safe to reuse as C-tile

    // dump acc -> sQb [128 rows][64 cols], then 128B coalesced stores
    #pragma unroll
    for (int mi = 0; mi < 2; ++mi)
        #pragma unroll
        for (int ni = 0; ni < 4; ++ni)
            #pragma unroll
            for (int r = 0; r < 4; ++r)
                sQb[w * 32 + mi * 16 + quad * 4 + r][ni * 16 + l16] =
                    (__bf16)acc[mi][ni][r];
    __syncthreads();
    bf16_t* xob = xoT + (size_t)b * KVSTRIDE;
    #pragma unroll
    for (int i = 0; i < 4; ++i) {
        int e = t + i * 256;               // 1024 = 128 rows x 8 segs
        int rr = e >> 3, seg = (e & 7) * 8;
        bf8 v = *(const bf8*)&sQb[rr][seg];
        *(bf8*)&xob[(size_t)(p0 + rr) * NC + h * 64 + seg] = v;
    }
}

// ---------------------------------------------------------------------------
// H: out = y/max(sqrt(ysq),eps)*g2*sqrtC + x (fp32 out). grid(1024, 8) b256.
// ---------------------------------------------------------------------------
__global__ __launch_bounds__(256) void
final_kernel(const bf16_t* __restrict__ y, const float* __restrict__ ysq,
             const float* __restrict__ g2, const float* __restrict__ x,
             float* __restrict__ out) {
    const int b = blockIdx.y;
    int idx = blockIdx.x * 256 + threadIdx.x;      // [0, 262144)
    int o = idx >> 9;
    int p8 = (idx & 511) * 8;
    const bf16_t* yb = y + (size_t)b * QSTRIDE;
    const float* xb = x + (size_t)b * QSTRIDE;
    float* outb = out + (size_t)b * QSTRIDE;
    const float* sq = ysq + (size_t)b * NP;

    bf8 yv = *(const bf8*)&yb[(size_t)o * NP + p8];
    float gv = g2[o] * SQRTC;
    float4 a = *(const float4*)&xb[(size_t)o * NP + p8];
    float4 b2 = *(const float4*)&xb[(size_t)o * NP + p8 + 4];
    float inb[8];
    #pragma unroll
    for (int j = 0; j < 8; ++j)
        inb[j] = 1.0f / fmaxf(sqrtf(sq[p8 + j]), 1e-12f);

    float4 r0, r1;
    r0.x = (float)yv[0] * inb[0] * gv + a.x;
    r0.y = (float)yv[1] * inb[1] * gv + a.y;
    r0.z = (float)yv[2] * inb[2] * gv + a.z;
    r0.w = (float)yv[3] * inb[3] * gv + a.w;
    r1.x = (float)yv[4] * inb[4] * gv + b2.x;
    r1.y = (float)yv[5] * inb[5] * gv + b2.y;
    r1.z = (float)yv[6] * inb[6] * gv + b2.z;
    r1.w = (float)yv[7] * inb[7] * gv + b2.w;
    *(float4*)&outb[(size_t)o * NP + p8] = r0;
    *(float4*)&outb[(size_t)o * NP + p8 + 4] = r1;
}

// ---------------------------------------------------------------------------
extern "C" void kernel_launch(void* const* d_in, const int* in_sizes, int n_in,
                              void* d_out, int out_size, void* d_ws, size_t ws_size,
                              hipStream_t stream) {
    const float* x     = (const float*)d_in[0];
    const float* g     = (const float*)d_in[1];
    const float* qkv_w = (const float*)d_in[2];
    const float* ffn_w = (const float*)d_in[3];
    const float* ffn_b = (const float*)d_in[4];
    const float* ffn_g = (const float*)d_in[5];
    float* out = (float*)d_out;
    bf16_t* kv = (bf16_t*)d_out;     // 8*KVSTRIDE bf16 = 64 MiB (K,V then xoT)

    // ws gate: full 8-batch xnT layout vs 2-batch chunks (as R6)
    const size_t FULL_BYTES =
        (8 * QSTRIDE + 8 * QSTRIDE + 786432 + 262144) * sizeof(bf16_t) +
        (8 * 512 + 8 * 512 + 8 * (size_t)NP) * sizeof(float);
    const bool full = ws_size >= FULL_BYTES;

    bf16_t* q    = (bf16_t*)d_ws;                    // 8*QSTRIDE bf16 (Q, then y)
    bf16_t* xnT  = q + 8 * QSTRIDE;                  // 8 or 2 batches
    bf16_t* Wg   = xnT + (full ? 8 : 2) * QSTRIDE;   // 786432 bf16
    float*  attnP = (float*)xnT;                     // 8.39 MB (after xnT dead)
    bf16_t* attnF = Wg;                              // 512 KB (after Wg dead)
    bf16_t* Wf   = Wg + 786432;                      // 262144 bf16
    float*  kmax = (float*)(Wf + 262144);            // 8*512 f32
    float*  kinv = kmax + 8 * 512;                   // 8*512 f32
    float*  ysq  = kinv + 8 * 512;                   // 8*4096 f32

    wconv_kernel<<<dim3(1024), 256, 0, stream>>>(qkv_w, g, ffn_w, Wg, Wf);

    if (full) {
        norm_transpose_kernel<<<dim3(128, 8), 512, 0, stream>>>(x, xnT);
        gemm_qkv_kernel<<<dim3(32, 12, 8), 256, 0, stream>>>(Wg, xnT, q, kv);
    } else {
        for (int c = 0; c < 4; ++c) {
            norm_transpose_kernel<<<dim3(128, 2), 512, 0, stream>>>(
                x + (size_t)(2 * c) * QSTRIDE, xnT);
            gemm_qkv_kernel<<<dim3(32, 12, 2), 256, 0, stream>>>(
                Wg, xnT, q + (size_t)(2 * c) * QSTRIDE,
                kv + (size_t)(2 * c) * KVSTRIDE);
        }
    }

    kstats_kernel<<<dim3(512, 8), 256, 0, stream>>>(kv, kmax, kinv);
    attn_kernel<<<dim3(8, 8, 8), 256, 0, stream>>>(kv, kmax, attnP);
    attnsum_kernel<<<dim3(64, 4), 256, 0, stream>>>(attnP, kinv, attnF, ysq);
    outgemm_kernel<<<dim3(32, 8, 8), 256, 0, stream>>>(q, attnF, kv);
    gemm_ffn_kernel<<<dim3(32, 4, 8), 256, 0, stream>>>(Wf, kv, ffn_b, q, ysq);
    final_kernel<<<dim3(1024, 8), 256, 0, stream>>>(q, ysq, ffn_g, x, out);
}

// Round 9
// 304.317 us; speedup vs baseline: 1.3049x; 1.0027x over previous
//
#include <hip/hip_runtime.h>

// ---------------------------------------------------------------------------
// MultiHeadsLinearAttention  (B=8, C=512, HEADS=8, CH=64, H=W=64 -> N=4096)
// Inputs fp32, output fp32. Compute: bf16 MFMA, fp32 accumulation.
//
// R8 dataflow (outgemm ELIMINATED by associativity):
//   y = Wf @ (qsm @ attnF)  ==  (Wf_h @ attnF_h per head) @ qsm = Wff_b @ qsm
// Stages:
//  W : Wg = qkv_w * g -> bf16 ; Wf = ffn_w -> bf16 (fused into nt, full mode)
//  T : per-token invx over fp32 x; xnT[p][c] = x*invx*sqrtC (bf16, k-contig)
//  C : QKV GEMM (128x128, BK=64, gload_lds + R7 source-permutation swizzle).
//      bm<4 (Q, 128 rows = exactly 2 heads): epilogue does q-softmax on fp32
//      acc (per token over its head's 64 ch) and stores qsm in [p][c] layout.
//      bm>=4: K,V -> d_out as before.
//  D : k-softmax stats (kmax,kinv)
//  E : attnP partials (MFMA, wave-specialized, zero atomics)
//  E2: attnsum: attnF[bh][d][c] = (sum_ks attnP)*kinv -> bf16 (+ zero ysq)
//  M : wmix: Wff[b][o][h*64+c] = sum_d Wf[o][h*64+d]*attnF[bh][d][c] (268 MF)
//  G : FFN GEMM y = ffn_b + Wff_b @ qsm -> fp32 DIRECT INTO d_out (K/V dead);
//      ysq epilogue from fp32 y; two-half LDS-staged fp32 C-write
//  H : final in-place: out = out*inv(||col||)*g2*sqrtC + x (element-local)
//
// R7: swizzle pairing verified on HW (bank conflicts 19.3M -> 393K).
// R6: linear [128][64] tile = 16-way conflict (T2 regime).
// R8 lesson base: m99-m141 say 128^2 2-barrier GEMM is at structural ceiling
// -> attack stage count/traffic algebraically instead of GEMM schedule.
// NOTE: previous round's identical source hit "container failed twice"
// (acquisition-layer infra error, same as R2 which passed on resubmission).
// Full audit found no defect (barrier uniformity, bounds, aliasing
// lifetimes, replay idempotence) -> resubmitted unchanged.
// ---------------------------------------------------------------------------

typedef __bf16 bf16_t;
typedef __bf16 bf8 __attribute__((ext_vector_type(8)));
typedef float f32x4 __attribute__((ext_vector_type(4)));

#define NC 512
#define NP 4096
#define SQRTC 22.62741699796952f
#define QSCALE 0.125f
#define QSTRIDE  ((size_t)NC * NP)      // 2097152  per-batch 512-row elems
#define KVSTRIDE ((size_t)1024 * NP)    // 4194304  per-batch kv elems (d_out)
#define LDC 136                          // epilogue C-tile stride (bank-spread)

__device__ inline unsigned short bfbits(__bf16 h) {
    return __builtin_bit_cast(unsigned short, h);
}

// async global->LDS, 16B per lane. LDS dest wave-uniform base + lane*16.
__device__ __forceinline__ void gload_lds16(const bf16_t* g, __bf16* l) {
    __builtin_amdgcn_global_load_lds(
        (const __attribute__((address_space(1))) void*)g,
        (__attribute__((address_space(3))) void*)l, 16, 0, 0);
}

// ---------------------------------------------------------------------------
// W (fallback only): both weight converts. blocks 0..767: Wg; 768..1023: Wf.
// ---------------------------------------------------------------------------
__global__ __launch_bounds__(256) void
wconv_kernel(const float* __restrict__ qkv_w, const float* __restrict__ g,
             const float* __restrict__ ffn_w, bf16_t* __restrict__ Wg,
             bf16_t* __restrict__ Wf) {
    const int bx = blockIdx.x;
    if (bx < 768) {
        int i0 = (bx * 256 + threadIdx.x) * 4;
        float4 wv = *(const float4*)&qkv_w[i0];
        const float4 gv = *(const float4*)&g[i0 & 511];
        ushort4 o;
        o.x = bfbits((__bf16)(wv.x * gv.x));
        o.y = bfbits((__bf16)(wv.y * gv.y));
        o.z = bfbits((__bf16)(wv.z * gv.z));
        o.w = bfbits((__bf16)(wv.w * gv.w));
        *(ushort4*)&Wg[i0] = o;
    } else {
        int i0 = ((bx - 768) * 256 + threadIdx.x) * 4;
        float4 wv = *(const float4*)&ffn_w[i0];
        ushort4 o;
        o.x = bfbits((__bf16)wv.x);
        o.y = bfbits((__bf16)wv.y);
        o.z = bfbits((__bf16)wv.z);
        o.w = bfbits((__bf16)wv.w);
        *(ushort4*)&Wf[i0] = o;
    }
}

// ---------------------------------------------------------------------------
// T: norm + transpose (+ optional fused weight convert in blocks bid<512).
// grid(128, nb) block 512. xnT[p][c] = x[c][p] * sqrtC/max(||x[:,p]||,eps)
// ---------------------------------------------------------------------------
__global__ __launch_bounds__(512) void
norm_transpose_kernel(const float* __restrict__ x, bf16_t* __restrict__ xnT,
                      const float* __restrict__ qkv_w, const float* __restrict__ g,
                      const float* __restrict__ ffn_w, bf16_t* __restrict__ Wg,
                      bf16_t* __restrict__ Wf, int doW) {
    const int bl = blockIdx.y;
    const int p0 = blockIdx.x * 32;
    const int t = threadIdx.x;

    if (doW) {                            // fused weight convert (full mode)
        const int bid = blockIdx.y * 128 + blockIdx.x;
        if (bid < 512) {
            int i0 = bid * 2048 + t * 4;  // blocks 0..383 qkv, 384..511 ffn
            if (i0 < 786432) {
                float4 wv = *(const float4*)&qkv_w[i0];
                const float4 gv = *(const float4*)&g[i0 & 511];
                ushort4 o;
                o.x = bfbits((__bf16)(wv.x * gv.x));
                o.y = bfbits((__bf16)(wv.y * gv.y));
                o.z = bfbits((__bf16)(wv.z * gv.z));
                o.w = bfbits((__bf16)(wv.w * gv.w));
                *(ushort4*)&Wg[i0] = o;
            } else {
                int j0 = i0 - 786432;
                float4 wv = *(const float4*)&ffn_w[j0];
                ushort4 o;
                o.x = bfbits((__bf16)wv.x);
                o.y = bfbits((__bf16)wv.y);
                o.z = bfbits((__bf16)wv.z);
                o.w = bfbits((__bf16)wv.w);
                *(ushort4*)&Wf[j0] = o;
            }
        }
    }

    const float* xb = x + (size_t)bl * QSTRIDE;
    bf16_t* ob = xnT + (size_t)bl * QSTRIDE;

    // pass 1: sumsq, float4 coalesced + shfl_xor tree
    const int cg = t & 7, r0 = t >> 3;
    f32x4 ss = {0.f, 0.f, 0.f, 0.f};
    #pragma unroll
    for (int k = 0; k < 8; ++k) {
        const int c = r0 + k * 64;
        float4 v = *(const float4*)&xb[(size_t)c * NP + p0 + cg * 4];
        ss.x += v.x * v.x; ss.y += v.y * v.y;
        ss.z += v.z * v.z; ss.w += v.w * v.w;
    }
    #pragma unroll
    for (int m = 8; m <= 32; m <<= 1) {
        ss.x += __shfl_xor(ss.x, m); ss.y += __shfl_xor(ss.y, m);
        ss.z += __shfl_xor(ss.z, m); ss.w += __shfl_xor(ss.w, m);
    }
    __shared__ float sP[8][34];
    __shared__ float sInv[32];
    const int w = t >> 6;
    if ((t & 63) < 8) {
        const int p = (t & 7) * 4;
        sP[w][p] = ss.x; sP[w][p + 1] = ss.y;
        sP[w][p + 2] = ss.z; sP[w][p + 3] = ss.w;
    }
    __syncthreads();
    if (t < 32) {
        float tot = 0.f;
        #pragma unroll
        for (int j = 0; j < 8; ++j) tot += sP[j][t];
        sInv[t] = SQRTC / fmaxf(sqrtf(tot), 1e-12f);
    }
    __syncthreads();

    // pass 2: 128-c x 32-p chunks through LDS transpose, float4 loads
    __shared__ __bf16 sT[128][41];
    for (int cc = 0; cc < 512; cc += 128) {
        #pragma unroll
        for (int j = 0; j < 2; ++j) {
            int idx = t + j * 512;               // [0,1024): 128 cr x 8 pg
            int cr = idx >> 3, pg = idx & 7;
            float4 v = *(const float4*)&xb[(size_t)(cc + cr) * NP + p0 + pg * 4];
            sT[cr][pg * 4 + 0] = (__bf16)(v.x * sInv[pg * 4 + 0]);
            sT[cr][pg * 4 + 1] = (__bf16)(v.y * sInv[pg * 4 + 1]);
            sT[cr][pg * 4 + 2] = (__bf16)(v.z * sInv[pg * 4 + 2]);
            sT[cr][pg * 4 + 3] = (__bf16)(v.w * sInv[pg * 4 + 3]);
        }
        __syncthreads();
        {
            int p = t >> 4, c8 = (t & 15) * 8;
            bf8 v;
            #pragma unroll
            for (int q = 0; q < 8; ++q) v[q] = sT[c8 + q][p];
            *(bf8*)&ob[(size_t)(p0 + p) * NC + cc + c8] = v;
        }
        __syncthreads();
    }
}

// ---------------------------------------------------------------------------
// C: QKV GEMM. grid(32, 12, nb) block 256.
// bm<4: Q path — softmax fused in epilogue, store qsm [p][c] (transposed).
// bm>=4: K,V path — coalesced row-segment stores into d_out.
// ---------------------------------------------------------------------------
__global__ __launch_bounds__(256) void
gemm_qkv_kernel(const bf16_t* __restrict__ Wg, const bf16_t* __restrict__ xnT,
                bf16_t* __restrict__ qout, bf16_t* __restrict__ kvout) {
    const int bn = blockIdx.x, bm = blockIdx.y, b = blockIdx.z;
    const int t = threadIdx.x;
    const int w = t >> 6, ln = t & 63, quad = ln >> 4, l16 = ln & 15;
    const int wm = w >> 1, wn = w & 1;

    __shared__ __align__(16) __bf16 sAB[128 * LDC];
    __bf16* const sA = sAB;
    __bf16* const sB = sAB + 8192;

    f32x4 acc[4][4] = {};
    const bf16_t* Abase = Wg + (size_t)(bm * 128) * NC;
    const bf16_t* Bbase = xnT + (size_t)b * QSTRIDE + (size_t)(bn * 128) * NC;

    // R7 swizzle: permuted global k-granule, XOR ds_read (verified on HW)
    const int lrow = ln >> 3;
    const int lkc = ((ln & 7) ^ lrow) * 8;
    const int xr = l16 & 7;

    for (int kt = 0; kt < 8; ++kt) {
        const int k0 = kt * 64;
        #pragma unroll
        for (int i = 0; i < 4; ++i) {
            const int chunk = w * 4 + i;
            const int row = chunk * 8 + lrow;
            gload_lds16(Abase + (size_t)row * NC + k0 + lkc, &sA[chunk * 512]);
            gload_lds16(Bbase + (size_t)row * NC + k0 + lkc, &sB[chunk * 512]);
        }
        __syncthreads();
        #pragma unroll
        for (int ks = 0; ks < 2; ++ks) {
            bf8 af[4], bfr[4];
            const int kx = ((ks * 4 + quad) ^ xr) << 3;
            #pragma unroll
            for (int mi = 0; mi < 4; ++mi)
                af[mi] = *(const bf8*)&sA[(wm * 64 + mi * 16 + l16) * 64 + kx];
            #pragma unroll
            for (int ni = 0; ni < 4; ++ni)
                bfr[ni] = *(const bf8*)&sB[(wn * 64 + ni * 16 + l16) * 64 + kx];
            #pragma unroll
            for (int mi = 0; mi < 4; ++mi)
                #pragma unroll
                for (int ni = 0; ni < 4; ++ni)
                    acc[mi][ni] = __builtin_amdgcn_mfma_f32_16x16x32_bf16(
                        af[mi], bfr[ni], acc[mi][ni], 0, 0, 0);
        }
        __syncthreads();
    }

    const int p0 = bn * 128;
    if (bm < 4) {
        // ---- Q path: dump TRANSPOSED [token][chan], softmax, store [p][c] --
        #pragma unroll
        for (int mi = 0; mi < 4; ++mi)
            #pragma unroll
            for (int ni = 0; ni < 4; ++ni)
                #pragma unroll
                for (int r = 0; r < 4; ++r)
                    sAB[(wn * 64 + ni * 16 + l16) * LDC +
                        wm * 64 + mi * 16 + quad * 4 + r] = (__bf16)acc[mi][ni][r];
        __syncthreads();
        {
            // thread -> (token = t&127, head-local = t>>7); row read is b128s
            __bf16* rp = &sAB[(t & 127) * LDC + (t >> 7) * 64];
            float m = -1e30f;
            #pragma unroll
            for (int gg = 0; gg < 8; ++gg) {
                bf8 v = *(const bf8*)&rp[gg * 8];
                #pragma unroll
                for (int j = 0; j < 8; ++j) m = fmaxf(m, (float)v[j]);
            }
            float s = 0.f;
            #pragma unroll
            for (int gg = 0; gg < 8; ++gg) {
                bf8 v = *(const bf8*)&rp[gg * 8];
                #pragma unroll
                for (int j = 0; j < 8; ++j) s += __expf((float)v[j] - m);
            }
            const float inv = QSCALE / s;
            #pragma unroll
            for (int gg = 0; gg < 8; ++gg) {
                bf8 v = *(const bf8*)&rp[gg * 8];
                #pragma unroll
                for (int j = 0; j < 8; ++j)
                    v[j] = (__bf16)(__expf((float)v[j] - m) * inv);
                *(bf8*)&rp[gg * 8] = v;
            }
        }
        __syncthreads();
        bf16_t* qb = qout + (size_t)b * QSTRIDE;
        #pragma unroll
        for (int i = 0; i < 8; ++i) {
            int e = t + i * 256;               // 2048 = 128 tok x 16 c8
            int p = e >> 4, c8 = (e & 15) * 8;
            bf8 v = *(const bf8*)&sAB[p * LDC + c8];
            *(bf8*)&qb[(size_t)(p0 + p) * NC + bm * 128 + c8] = v;
        }
    } else {
        // ---- K/V path: normal dump + coalesced row-segment stores ---------
        {
            const int rbase = wm * 64 + quad * 4;
            const int cbase = wn * 64 + l16;
            #pragma unroll
            for (int mi = 0; mi < 4; ++mi)
                #pragma unroll
                for (int ni = 0; ni < 4; ++ni)
                    #pragma unroll
                    for (int r = 0; r < 4; ++r)
                        sAB[(rbase + mi * 16 + r) * LDC + cbase + ni * 16] =
                            (__bf16)acc[mi][ni][r];
        }
        __syncthreads();
        bf16_t* kvb = kvout + (size_t)b * KVSTRIDE;
        #pragma unroll
        for (int i = 0; i < 8; ++i) {
            int e = t + i * 256;
            int rr = e >> 4, seg = (e & 15) * 8;
            bf8 v = *(const bf8*)&sAB[rr * LDC + seg];
            *(bf8*)&kvb[(size_t)(bm * 128 + rr - 512) * NP + p0 + seg] = v;
        }
    }
}

// ---------------------------------------------------------------------------
// D: k-softmax stats per (b, channel) row. grid(512, 8) block 256.
// ---------------------------------------------------------------------------
__global__ __launch_bounds__(256) void
kstats_kernel(const bf16_t* __restrict__ kv, float* __restrict__ kmax,
              float* __restrict__ kinv) {
    const int oc = blockIdx.x, b = blockIdx.y;
    const int t = threadIdx.x, w = t >> 6, ln = t & 63;

    const bf16_t* row = kv + (size_t)b * KVSTRIDE + (size_t)oc * NP;
    float v[16];
    bf8 x0 = *(const bf8*)&row[t * 8];
    bf8 x1 = *(const bf8*)&row[2048 + t * 8];
    #pragma unroll
    for (int j = 0; j < 8; ++j) { v[j] = (float)x0[j]; v[8 + j] = (float)x1[j]; }

    float m = v[0];
    #pragma unroll
    for (int j = 1; j < 16; ++j) m = fmaxf(m, v[j]);
    #pragma unroll
    for (int off = 32; off > 0; off >>= 1) m = fmaxf(m, __shfl_down(m, off));
    __shared__ float sR[4];
    __shared__ float sS[4];
    if (ln == 0) sR[w] = m;
    __syncthreads();
    m = fmaxf(fmaxf(sR[0], sR[1]), fmaxf(sR[2], sR[3]));

    float s = 0.f;
    #pragma unroll
    for (int j = 0; j < 16; ++j) s += __expf(v[j] - m);
    #pragma unroll
    for (int off = 32; off > 0; off >>= 1) s += __shfl_down(s, off);
    if (ln == 0) sS[w] = s;
    __syncthreads();
    if (t == 0) {
        kmax[b * 512 + oc] = m;
        kinv[b * 512 + oc] = 1.0f / (sS[0] + sS[1] + sS[2] + sS[3]);
    }
}

// ---------------------------------------------------------------------------
// E: attnP[bh][ks][d][c] partials. grid(8, 8, 8) block 256. Wave-specialized
// over d; no atomics, no LDS.
// ---------------------------------------------------------------------------
__global__ __launch_bounds__(256) void
attn_kernel(const bf16_t* __restrict__ kv, const float* __restrict__ kmax,
            float* __restrict__ attnP) {
    const int h = blockIdx.x, ks = blockIdx.y, b = blockIdx.z;
    const int t = threadIdx.x, w = t >> 6, ln = t & 63, quad = ln >> 4, l16 = ln & 15;

    const bf16_t* Kb = kv + (size_t)b * KVSTRIDE + (size_t)(h * 64) * NP;
    const bf16_t* Vb = kv + (size_t)b * KVSTRIDE + (size_t)(512 + h * 64 + w * 16) * NP;

    float km[4];
    #pragma unroll
    for (int mi = 0; mi < 4; ++mi) km[mi] = kmax[b * 512 + h * 64 + mi * 16 + l16];

    f32x4 acc[4] = {};
    const int pbase = ks * 512 + quad * 8;
    #pragma unroll 4
    for (int it = 0; it < 16; ++it) {
        const int p0 = pbase + it * 32;
        bf8 bfr = *(const bf8*)&Vb[(size_t)l16 * NP + p0];
        #pragma unroll
        for (int mi = 0; mi < 4; ++mi) {
            bf8 kr = *(const bf8*)&Kb[(size_t)(mi * 16 + l16) * NP + p0];
            bf8 af;
            #pragma unroll
            for (int j = 0; j < 8; ++j)
                af[j] = (__bf16)__expf((float)kr[j] - km[mi]);
            acc[mi] = __builtin_amdgcn_mfma_f32_16x16x32_bf16(af, bfr, acc[mi], 0, 0, 0);
        }
    }

    float* outp = attnP + (((size_t)(b * 8 + h) * 8 + ks) << 12);
    #pragma unroll
    for (int mi = 0; mi < 4; ++mi) {
        float4 v;
        v.x = acc[mi][0]; v.y = acc[mi][1]; v.z = acc[mi][2]; v.w = acc[mi][3];
        *(float4*)&outp[(w * 16 + l16) * 64 + mi * 16 + quad * 4] = v;
    }
}

// ---------------------------------------------------------------------------
// E2: attnF[bh][d][c] = (sum_ks attnP)*kinv -> bf16. grid(64,4) block 256.
// Also zeroes ysq (stream-ordered before gemm_ffn accumulation).
// ---------------------------------------------------------------------------
__global__ __launch_bounds__(256) void
attnsum_kernel(const float* __restrict__ attnP, const float* __restrict__ kinv,
               bf16_t* __restrict__ attnF, float* __restrict__ ysq) {
    const int gtid = (blockIdx.x * 4 + blockIdx.y) * 256 + threadIdx.x;
    if (gtid < 8 * NP) ysq[gtid] = 0.f;

    const int bh = blockIdx.x;
    const int e0 = blockIdx.y * 1024 + threadIdx.x * 4;
    const float* ap = attnP + ((size_t)bh << 15);
    float4 s = {0.f, 0.f, 0.f, 0.f};
    #pragma unroll
    for (int ks = 0; ks < 8; ++ks) {
        float4 v = *(const float4*)&ap[(ks << 12) + e0];
        s.x += v.x; s.y += v.y; s.z += v.z; s.w += v.w;
    }
    const float* kvp = kinv + (bh >> 3) * 512 + (bh & 7) * 64;
    const int c = e0 & 63;
    ushort4 o;
    o.x = bfbits((__bf16)(s.x * kvp[c]));
    o.y = bfbits((__bf16)(s.y * kvp[c + 1]));
    o.z = bfbits((__bf16)(s.z * kvp[c + 2]));
    o.w = bfbits((__bf16)(s.w * kvp[c + 3]));
    *(ushort4*)&attnF[((size_t)bh << 12) + e0] = o;
}

// ---------------------------------------------------------------------------
// M: wmix — Wff[b][o][h*64+c] = sum_d Wf[o][h*64+d] * attnF[bh][d][c].
// grid(4, 8, 8) = (om, h, b), block 256 (4 waves x 32 o-rows). 268 MFLOP.
// ---------------------------------------------------------------------------
__global__ __launch_bounds__(256) void
wmix_kernel(const bf16_t* __restrict__ Wf, const bf16_t* __restrict__ attnF,
            bf16_t* __restrict__ Wff) {
    const int om = blockIdx.x, h = blockIdx.y, b = blockIdx.z;
    const int t = threadIdx.x, w = t >> 6, ln = t & 63, quad = ln >> 4, l16 = ln & 15;

    __shared__ __bf16 sT[64][72];          // sT[c][d] = attnF[d][c]
    const bf16_t* aF = attnF + ((size_t)(b * 8 + h) << 12);
    #pragma unroll
    for (int i = 0; i < 2; ++i) {
        int e = t + i * 256;               // 512 jobs: d row, 8-c group
        int d = e >> 3, c8 = (e & 7) * 8;
        bf8 v = *(const bf8*)&aF[d * 64 + c8];
        #pragma unroll
        for (int j = 0; j < 8; ++j) sT[c8 + j][d] = v[j];
    }
    __syncthreads();

    const int obase = om * 128 + w * 32;
    f32x4 acc[2][4] = {};
    #pragma unroll
    for (int kk = 0; kk < 2; ++kk) {
        bf8 af[2], bfr[4];
        #pragma unroll
        for (int mi = 0; mi < 2; ++mi)
            af[mi] = *(const bf8*)&Wf[(size_t)(obase + mi * 16 + l16) * NC +
                                      h * 64 + kk * 32 + quad * 8];
        #pragma unroll
        for (int ni = 0; ni < 4; ++ni)
            bfr[ni] = *(const bf8*)&sT[ni * 16 + l16][kk * 32 + quad * 8];
        #pragma unroll
        for (int mi = 0; mi < 2; ++mi)
            #pragma unroll
            for (int ni = 0; ni < 4; ++ni)
                acc[mi][ni] = __builtin_amdgcn_mfma_f32_16x16x32_bf16(
                    af[mi], bfr[ni], acc[mi][ni], 0, 0, 0);
    }
    bf16_t* outp = Wff + ((size_t)b << 18);     // 512*512 per batch
    #pragma unroll
    for (int mi = 0; mi < 2; ++mi)
        #pragma unroll
        for (int ni = 0; ni < 4; ++ni)
            #pragma unroll
            for (int r = 0; r < 4; ++r) {
                int o = obase + mi * 16 + quad * 4 + r;
                int c = ni * 16 + l16;
                outp[(size_t)o * NC + h * 64 + c] = (__bf16)acc[mi][ni][r];
            }
}

// ---------------------------------------------------------------------------
// G: FFN GEMM. grid(32, 4, 8) block 256. A = Wff[b] [512][512], B = qsm [p][c].
// y fp32 DIRECT into d_out (K/V dead). ysq from fp32 y. Two-half LDS-staged
// fp32 C-write ([64][136] f32 = 34816B fits the same LDS block).
// ---------------------------------------------------------------------------
__global__ __launch_bounds__(256) void
gemm_ffn_kernel(const bf16_t* __restrict__ Wff, const bf16_t* __restrict__ qsm,
                const float* __restrict__ bias, float* __restrict__ out,
                float* __restrict__ ysq) {
    const int bn = blockIdx.x, bm = blockIdx.y, b = blockIdx.z;
    const int t = threadIdx.x;
    const int w = t >> 6, ln = t & 63, quad = ln >> 4, l16 = ln & 15;
    const int wm = w >> 1, wn = w & 1;

    __shared__ __align__(16) __bf16 sAB[128 * LDC];
    __bf16* const sA = sAB;
    __bf16* const sB = sAB + 8192;

    f32x4 acc[4][4] = {};
    const bf16_t* Abase = Wff + ((size_t)b << 18) + (size_t)(bm * 128) * NC;
    const bf16_t* Bbase = qsm + (size_t)b * QSTRIDE + (size_t)(bn * 128) * NC;

    const int lrow = ln >> 3;
    const int lkc = ((ln & 7) ^ lrow) * 8;
    const int xr = l16 & 7;

    for (int kt = 0; kt < 8; ++kt) {
        const int k0 = kt * 64;
        #pragma unroll
        for (int i = 0; i < 4; ++i) {
            const int chunk = w * 4 + i;
            const int row = chunk * 8 + lrow;
            gload_lds16(Abase + (size_t)row * NC + k0 + lkc, &sA[chunk * 512]);
            gload_lds16(Bbase + (size_t)row * NC + k0 + lkc, &sB[chunk * 512]);
        }
        __syncthreads();
        #pragma unroll
        for (int ks = 0; ks < 2; ++ks) {
            bf8 af[4], bfr[4];
            const int kx = ((ks * 4 + quad) ^ xr) << 3;
            #pragma unroll
            for (int mi = 0; mi < 4; ++mi)
                af[mi] = *(const bf8*)&sA[(wm * 64 + mi * 16 + l16) * 64 + kx];
            #pragma unroll
            for (int ni = 0; ni < 4; ++ni)
                bfr[ni] = *(const bf8*)&sB[(wn * 64 + ni * 16 + l16) * 64 + kx];
            #pragma unroll
            for (int mi = 0; mi < 4; ++mi)
                #pragma unroll
                for (int ni = 0; ni < 4; ++ni)
                    acc[mi][ni] = __builtin_amdgcn_mfma_f32_16x16x32_bf16(
                        af[mi], bfr[ni], acc[mi][ni], 0, 0, 0);
        }
        __syncthreads();
    }

    // ysq from fp32 y (register layout)
    float* sq = ysq + (size_t)b * NP;
    const int p0 = bn * 128;
    const int rbase = wm * 64 + quad * 4;
    #pragma unroll
    for (int ni = 0; ni < 4; ++ni) {
        const int col = p0 + wn * 64 + ni * 16 + l16;
        float colsq = 0.f;
        #pragma unroll
        for (int mi = 0; mi < 4; ++mi)
            #pragma unroll
            for (int r = 0; r < 4; ++r) {
                float vf = acc[mi][ni][r] + bias[bm * 128 + rbase + mi * 16 + r];
                colsq += vf * vf;
            }
        colsq += __shfl_xor(colsq, 16);
        colsq += __shfl_xor(colsq, 32);
        if (quad == 0) atomicAdd(&sq[col], colsq);
    }

    // two-half fp32 C-write through LDS
    float* sF = (float*)sAB;                    // [64][136] f32 = 34816 B
    float* ob = out + (size_t)b * QSTRIDE;
    #pragma unroll
    for (int half = 0; half < 2; ++half) {
        __syncthreads();
        if (wm == half) {
            #pragma unroll
            for (int mi = 0; mi < 4; ++mi)
                #pragma unroll
                for (int ni = 0; ni < 4; ++ni)
                    #pragma unroll
                    for (int r = 0; r < 4; ++r)
                        sF[(quad * 4 + mi * 16 + r) * 136 + wn * 64 + ni * 16 + l16] =
                            acc[mi][ni][r] +
                            bias[bm * 128 + half * 64 + quad * 4 + mi * 16 + r];
        }
        __syncthreads();
        #pragma unroll
        for (int i = 0; i < 8; ++i) {
            int e = t + i * 256;                // 2048 = 64 rows x 32 f4-segs
            int rr = e >> 5, c4 = (e & 31) * 4;
            float4 v = *(const float4*)&sF[rr * 136 + c4];
            *(float4*)&ob[(size_t)(bm * 128 + half * 64 + rr) * NP + p0 + c4] = v;
        }
    }
}

// ---------------------------------------------------------------------------
// H: in-place final: out = out*inv*g2*sqrtC + x. grid(1024, 8) block 256.
// Element-local read-modify-write -> no aliasing hazard.
// ---------------------------------------------------------------------------
__global__ __launch_bounds__(256) void
final_kernel(float* __restrict__ out, const float* __restrict__ ysq,
             const float* __restrict__ g2, const float* __restrict__ x) {
    const int b = blockIdx.y;
    int idx = blockIdx.x * 256 + threadIdx.x;
    int o = idx >> 9;
    int p8 = (idx & 511) * 8;
    float* ob = out + (size_t)b * QSTRIDE;
    const float* xb = x + (size_t)b * QSTRIDE;
    const float* sq = ysq + (size_t)b * NP;

    float4 y0 = *(const float4*)&ob[(size_t)o * NP + p8];
    float4 y1 = *(const float4*)&ob[(size_t)o * NP + p8 + 4];
    float gv = g2[o] * SQRTC;
    float4 a = *(const float4*)&xb[(size_t)o * NP + p8];
    float4 b2 = *(const float4*)&xb[(size_t)o * NP + p8 + 4];
    float inb[8];
    #pragma unroll
    for (int j = 0; j < 8; ++j)
        inb[j] = 1.0f / fmaxf(sqrtf(sq[p8 + j]), 1e-12f);

    float4 r0, r1;
    r0.x = y0.x * inb[0] * gv + a.x;
    r0.y = y0.y * inb[1] * gv + a.y;
    r0.z = y0.z * inb[2] * gv + a.z;
    r0.w = y0.w * inb[3] * gv + a.w;
    r1.x = y1.x * inb[4] * gv + b2.x;
    r1.y = y1.y * inb[5] * gv + b2.y;
    r1.z = y1.z * inb[6] * gv + b2.z;
    r1.w = y1.w * inb[7] * gv + b2.w;
    *(float4*)&ob[(size_t)o * NP + p8] = r0;
    *(float4*)&ob[(size_t)o * NP + p8 + 4] = r1;
}

// ---------------------------------------------------------------------------
extern "C" void kernel_launch(void* const* d_in, const int* in_sizes, int n_in,
                              void* d_out, int out_size, void* d_ws, size_t ws_size,
                              hipStream_t stream) {
    const float* x     = (const float*)d_in[0];
    const float* g     = (const float*)d_in[1];
    const float* qkv_w = (const float*)d_in[2];
    const float* ffn_w = (const float*)d_in[3];
    const float* ffn_b = (const float*)d_in[4];
    const float* ffn_g = (const float*)d_in[5];
    float* out = (float*)d_out;
    bf16_t* kv = (bf16_t*)d_out;     // K,V (bf16) then fp32 y/out (all of d_out)

    // ws gate: full 8-batch xnT layout vs 2-batch chunks (unchanged from R6)
    const size_t FULL_BYTES =
        (8 * QSTRIDE + 8 * QSTRIDE + 786432 + 262144) * sizeof(bf16_t) +
        (8 * 512 + 8 * 512 + 8 * (size_t)NP) * sizeof(float);
    const bool full = ws_size >= FULL_BYTES;

    bf16_t* q    = (bf16_t*)d_ws;                    // qsm, [p][c] per batch
    bf16_t* xnT  = q + 8 * QSTRIDE;                  // 8 or 2 batches
    bf16_t* Wg   = xnT + (full ? 8 : 2) * QSTRIDE;   // 786432 bf16
    float*  attnP = (float*)xnT;                     // 8.39 MB (xnT dead)
    bf16_t* attnF = Wg;                              // 512 KB (Wg dead)
    bf16_t* Wff  = xnT;                              // 4 MB (attnP dead)
    bf16_t* Wf   = Wg + 786432;                      // 262144 bf16
    float*  kmax = (float*)(Wf + 262144);            // 8*512 f32
    float*  kinv = kmax + 8 * 512;                   // 8*512 f32
    float*  ysq  = kinv + 8 * 512;                   // 8*4096 f32

    if (full) {
        norm_transpose_kernel<<<dim3(128, 8), 512, 0, stream>>>(
            x, xnT, qkv_w, g, ffn_w, Wg, Wf, 1);
        gemm_qkv_kernel<<<dim3(32, 12, 8), 256, 0, stream>>>(Wg, xnT, q, kv);
    } else {
        wconv_kernel<<<dim3(1024), 256, 0, stream>>>(qkv_w, g, ffn_w, Wg, Wf);
        for (int c = 0; c < 4; ++c) {
            norm_transpose_kernel<<<dim3(128, 2), 512, 0, stream>>>(
                x + (size_t)(2 * c) * QSTRIDE, xnT,
                qkv_w, g, ffn_w, Wg, Wf, 0);
            gemm_qkv_kernel<<<dim3(32, 12, 2), 256, 0, stream>>>(
                Wg, xnT, q + (size_t)(2 * c) * QSTRIDE,
                kv + (size_t)(2 * c) * KVSTRIDE);
        }
    }

    kstats_kernel<<<dim3(512, 8), 256, 0, stream>>>(kv, kmax, kinv);
    attn_kernel<<<dim3(8, 8, 8), 256, 0, stream>>>(kv, kmax, attnP);
    attnsum_kernel<<<dim3(64, 4), 256, 0, stream>>>(attnP, kinv, attnF, ysq);
    wmix_kernel<<<dim3(4, 8, 8), 256, 0, stream>>>(Wf, attnF, Wff);
    gemm_ffn_kernel<<<dim3(32, 4, 8), 256, 0, stream>>>(Wff, q, ffn_b, out, ysq);
    final_kernel<<<dim3(1024, 8), 256, 0, stream>>>(out, ysq, ffn_g, x);
}

// Round 10
// 294.339 us; speedup vs baseline: 1.3492x; 1.0339x over previous
//
#include <hip/hip_runtime.h>

// ---------------------------------------------------------------------------
// MultiHeadsLinearAttention  (B=8, C=512, HEADS=8, CH=64, H=W=64 -> N=4096)
// Inputs fp32, output fp32. Compute: bf16 MFMA, fp32 accumulation.
//
// Dataflow (outgemm eliminated by associativity, R8):
//   y = Wf @ (qsm @ attnF)  ==  (Wf_h @ attnF_h per head) @ qsm = Wff_b @ qsm
// Stages (full-ws mode):
//  T : norm+transpose (+fused weight convert); xnT[p][c] bf16
//  C : QKV GEMM (128x128, BK=64, gload_lds + R7 source-permutation swizzle);
//      Q path fuses q-softmax on fp32 acc, stores qsm [p][c]; K,V -> d_out
//  D : k-softmax stats (kmax,kinv)
//  E : attnP partials (MFMA, wave-specialized, zero atomics) + zeroes ysq
//  M : wmix SELF-SUMS attnP (R10: attnsum deleted), folds kinv, computes
//      Wff[b][o][h*64+c] = sum_d Wf[o][h*64+d]*attnF[bh][d][c] -> d_out base
//      (K/V dead after E; Wff 4MB overwrites dead batch-0 K)
//  G : FFN GEMM y = ffn_b + Wff_b @ qsm -> bf16 y into dead xnT region
//      (R10: reverted from fp32-in-d_out — R9 counters showed the fp32 y
//      cost ~10us of pure write/read traffic for zero absmax gain);
//      ysq from bf16-rounded y (R7-consistent numerics)
//  H : final: out = y*inv(||col||)*g2*sqrtC + x -> d_out (write-only)
// Chunk-ws fallback keeps the R9 pipeline verbatim (flagged paths).
//
// R7: swizzle pairing verified on HW (bank conflicts 19.3M -> 393K).
// R9 lesson: fp32-y was a hidden regression; outgemm was ~8us not 15.
// R8 scar: 8.4M contended atomics -> partials + wave-specialization.
// m99-m141: 128^2 2-barrier GEMM at structural ceiling; VGPR 88 caps
// occupancy at 4 blocks/CU regardless of LDS.
// ---------------------------------------------------------------------------

typedef __bf16 bf16_t;
typedef __bf16 bf8 __attribute__((ext_vector_type(8)));
typedef float f32x4 __attribute__((ext_vector_type(4)));

#define NC 512
#define NP 4096
#define SQRTC 22.62741699796952f
#define QSCALE 0.125f
#define QSTRIDE  ((size_t)NC * NP)      // 2097152  per-batch 512-row elems
#define KVSTRIDE ((size_t)1024 * NP)    // 4194304  per-batch kv elems (d_out)
#define LDC 136                          // epilogue C-tile stride (bank-spread)

__device__ inline unsigned short bfbits(__bf16 h) {
    return __builtin_bit_cast(unsigned short, h);
}

// async global->LDS, 16B per lane. LDS dest wave-uniform base + lane*16.
__device__ __forceinline__ void gload_lds16(const bf16_t* g, __bf16* l) {
    __builtin_amdgcn_global_load_lds(
        (const __attribute__((address_space(1))) void*)g,
        (__attribute__((address_space(3))) void*)l, 16, 0, 0);
}

// ---------------------------------------------------------------------------
// W (chunk fallback only): both weight converts.
// ---------------------------------------------------------------------------
__global__ __launch_bounds__(256) void
wconv_kernel(const float* __restrict__ qkv_w, const float* __restrict__ g,
             const float* __restrict__ ffn_w, bf16_t* __restrict__ Wg,
             bf16_t* __restrict__ Wf) {
    const int bx = blockIdx.x;
    if (bx < 768) {
        int i0 = (bx * 256 + threadIdx.x) * 4;
        float4 wv = *(const float4*)&qkv_w[i0];
        const float4 gv = *(const float4*)&g[i0 & 511];
        ushort4 o;
        o.x = bfbits((__bf16)(wv.x * gv.x));
        o.y = bfbits((__bf16)(wv.y * gv.y));
        o.z = bfbits((__bf16)(wv.z * gv.z));
        o.w = bfbits((__bf16)(wv.w * gv.w));
        *(ushort4*)&Wg[i0] = o;
    } else {
        int i0 = ((bx - 768) * 256 + threadIdx.x) * 4;
        float4 wv = *(const float4*)&ffn_w[i0];
        ushort4 o;
        o.x = bfbits((__bf16)wv.x);
        o.y = bfbits((__bf16)wv.y);
        o.z = bfbits((__bf16)wv.z);
        o.w = bfbits((__bf16)wv.w);
        *(ushort4*)&Wf[i0] = o;
    }
}

// ---------------------------------------------------------------------------
// T: norm + transpose (+ optional fused weight convert in blocks bid<512).
// grid(128, nb) block 512. xnT[p][c] = x[c][p] * sqrtC/max(||x[:,p]||,eps)
// ---------------------------------------------------------------------------
__global__ __launch_bounds__(512) void
norm_transpose_kernel(const float* __restrict__ x, bf16_t* __restrict__ xnT,
                      const float* __restrict__ qkv_w, const float* __restrict__ g,
                      const float* __restrict__ ffn_w, bf16_t* __restrict__ Wg,
                      bf16_t* __restrict__ Wf, int doW) {
    const int bl = blockIdx.y;
    const int p0 = blockIdx.x * 32;
    const int t = threadIdx.x;

    if (doW) {                            // fused weight convert (full mode)
        const int bid = blockIdx.y * 128 + blockIdx.x;
        if (bid < 512) {
            int i0 = bid * 2048 + t * 4;  // blocks 0..383 qkv, 384..511 ffn
            if (i0 < 786432) {
                float4 wv = *(const float4*)&qkv_w[i0];
                const float4 gv = *(const float4*)&g[i0 & 511];
                ushort4 o;
                o.x = bfbits((__bf16)(wv.x * gv.x));
                o.y = bfbits((__bf16)(wv.y * gv.y));
                o.z = bfbits((__bf16)(wv.z * gv.z));
                o.w = bfbits((__bf16)(wv.w * gv.w));
                *(ushort4*)&Wg[i0] = o;
            } else {
                int j0 = i0 - 786432;
                float4 wv = *(const float4*)&ffn_w[j0];
                ushort4 o;
                o.x = bfbits((__bf16)wv.x);
                o.y = bfbits((__bf16)wv.y);
                o.z = bfbits((__bf16)wv.z);
                o.w = bfbits((__bf16)wv.w);
                *(ushort4*)&Wf[j0] = o;
            }
        }
    }

    const float* xb = x + (size_t)bl * QSTRIDE;
    bf16_t* ob = xnT + (size_t)bl * QSTRIDE;

    // pass 1: sumsq, float4 coalesced + shfl_xor tree
    const int cg = t & 7, r0 = t >> 3;
    f32x4 ss = {0.f, 0.f, 0.f, 0.f};
    #pragma unroll
    for (int k = 0; k < 8; ++k) {
        const int c = r0 + k * 64;
        float4 v = *(const float4*)&xb[(size_t)c * NP + p0 + cg * 4];
        ss.x += v.x * v.x; ss.y += v.y * v.y;
        ss.z += v.z * v.z; ss.w += v.w * v.w;
    }
    #pragma unroll
    for (int m = 8; m <= 32; m <<= 1) {
        ss.x += __shfl_xor(ss.x, m); ss.y += __shfl_xor(ss.y, m);
        ss.z += __shfl_xor(ss.z, m); ss.w += __shfl_xor(ss.w, m);
    }
    __shared__ float sP[8][34];
    __shared__ float sInv[32];
    const int w = t >> 6;
    if ((t & 63) < 8) {
        const int p = (t & 7) * 4;
        sP[w][p] = ss.x; sP[w][p + 1] = ss.y;
        sP[w][p + 2] = ss.z; sP[w][p + 3] = ss.w;
    }
    __syncthreads();
    if (t < 32) {
        float tot = 0.f;
        #pragma unroll
        for (int j = 0; j < 8; ++j) tot += sP[j][t];
        sInv[t] = SQRTC / fmaxf(sqrtf(tot), 1e-12f);
    }
    __syncthreads();

    // pass 2: 128-c x 32-p chunks through LDS transpose, float4 loads
    __shared__ __bf16 sT[128][41];
    for (int cc = 0; cc < 512; cc += 128) {
        #pragma unroll
        for (int j = 0; j < 2; ++j) {
            int idx = t + j * 512;               // [0,1024): 128 cr x 8 pg
            int cr = idx >> 3, pg = idx & 7;
            float4 v = *(const float4*)&xb[(size_t)(cc + cr) * NP + p0 + pg * 4];
            sT[cr][pg * 4 + 0] = (__bf16)(v.x * sInv[pg * 4 + 0]);
            sT[cr][pg * 4 + 1] = (__bf16)(v.y * sInv[pg * 4 + 1]);
            sT[cr][pg * 4 + 2] = (__bf16)(v.z * sInv[pg * 4 + 2]);
            sT[cr][pg * 4 + 3] = (__bf16)(v.w * sInv[pg * 4 + 3]);
        }
        __syncthreads();
        {
            int p = t >> 4, c8 = (t & 15) * 8;
            bf8 v;
            #pragma unroll
            for (int q = 0; q < 8; ++q) v[q] = sT[c8 + q][p];
            *(bf8*)&ob[(size_t)(p0 + p) * NC + cc + c8] = v;
        }
        __syncthreads();
    }
}

// ---------------------------------------------------------------------------
// C: QKV GEMM. grid(32, 12, nb) block 256.
// bm<4: Q path — softmax fused in epilogue, store qsm [p][c] (transposed).
// bm>=4: K,V path — coalesced row-segment stores into d_out.
// ---------------------------------------------------------------------------
__global__ __launch_bounds__(256) void
gemm_qkv_kernel(const bf16_t* __restrict__ Wg, const bf16_t* __restrict__ xnT,
                bf16_t* __restrict__ qout, bf16_t* __restrict__ kvout) {
    const int bn = blockIdx.x, bm = blockIdx.y, b = blockIdx.z;
    const int t = threadIdx.x;
    const int w = t >> 6, ln = t & 63, quad = ln >> 4, l16 = ln & 15;
    const int wm = w >> 1, wn = w & 1;

    __shared__ __align__(16) __bf16 sAB[128 * LDC];
    __bf16* const sA = sAB;
    __bf16* const sB = sAB + 8192;

    f32x4 acc[4][4] = {};
    const bf16_t* Abase = Wg + (size_t)(bm * 128) * NC;
    const bf16_t* Bbase = xnT + (size_t)b * QSTRIDE + (size_t)(bn * 128) * NC;

    // R7 swizzle: permuted global k-granule, XOR ds_read (verified on HW)
    const int lrow = ln >> 3;
    const int lkc = ((ln & 7) ^ lrow) * 8;
    const int xr = l16 & 7;

    for (int kt = 0; kt < 8; ++kt) {
        const int k0 = kt * 64;
        #pragma unroll
        for (int i = 0; i < 4; ++i) {
            const int chunk = w * 4 + i;
            const int row = chunk * 8 + lrow;
            gload_lds16(Abase + (size_t)row * NC + k0 + lkc, &sA[chunk * 512]);
            gload_lds16(Bbase + (size_t)row * NC + k0 + lkc, &sB[chunk * 512]);
        }
        __syncthreads();
        #pragma unroll
        for (int ks = 0; ks < 2; ++ks) {
            bf8 af[4], bfr[4];
            const int kx = ((ks * 4 + quad) ^ xr) << 3;
            #pragma unroll
            for (int mi = 0; mi < 4; ++mi)
                af[mi] = *(const bf8*)&sA[(wm * 64 + mi * 16 + l16) * 64 + kx];
            #pragma unroll
            for (int ni = 0; ni < 4; ++ni)
                bfr[ni] = *(const bf8*)&sB[(wn * 64 + ni * 16 + l16) * 64 + kx];
            #pragma unroll
            for (int mi = 0; mi < 4; ++mi)
                #pragma unroll
                for (int ni = 0; ni < 4; ++ni)
                    acc[mi][ni] = __builtin_amdgcn_mfma_f32_16x16x32_bf16(
                        af[mi], bfr[ni], acc[mi][ni], 0, 0, 0);
        }
        __syncthreads();
    }

    const int p0 = bn * 128;
    if (bm < 4) {
        // ---- Q path: dump TRANSPOSED [token][chan], softmax, store [p][c] --
        #pragma unroll
        for (int mi = 0; mi < 4; ++mi)
            #pragma unroll
            for (int ni = 0; ni < 4; ++ni)
                #pragma unroll
                for (int r = 0; r < 4; ++r)
                    sAB[(wn * 64 + ni * 16 + l16) * LDC +
                        wm * 64 + mi * 16 + quad * 4 + r] = (__bf16)acc[mi][ni][r];
        __syncthreads();
        {
            // thread -> (token = t&127, head-local = t>>7); row read is b128s
            __bf16* rp = &sAB[(t & 127) * LDC + (t >> 7) * 64];
            float m = -1e30f;
            #pragma unroll
            for (int gg = 0; gg < 8; ++gg) {
                bf8 v = *(const bf8*)&rp[gg * 8];
                #pragma unroll
                for (int j = 0; j < 8; ++j) m = fmaxf(m, (float)v[j]);
            }
            float s = 0.f;
            #pragma unroll
            for (int gg = 0; gg < 8; ++gg) {
                bf8 v = *(const bf8*)&rp[gg * 8];
                #pragma unroll
                for (int j = 0; j < 8; ++j) s += __expf((float)v[j] - m);
            }
            const float inv = QSCALE / s;
            #pragma unroll
            for (int gg = 0; gg < 8; ++gg) {
                bf8 v = *(const bf8*)&rp[gg * 8];
                #pragma unroll
                for (int j = 0; j < 8; ++j)
                    v[j] = (__bf16)(__expf((float)v[j] - m) * inv);
                *(bf8*)&rp[gg * 8] = v;
            }
        }
        __syncthreads();
        bf16_t* qb = qout + (size_t)b * QSTRIDE;
        #pragma unroll
        for (int i = 0; i < 8; ++i) {
            int e = t + i * 256;               // 2048 = 128 tok x 16 c8
            int p = e >> 4, c8 = (e & 15) * 8;
            bf8 v = *(const bf8*)&sAB[p * LDC + c8];
            *(bf8*)&qb[(size_t)(p0 + p) * NC + bm * 128 + c8] = v;
        }
    } else {
        // ---- K/V path: normal dump + coalesced row-segment stores ---------
        {
            const int rbase = wm * 64 + quad * 4;
            const int cbase = wn * 64 + l16;
            #pragma unroll
            for (int mi = 0; mi < 4; ++mi)
                #pragma unroll
                for (int ni = 0; ni < 4; ++ni)
                    #pragma unroll
                    for (int r = 0; r < 4; ++r)
                        sAB[(rbase + mi * 16 + r) * LDC + cbase + ni * 16] =
                            (__bf16)acc[mi][ni][r];
        }
        __syncthreads();
        bf16_t* kvb = kvout + (size_t)b * KVSTRIDE;
        #pragma unroll
        for (int i = 0; i < 8; ++i) {
            int e = t + i * 256;
            int rr = e >> 4, seg = (e & 15) * 8;
            bf8 v = *(const bf8*)&sAB[rr * LDC + seg];
            *(bf8*)&kvb[(size_t)(bm * 128 + rr - 512) * NP + p0 + seg] = v;
        }
    }
}

// ---------------------------------------------------------------------------
// D: k-softmax stats per (b, channel) row. grid(512, 8) block 256.
// ---------------------------------------------------------------------------
__global__ __launch_bounds__(256) void
kstats_kernel(const bf16_t* __restrict__ kv, float* __restrict__ kmax,
              float* __restrict__ kinv) {
    const int oc = blockIdx.x, b = blockIdx.y;
    const int t = threadIdx.x, w = t >> 6, ln = t & 63;

    const bf16_t* row = kv + (size_t)b * KVSTRIDE + (size_t)oc * NP;
    float v[16];
    bf8 x0 = *(const bf8*)&row[t * 8];
    bf8 x1 = *(const bf8*)&row[2048 + t * 8];
    #pragma unroll
    for (int j = 0; j < 8; ++j) { v[j] = (float)x0[j]; v[8 + j] = (float)x1[j]; }

    float m = v[0];
    #pragma unroll
    for (int j = 1; j < 16; ++j) m = fmaxf(m, v[j]);
    #pragma unroll
    for (int off = 32; off > 0; off >>= 1) m = fmaxf(m, __shfl_down(m, off));
    __shared__ float sR[4];
    __shared__ float sS[4];
    if (ln == 0) sR[w] = m;
    __syncthreads();
    m = fmaxf(fmaxf(sR[0], sR[1]), fmaxf(sR[2], sR[3]));

    float s = 0.f;
    #pragma unroll
    for (int j = 0; j < 16; ++j) s += __expf(v[j] - m);
    #pragma unroll
    for (int off = 32; off > 0; off >>= 1) s += __shfl_down(s, off);
    if (ln == 0) sS[w] = s;
    __syncthreads();
    if (t == 0) {
        kmax[b * 512 + oc] = m;
        kinv[b * 512 + oc] = 1.0f / (sS[0] + sS[1] + sS[2] + sS[3]);
    }
}

// ---------------------------------------------------------------------------
// E: attnP[bh][ks][d][c] partials. grid(8, 8, 8) block 256. Wave-specialized
// over d; no atomics, no LDS. Also zeroes ysq (first 128 blocks).
// ---------------------------------------------------------------------------
__global__ __launch_bounds__(256) void
attn_kernel(const bf16_t* __restrict__ kv, const float* __restrict__ kmax,
            float* __restrict__ attnP, float* __restrict__ ysq) {
    const int h = blockIdx.x, ks = blockIdx.y, b = blockIdx.z;
    const int t = threadIdx.x, w = t >> 6, ln = t & 63, quad = ln >> 4, l16 = ln & 15;

    const int zid = ((b * 8 + ks) * 8 + h) * 256 + t;
    if (zid < 8 * NP) ysq[zid] = 0.f;

    const bf16_t* Kb = kv + (size_t)b * KVSTRIDE + (size_t)(h * 64) * NP;
    const bf16_t* Vb = kv + (size_t)b * KVSTRIDE + (size_t)(512 + h * 64 + w * 16) * NP;

    float km[4];
    #pragma unroll
    for (int mi = 0; mi < 4; ++mi) km[mi] = kmax[b * 512 + h * 64 + mi * 16 + l16];

    f32x4 acc[4] = {};
    const int pbase = ks * 512 + quad * 8;
    #pragma unroll 4
    for (int it = 0; it < 16; ++it) {
        const int p0 = pbase + it * 32;
        bf8 bfr = *(const bf8*)&Vb[(size_t)l16 * NP + p0];
        #pragma unroll
        for (int mi = 0; mi < 4; ++mi) {
            bf8 kr = *(const bf8*)&Kb[(size_t)(mi * 16 + l16) * NP + p0];
            bf8 af;
            #pragma unroll
            for (int j = 0; j < 8; ++j)
                af[j] = (__bf16)__expf((float)kr[j] - km[mi]);
            acc[mi] = __builtin_amdgcn_mfma_f32_16x16x32_bf16(af, bfr, acc[mi], 0, 0, 0);
        }
    }

    float* outp = attnP + (((size_t)(b * 8 + h) * 8 + ks) << 12);
    #pragma unroll
    for (int mi = 0; mi < 4; ++mi) {
        float4 v;
        v.x = acc[mi][0]; v.y = acc[mi][1]; v.z = acc[mi][2]; v.w = acc[mi][3];
        *(float4*)&outp[(w * 16 + l16) * 64 + mi * 16 + quad * 4] = v;
    }
}

// ---------------------------------------------------------------------------
// E2 (chunk fallback only): attnF = (sum_ks attnP)*kinv -> bf16; zeroes ysq.
// ---------------------------------------------------------------------------
__global__ __launch_bounds__(256) void
attnsum_kernel(const float* __restrict__ attnP, const float* __restrict__ kinv,
               bf16_t* __restrict__ attnF, float* __restrict__ ysq) {
    const int gtid = (blockIdx.x * 4 + blockIdx.y) * 256 + threadIdx.x;
    if (gtid < 8 * NP) ysq[gtid] = 0.f;

    const int bh = blockIdx.x;
    const int e0 = blockIdx.y * 1024 + threadIdx.x * 4;
    const float* ap = attnP + ((size_t)bh << 15);
    float4 s = {0.f, 0.f, 0.f, 0.f};
    #pragma unroll
    for (int ks = 0; ks < 8; ++ks) {
        float4 v = *(const float4*)&ap[(ks << 12) + e0];
        s.x += v.x; s.y += v.y; s.z += v.z; s.w += v.w;
    }
    const float* kvp = kinv + (bh >> 3) * 512 + (bh & 7) * 64;
    const int c = e0 & 63;
    ushort4 o;
    o.x = bfbits((__bf16)(s.x * kvp[c]));
    o.y = bfbits((__bf16)(s.y * kvp[c + 1]));
    o.z = bfbits((__bf16)(s.z * kvp[c + 2]));
    o.w = bfbits((__bf16)(s.w * kvp[c + 3]));
    *(ushort4*)&attnF[((size_t)bh << 12) + e0] = o;
}

// ---------------------------------------------------------------------------
// M: wmix — Wff[b][o][h*64+c] = sum_d Wf[o][h*64+d] * attnF[bh][d][c].
// grid(4, 8, 8) = (om, h, b), block 256. selfsum=1 (full mode): builds the
// B-operand directly from attnP partials (L2-resident) with kinv folded —
// attnsum kernel eliminated. selfsum=0 (chunk): reads precomputed attnF.
// ---------------------------------------------------------------------------
__global__ __launch_bounds__(256) void
wmix_kernel(const bf16_t* __restrict__ Wf, const float* __restrict__ attnP,
            const float* __restrict__ kinv, const bf16_t* __restrict__ attnF,
            bf16_t* __restrict__ Wff, int selfsum) {
    const int om = blockIdx.x, h = blockIdx.y, b = blockIdx.z;
    const int t = threadIdx.x, w = t >> 6, ln = t & 63, quad = ln >> 4, l16 = ln & 15;

    __shared__ __bf16 sT[64][72];          // sT[c][d] = attnF[d][c]
    if (selfsum) {
        const float* ap = attnP + ((size_t)(b * 8 + h) << 15);
        const float* kvp = kinv + b * 512 + h * 64;
        #pragma unroll
        for (int i = 0; i < 2; ++i) {
            int e = t + i * 256;           // 512 jobs: d row, 8-c group
            int d = e >> 3, c8 = (e & 7) * 8;
            float s[8] = {};
            #pragma unroll
            for (int ks = 0; ks < 8; ++ks) {
                const float* pp = &ap[(ks << 12) + d * 64 + c8];
                float4 v0 = *(const float4*)pp;
                float4 v1 = *(const float4*)(pp + 4);
                s[0] += v0.x; s[1] += v0.y; s[2] += v0.z; s[3] += v0.w;
                s[4] += v1.x; s[5] += v1.y; s[6] += v1.z; s[7] += v1.w;
            }
            #pragma unroll
            for (int j = 0; j < 8; ++j)
                sT[c8 + j][d] = (__bf16)(s[j] * kvp[c8 + j]);
        }
    } else {
        const bf16_t* aF = attnF + ((size_t)(b * 8 + h) << 12);
        #pragma unroll
        for (int i = 0; i < 2; ++i) {
            int e = t + i * 256;
            int d = e >> 3, c8 = (e & 7) * 8;
            bf8 v = *(const bf8*)&aF[d * 64 + c8];
            #pragma unroll
            for (int j = 0; j < 8; ++j) sT[c8 + j][d] = v[j];
        }
    }
    __syncthreads();

    const int obase = om * 128 + w * 32;
    f32x4 acc[2][4] = {};
    #pragma unroll
    for (int kk = 0; kk < 2; ++kk) {
        bf8 af[2], bfr[4];
        #pragma unroll
        for (int mi = 0; mi < 2; ++mi)
            af[mi] = *(const bf8*)&Wf[(size_t)(obase + mi * 16 + l16) * NC +
                                      h * 64 + kk * 32 + quad * 8];
        #pragma unroll
        for (int ni = 0; ni < 4; ++ni)
            bfr[ni] = *(const bf8*)&sT[ni * 16 + l16][kk * 32 + quad * 8];
        #pragma unroll
        for (int mi = 0; mi < 2; ++mi)
            #pragma unroll
            for (int ni = 0; ni < 4; ++ni)
                acc[mi][ni] = __builtin_amdgcn_mfma_f32_16x16x32_bf16(
                    af[mi], bfr[ni], acc[mi][ni], 0, 0, 0);
    }
    bf16_t* outp = Wff + ((size_t)b << 18);     // 512*512 per batch
    #pragma unroll
    for (int mi = 0; mi < 2; ++mi)
        #pragma unroll
        for (int ni = 0; ni < 4; ++ni)
            #pragma unroll
            for (int r = 0; r < 4; ++r) {
                int o = obase + mi * 16 + quad * 4 + r;
                int c = ni * 16 + l16;
                outp[(size_t)o * NC + h * 64 + c] = (__bf16)acc[mi][ni][r];
            }
}

// ---------------------------------------------------------------------------
// G: FFN GEMM. grid(32, 4, 8) block 256. A = Wff[b], B = qsm [p][c].
// ybf=1 (full): bf16 y into ws (dead xnT region), ysq from rounded bf16.
// ybf=0 (chunk): fp32 y direct into d_out, ysq from fp32, two-half C-write.
// ---------------------------------------------------------------------------
__global__ __launch_bounds__(256) void
gemm_ffn_kernel(const bf16_t* __restrict__ Wff, const bf16_t* __restrict__ qsm,
                const float* __restrict__ bias, float* __restrict__ outf,
                bf16_t* __restrict__ ybf16, float* __restrict__ ysq, int ybf) {
    const int bn = blockIdx.x, bm = blockIdx.y, b = blockIdx.z;
    const int t = threadIdx.x;
    const int w = t >> 6, ln = t & 63, quad = ln >> 4, l16 = ln & 15;
    const int wm = w >> 1, wn = w & 1;

    __shared__ __align__(16) __bf16 sAB[128 * LDC];
    __bf16* const sA = sAB;
    __bf16* const sB = sAB + 8192;

    f32x4 acc[4][4] = {};
    const bf16_t* Abase = Wff + ((size_t)b << 18) + (size_t)(bm * 128) * NC;
    const bf16_t* Bbase = qsm + (size_t)b * QSTRIDE + (size_t)(bn * 128) * NC;

    const int lrow = ln >> 3;
    const int lkc = ((ln & 7) ^ lrow) * 8;
    const int xr = l16 & 7;

    for (int kt = 0; kt < 8; ++kt) {
        const int k0 = kt * 64;
        #pragma unroll
        for (int i = 0; i < 4; ++i) {
            const int chunk = w * 4 + i;
            const int row = chunk * 8 + lrow;
            gload_lds16(Abase + (size_t)row * NC + k0 + lkc, &sA[chunk * 512]);
            gload_lds16(Bbase + (size_t)row * NC + k0 + lkc, &sB[chunk * 512]);
        }
        __syncthreads();
        #pragma unroll
        for (int ks = 0; ks < 2; ++ks) {
            bf8 af[4], bfr[4];
            const int kx = ((ks * 4 + quad) ^ xr) << 3;
            #pragma unroll
            for (int mi = 0; mi < 4; ++mi)
                af[mi] = *(const bf8*)&sA[(wm * 64 + mi * 16 + l16) * 64 + kx];
            #pragma unroll
            for (int ni = 0; ni < 4; ++ni)
                bfr[ni] = *(const bf8*)&sB[(wn * 64 + ni * 16 + l16) * 64 + kx];
            #pragma unroll
            for (int mi = 0; mi < 4; ++mi)
                #pragma unroll
                for (int ni = 0; ni < 4; ++ni)
                    acc[mi][ni] = __builtin_amdgcn_mfma_f32_16x16x32_bf16(
                        af[mi], bfr[ni], acc[mi][ni], 0, 0, 0);
        }
        __syncthreads();
    }

    float* sq = ysq + (size_t)b * NP;
    const int p0 = bn * 128;
    const int rbase = wm * 64 + quad * 4;

    if (ybf) {
        // bf16 y path (R7-consistent): ysq from rounded bf16, LDS C-tile
        #pragma unroll
        for (int ni = 0; ni < 4; ++ni) {
            const int col = p0 + wn * 64 + ni * 16 + l16;
            float colsq = 0.f;
            #pragma unroll
            for (int mi = 0; mi < 4; ++mi) {
                #pragma unroll
                for (int r = 0; r < 4; ++r) {
                    const int row = bm * 128 + rbase + mi * 16 + r;
                    __bf16 vb = (__bf16)(acc[mi][ni][r] + bias[row]);
                    sAB[(rbase + mi * 16 + r) * LDC + wn * 64 + ni * 16 + l16] = vb;
                    float vf = (float)vb;
                    colsq += vf * vf;
                }
            }
            colsq += __shfl_xor(colsq, 16);
            colsq += __shfl_xor(colsq, 32);
            if (quad == 0) atomicAdd(&sq[col], colsq);
        }
        __syncthreads();
        bf16_t* yb = ybf16 + (size_t)b * QSTRIDE;
        #pragma unroll
        for (int i = 0; i < 8; ++i) {
            int e = t + i * 256;
            int rr = e >> 4, seg = (e & 15) * 8;
            bf8 v = *(const bf8*)&sAB[rr * LDC + seg];
            *(bf8*)&yb[(size_t)(bm * 128 + rr) * NP + p0 + seg] = v;
        }
    } else {
        // fp32 y path (chunk fallback, R9)
        #pragma unroll
        for (int ni = 0; ni < 4; ++ni) {
            const int col = p0 + wn * 64 + ni * 16 + l16;
            float colsq = 0.f;
            #pragma unroll
            for (int mi = 0; mi < 4; ++mi)
                #pragma unroll
                for (int r = 0; r < 4; ++r) {
                    float vf = acc[mi][ni][r] + bias[bm * 128 + rbase + mi * 16 + r];
                    colsq += vf * vf;
                }
            colsq += __shfl_xor(colsq, 16);
            colsq += __shfl_xor(colsq, 32);
            if (quad == 0) atomicAdd(&sq[col], colsq);
        }
        float* sF = (float*)sAB;                    // [64][136] f32 = 34816 B
        float* ob = outf + (size_t)b * QSTRIDE;
        #pragma unroll
        for (int half = 0; half < 2; ++half) {
            __syncthreads();
            if (wm == half) {
                #pragma unroll
                for (int mi = 0; mi < 4; ++mi)
                    #pragma unroll
                    for (int ni = 0; ni < 4; ++ni)
                        #pragma unroll
                        for (int r = 0; r < 4; ++r)
                            sF[(quad * 4 + mi * 16 + r) * 136 + wn * 64 + ni * 16 + l16] =
                                acc[mi][ni][r] +
                                bias[bm * 128 + half * 64 + quad * 4 + mi * 16 + r];
            }
            __syncthreads();
            #pragma unroll
            for (int i = 0; i < 8; ++i) {
                int e = t + i * 256;
                int rr = e >> 5, c4 = (e & 31) * 4;
                float4 v = *(const float4*)&sF[rr * 136 + c4];
                *(float4*)&ob[(size_t)(bm * 128 + half * 64 + rr) * NP + p0 + c4] = v;
            }
        }
    }
}

// ---------------------------------------------------------------------------
// H: final. ybf=1: out = ybf16*inv*g2*sqrtC + x (write-only out).
//          ybf=0: in-place on fp32 out (chunk fallback, R9).
// grid(1024, 8) block 256.
// ---------------------------------------------------------------------------
__global__ __launch_bounds__(256) void
final_kernel(float* __restrict__ out, const bf16_t* __restrict__ ybf16,
             const float* __restrict__ ysq, const float* __restrict__ g2,
             const float* __restrict__ x, int ybf) {
    const int b = blockIdx.y;
    int idx = blockIdx.x * 256 + threadIdx.x;
    int o = idx >> 9;
    int p8 = (idx & 511) * 8;
    float* ob = out + (size_t)b * QSTRIDE;
    const float* xb = x + (size_t)b * QSTRIDE;
    const float* sq = ysq + (size_t)b * NP;

    float gv = g2[o] * SQRTC;
    float4 a = *(const float4*)&xb[(size_t)o * NP + p8];
    float4 b2 = *(const float4*)&xb[(size_t)o * NP + p8 + 4];
    float inb[8];
    #pragma unroll
    for (int j = 0; j < 8; ++j)
        inb[j] = 1.0f / fmaxf(sqrtf(sq[p8 + j]), 1e-12f);

    float y[8];
    if (ybf) {
        const bf16_t* yb = ybf16 + (size_t)b * QSTRIDE;
        bf8 yv = *(const bf8*)&yb[(size_t)o * NP + p8];
        #pragma unroll
        for (int j = 0; j < 8; ++j) y[j] = (float)yv[j];
    } else {
        float4 y0 = *(const float4*)&ob[(size_t)o * NP + p8];
        float4 y1 = *(const float4*)&ob[(size_t)o * NP + p8 + 4];
        y[0] = y0.x; y[1] = y0.y; y[2] = y0.z; y[3] = y0.w;
        y[4] = y1.x; y[5] = y1.y; y[6] = y1.z; y[7] = y1.w;
    }

    float4 r0, r1;
    r0.x = y[0] * inb[0] * gv + a.x;
    r0.y = y[1] * inb[1] * gv + a.y;
    r0.z = y[2] * inb[2] * gv + a.z;
    r0.w = y[3] * inb[3] * gv + a.w;
    r1.x = y[4] * inb[4] * gv + b2.x;
    r1.y = y[5] * inb[5] * gv + b2.y;
    r1.z = y[6] * inb[6] * gv + b2.z;
    r1.w = y[7] * inb[7] * gv + b2.w;
    *(float4*)&ob[(size_t)o * NP + p8] = r0;
    *(float4*)&ob[(size_t)o * NP + p8 + 4] = r1;
}

// ---------------------------------------------------------------------------
extern "C" void kernel_launch(void* const* d_in, const int* in_sizes, int n_in,
                              void* d_out, int out_size, void* d_ws, size_t ws_size,
                              hipStream_t stream) {
    const float* x     = (const float*)d_in[0];
    const float* g     = (const float*)d_in[1];
    const float* qkv_w = (const float*)d_in[2];
    const float* ffn_w = (const float*)d_in[3];
    const float* ffn_b = (const float*)d_in[4];
    const float* ffn_g = (const float*)d_in[5];
    float* out = (float*)d_out;
    bf16_t* kv = (bf16_t*)d_out;     // K,V bf16; later Wff (full) / fp32 y

    const size_t FULL_BYTES =
        (8 * QSTRIDE + 8 * QSTRIDE + 786432 + 262144) * sizeof(bf16_t) +
        (8 * 512 + 8 * 512 + 8 * (size_t)NP) * sizeof(float);
    const bool full = ws_size >= FULL_BYTES;

    bf16_t* q    = (bf16_t*)d_ws;                    // qsm, [p][c] per batch
    bf16_t* xnT  = q + 8 * QSTRIDE;                  // 8 or 2 batches
    bf16_t* Wg   = xnT + (full ? 8 : 2) * QSTRIDE;   // 786432 bf16
    float*  attnP = (float*)xnT;                     // 8.39 MB (xnT dead)
    bf16_t* y16  = xnT;                              // full: bf16 y (attnP dead)
    bf16_t* attnF = Wg;                              // chunk only (Wg dead)
    bf16_t* WffC = xnT;                              // chunk: Wff (attnP dead)
    bf16_t* WffF = kv;                               // full: Wff in d_out (K dead)
    bf16_t* Wf   = Wg + 786432;                      // 262144 bf16
    float*  kmax = (float*)(Wf + 262144);            // 8*512 f32
    float*  kinv = kmax + 8 * 512;                   // 8*512 f32
    float*  ysq  = kinv + 8 * 512;                   // 8*4096 f32

    if (full) {
        norm_transpose_kernel<<<dim3(128, 8), 512, 0, stream>>>(
            x, xnT, qkv_w, g, ffn_w, Wg, Wf, 1);
        gemm_qkv_kernel<<<dim3(32, 12, 8), 256, 0, stream>>>(Wg, xnT, q, kv);
        kstats_kernel<<<dim3(512, 8), 256, 0, stream>>>(kv, kmax, kinv);
        attn_kernel<<<dim3(8, 8, 8), 256, 0, stream>>>(kv, kmax, attnP, ysq);
        // wmix self-sums attnP (attnsum eliminated); Wff -> d_out (K/V dead)
        wmix_kernel<<<dim3(4, 8, 8), 256, 0, stream>>>(
            Wf, attnP, kinv, nullptr, WffF, 1);
        // ffn: bf16 y into dead xnT region; ysq from rounded bf16
        gemm_ffn_kernel<<<dim3(32, 4, 8), 256, 0, stream>>>(
            WffF, q, ffn_b, nullptr, y16, ysq, 1);
        final_kernel<<<dim3(1024, 8), 256, 0, stream>>>(
            out, y16, ysq, ffn_g, x, 1);
    } else {
        wconv_kernel<<<dim3(1024), 256, 0, stream>>>(qkv_w, g, ffn_w, Wg, Wf);
        for (int c = 0; c < 4; ++c) {
            norm_transpose_kernel<<<dim3(128, 2), 512, 0, stream>>>(
                x + (size_t)(2 * c) * QSTRIDE, xnT,
                qkv_w, g, ffn_w, Wg, Wf, 0);
            gemm_qkv_kernel<<<dim3(32, 12, 2), 256, 0, stream>>>(
                Wg, xnT, q + (size_t)(2 * c) * QSTRIDE,
                kv + (size_t)(2 * c) * KVSTRIDE);
        }
        kstats_kernel<<<dim3(512, 8), 256, 0, stream>>>(kv, kmax, kinv);
        attn_kernel<<<dim3(8, 8, 8), 256, 0, stream>>>(kv, kmax, attnP, ysq);
        attnsum_kernel<<<dim3(64, 4), 256, 0, stream>>>(attnP, kinv, attnF, ysq);
        wmix_kernel<<<dim3(4, 8, 8), 256, 0, stream>>>(
            Wf, attnP, kinv, attnF, WffC, 0);
        gemm_ffn_kernel<<<dim3(32, 4, 8), 256, 0, stream>>>(
            WffC, q, ffn_b, out, nullptr, ysq, 0);
        final_kernel<<<dim3(1024, 8), 256, 0, stream>>>(
            out, nullptr, ysq, ffn_g, x, 0);
    }
}